// Round 1
// baseline (1330.351 us; speedup 1.0000x reference)
//
#include <hip/hip_runtime.h>

// ---- static config (mirrors reference) ----
constexpr int H    = 1024;
constexpr int HD   = 64;
constexpr int NQ   = 16;
constexpr int NKV  = 4;
constexpr int E_   = 8;
constexpr int FFN  = 1024;
constexpr int B_   = 4;
constexpr int Q_   = 128;
constexpr int P_   = 8;
constexpr int PS   = 128;
constexpr int S_   = P_ * PS;                 // 1024
constexpr int T_   = B_ * Q_;                 // 512
constexpr int QKV_N = HD * (NQ + 2 * NKV);    // 1536
constexpr float EPS   = 1e-5f;
constexpr float ALPHA = 1.702f;
constexpr float LIMIT = 7.0f;
constexpr float SCALE = 0.125f;               // HD^-0.5

// ---------------- RMSNorm: one block per token ----------------
__global__ __launch_bounds__(256) void rmsnorm_kernel(const float* __restrict__ in,
                                                      const float* __restrict__ w,
                                                      float* __restrict__ out) {
    int t   = blockIdx.x;
    int tid = threadIdx.x;
    const float4* in4 = (const float4*)(in + (size_t)t * H);
    float4 v = in4[tid];
    float ss = v.x * v.x + v.y * v.y + v.z * v.z + v.w * v.w;
#pragma unroll
    for (int off = 32; off; off >>= 1) ss += __shfl_down(ss, off);
    __shared__ float partial[4];
    __shared__ float s_inv;
    if ((tid & 63) == 0) partial[tid >> 6] = ss;
    __syncthreads();
    if (tid == 0)
        s_inv = rsqrtf((partial[0] + partial[1] + partial[2] + partial[3]) * (1.0f / H) + EPS);
    __syncthreads();
    float inv = s_inv;
    float4 wv = ((const float4*)w)[tid];
    float4 o;
    o.x = v.x * wv.x * inv; o.y = v.y * wv.y * inv;
    o.z = v.z * wv.z * inv; o.w = v.w * wv.w * inv;
    ((float4*)(out + (size_t)t * H))[tid] = o;
}

// ---------------- f32 GEMM: C[M,N] = A[M,K] @ W[K,N] + bias (+resid) ----------------
constexpr int BM = 64, BN = 64, BK = 16;
__global__ __launch_bounds__(256) void gemm_kernel(const float* __restrict__ A,
                                                   const float* __restrict__ Wm,
                                                   const float* __restrict__ bias,
                                                   const float* __restrict__ resid,
                                                   float* __restrict__ C,
                                                   int M, int N, int K) {
    __shared__ float As[BM][BK + 1];   // +1 pad breaks bank aliasing on column reads
    __shared__ float Bs[BK][BN];
    int tid = threadIdx.x;
    int bm = blockIdx.y * BM;
    int bn = blockIdx.x * BN;
    int ty = tid >> 4, tx = tid & 15;
    int r0 = ty * 4, c0 = tx * 4;
    float acc[4][4] = {};
    for (int k0 = 0; k0 < K; k0 += BK) {
#pragma unroll
        for (int i = 0; i < 4; i++) {
            int idx = tid + i * 256;
            int ar = idx >> 4, ak = idx & 15;
            As[ar][ak] = A[(size_t)(bm + ar) * K + k0 + ak];
        }
#pragma unroll
        for (int i = 0; i < 4; i++) {
            int idx = tid + i * 256;
            int br = idx >> 6, bc = idx & 63;
            Bs[br][bc] = Wm[(size_t)(k0 + br) * N + bn + bc];
        }
        __syncthreads();
#pragma unroll
        for (int kk = 0; kk < BK; kk++) {
            float a[4], bv[4];
#pragma unroll
            for (int i = 0; i < 4; i++) a[i] = As[r0 + i][kk];
#pragma unroll
            for (int j = 0; j < 4; j++) bv[j] = Bs[kk][c0 + j];
#pragma unroll
            for (int i = 0; i < 4; i++)
#pragma unroll
                for (int j = 0; j < 4; j++) acc[i][j] += a[i] * bv[j];
        }
        __syncthreads();
    }
#pragma unroll
    for (int i = 0; i < 4; i++) {
        int row = bm + r0 + i;
#pragma unroll
        for (int j = 0; j < 4; j++) {
            int col = bn + c0 + j;
            float v = acc[i][j] + bias[col];
            if (resid) v += resid[(size_t)row * N + col];
            C[(size_t)row * N + col] = v;
        }
    }
}

// ---------------- Attention: one block per (b, q, head); exactly 128 keys in window ----------------
__global__ __launch_bounds__(128) void attn_kernel(const float* __restrict__ qkv,
                                                   const float* __restrict__ kv_cache,
                                                   const int* __restrict__ page_idx,
                                                   const float* __restrict__ sinks,
                                                   float* __restrict__ attn_out) {
    int blk = blockIdx.x;
    int h = blk & 15;
    int q = (blk >> 4) & 127;
    int b = blk >> 11;
    int tid = threadIdx.x;      // 128
    int t = b * Q_ + q;
    int kvh = h >> 2;           // G = 4

    __shared__ __align__(16) float qs[HD];
    __shared__ float pv[128];
    __shared__ float wmax[2];
    __shared__ float wsum[2];

    if (tid < HD) qs[tid] = qkv[(size_t)t * QKV_N + h * HD + tid];
    __syncthreads();

    // valid keys: s in [769+q, 896+q]  (window 128, causal)
    int s_lo = S_ - Q_ - 127 + q;   // 769+q
    int s = s_lo + tid;
    const float* kp;
    if (s < S_ - Q_) {
        int page = page_idx[b * P_ + (s >> 7)];
        kp = kv_cache + (size_t)page * 65536 + (size_t)(s & 127) * (NKV * HD) + kvh * HD;
    } else {
        kp = qkv + (size_t)(b * Q_ + (s - (S_ - Q_))) * QKV_N + NQ * HD + kvh * HD;
    }
    float sc = 0.f;
    const float4* kp4 = (const float4*)kp;
    const float4* qs4 = (const float4*)qs;
#pragma unroll
    for (int d = 0; d < HD / 4; d++) {
        float4 kk = kp4[d], qq = qs4[d];
        sc += qq.x * kk.x + qq.y * kk.y + qq.z * kk.z + qq.w * kk.w;
    }
    sc *= SCALE;

    float m = sc;
#pragma unroll
    for (int off = 32; off; off >>= 1) m = fmaxf(m, __shfl_down(m, off));
    if ((tid & 63) == 0) wmax[tid >> 6] = m;
    __syncthreads();
    float mm = fmaxf(wmax[0], wmax[1]);

    float p = __expf(sc - mm);
    pv[tid] = p;
    float l = p;
#pragma unroll
    for (int off = 32; off; off >>= 1) l += __shfl_down(l, off);
    if ((tid & 63) == 0) wsum[tid >> 6] = l;
    __syncthreads();
    float denom = wsum[0] + wsum[1] + __expf(sinks[h] - mm);

    if (tid < HD) {
        float acc = 0.f;
        for (int i = 0; i < 128; i++) {
            int s2 = s_lo + i;
            const float* vp;
            if (s2 < S_ - Q_) {
                int page = page_idx[b * P_ + (s2 >> 7)];
                vp = kv_cache + (size_t)page * 65536 + 32768 + (size_t)(s2 & 127) * (NKV * HD) + kvh * HD;
            } else {
                vp = qkv + (size_t)(b * Q_ + (s2 - (S_ - Q_))) * QKV_N + (NQ + NKV) * HD + kvh * HD;
            }
            acc += pv[i] * vp[tid];
        }
        attn_out[(size_t)t * (NQ * HD) + h * HD + tid] = acc / denom;
    }
}

// ---------------- Router: logits, top-2, softmax weights ----------------
__global__ __launch_bounds__(256) void router_kernel(const float* __restrict__ x2,
                                                     const float* __restrict__ w_router,
                                                     const float* __restrict__ b_router,
                                                     int* __restrict__ ridx,
                                                     float* __restrict__ rwt) {
    int t = blockIdx.x;
    int tid = threadIdx.x;
    int e = tid >> 5;       // 0..7
    int j = tid & 31;
    float acc = 0.f;
    for (int hh = j; hh < H; hh += 32) acc += x2[(size_t)t * H + hh] * w_router[hh * E_ + e];
#pragma unroll
    for (int off = 16; off; off >>= 1) acc += __shfl_down(acc, off);
    __shared__ float logits[E_];
    if (j == 0) logits[e] = acc + b_router[e];
    __syncthreads();
    if (tid == 0) {
        int i0 = 0; float v0 = logits[0];
        for (int ee = 1; ee < E_; ee++)
            if (logits[ee] > v0) { v0 = logits[ee]; i0 = ee; }
        int i1 = -1; float v1 = -3.4e38f;
        for (int ee = 0; ee < E_; ee++)
            if (ee != i0 && logits[ee] > v1) { v1 = logits[ee]; i1 = ee; }
        float w0 = 1.0f / (1.0f + __expf(v1 - v0));
        ridx[t * 2] = i0; ridx[t * 2 + 1] = i1;
        rwt[t * 2] = w0;  rwt[t * 2 + 1] = 1.0f - w0;
    }
}

// ---------------- MoE: one block per (token, k) — gate/up, swiglu, down ----------------
__global__ __launch_bounds__(256) void moe_kernel(const float* __restrict__ x2,
                                                  const int* __restrict__ ridx,
                                                  const float* __restrict__ rwt,
                                                  const float* __restrict__ w_gate_up,
                                                  const float* __restrict__ b_gate_up,
                                                  const float* __restrict__ w_down,
                                                  const float* __restrict__ b_down,
                                                  float* __restrict__ part) {
    int blk = blockIdx.x;       // 0 .. 2T-1
    int t = blk >> 1;
    int k = blk & 1;
    int tid = threadIdx.x;
    __shared__ __align__(16) float xs[H];
    __shared__ __align__(16) float act[FFN];
    ((float4*)xs)[tid] = ((const float4*)(x2 + (size_t)t * H))[tid];
    int e = ridx[t * 2 + k];
    float wgt = rwt[t * 2 + k];
    __syncthreads();

    const float* wg = w_gate_up + (size_t)e * H * 2 * FFN;
    float g0 = 0, u0 = 0, g1 = 0, u1 = 0, g2 = 0, u2 = 0, g3 = 0, u3 = 0;
    for (int hh = 0; hh < H; hh++) {
        float xv = xs[hh];
        const float4* row4 = (const float4*)(wg + (size_t)hh * 2 * FFN);
        float4 w0 = row4[tid];
        float4 w1 = row4[tid + 256];
        g0 += xv * w0.x; u0 += xv * w0.y; g1 += xv * w0.z; u1 += xv * w0.w;
        g2 += xv * w1.x; u2 += xv * w1.y; g3 += xv * w1.z; u3 += xv * w1.w;
    }
    float gg[4] = { g0, g1, g2, g3 };
    float uu[4] = { u0, u1, u2, u3 };
    int jb[4] = { 2 * tid, 2 * tid + 1, 2 * tid + 512, 2 * tid + 513 };
#pragma unroll
    for (int jj = 0; jj < 4; jj++) {
        int j = jb[jj];
        float gate = gg[jj] + b_gate_up[e * 2 * FFN + 2 * j];
        float up   = uu[jj] + b_gate_up[e * 2 * FFN + 2 * j + 1];
        gate = fminf(gate, LIMIT);
        up = fminf(fmaxf(up, -LIMIT), LIMIT);
        float glu = gate / (1.0f + __expf(-ALPHA * gate));
        act[j] = (up + 1.0f) * glu;
    }
    __syncthreads();

    const float* wd = w_down + (size_t)e * FFN * H;
    float4 dacc = make_float4(0.f, 0.f, 0.f, 0.f);
    for (int f = 0; f < FFN; f++) {
        float av = act[f];
        float4 wv = ((const float4*)(wd + (size_t)f * H))[tid];
        dacc.x += av * wv.x; dacc.y += av * wv.y;
        dacc.z += av * wv.z; dacc.w += av * wv.w;
    }
    const float* bd = b_down + e * H + 4 * tid;
    float4 o;
    o.x = wgt * (dacc.x + bd[0]);
    o.y = wgt * (dacc.y + bd[1]);
    o.z = wgt * (dacc.z + bd[2]);
    o.w = wgt * (dacc.w + bd[3]);
    ((float4*)(part + ((size_t)t * 2 + k) * H))[tid] = o;
}

// ---------------- out = h + part0 + part1 ----------------
__global__ __launch_bounds__(256) void final_add_kernel(const float* __restrict__ hbuf,
                                                        const float* __restrict__ part,
                                                        float* __restrict__ out) {
    int t = blockIdx.x;
    int tid = threadIdx.x;
    float4 a  = ((const float4*)(hbuf + (size_t)t * H))[tid];
    float4 p0 = ((const float4*)(part + (size_t)(t * 2) * H))[tid];
    float4 p1 = ((const float4*)(part + (size_t)(t * 2 + 1) * H))[tid];
    float4 o;
    o.x = a.x + p0.x + p1.x; o.y = a.y + p0.y + p1.y;
    o.z = a.z + p0.z + p1.z; o.w = a.w + p0.w + p1.w;
    ((float4*)(out + (size_t)t * H))[tid] = o;
}

extern "C" void kernel_launch(void* const* d_in, const int* in_sizes, int n_in,
                              void* d_out, int out_size, void* d_ws, size_t ws_size,
                              hipStream_t stream) {
    const float* hidden          = (const float*)d_in[0];
    const float* kv_cache        = (const float*)d_in[1];
    // d_in[2] attention_mask: pure causal — applied analytically (exact: exp(-1e30-m)==0 in f32)
    const int*   kv_page_indices = (const int*)d_in[3];
    const float* sinks           = (const float*)d_in[4];
    const float* w_qkv           = (const float*)d_in[5];
    const float* b_qkv           = (const float*)d_in[6];
    const float* w_o             = (const float*)d_in[7];
    const float* b_o             = (const float*)d_in[8];
    const float* ln1_w           = (const float*)d_in[9];
    const float* ln2_w           = (const float*)d_in[10];
    const float* w_router        = (const float*)d_in[11];
    const float* b_router        = (const float*)d_in[12];
    const float* w_gate_up       = (const float*)d_in[13];
    const float* b_gate_up       = (const float*)d_in[14];
    const float* w_down          = (const float*)d_in[15];
    const float* b_down          = (const float*)d_in[16];
    float* out = (float*)d_out;

    float* ws   = (float*)d_ws;
    float* x    = ws;  ws += (size_t)T_ * H;        // rmsnorm1 out
    float* qkv  = ws;  ws += (size_t)T_ * QKV_N;    // qkv projection
    float* attn = ws;  ws += (size_t)T_ * NQ * HD;  // attention out
    float* hbuf = ws;  ws += (size_t)T_ * H;        // post-attn residual
    float* x2   = ws;  ws += (size_t)T_ * H;        // rmsnorm2 out
    float* part = ws;  ws += (size_t)T_ * 2 * H;    // per-(t,k) expert contributions
    int*   ridx = (int*)ws;  ws += T_ * 2;
    float* rwt  = ws;  ws += T_ * 2;

    rmsnorm_kernel<<<T_, 256, 0, stream>>>(hidden, ln1_w, x);
    gemm_kernel<<<dim3(QKV_N / BN, T_ / BM), 256, 0, stream>>>(x, w_qkv, b_qkv, nullptr, qkv,
                                                               T_, QKV_N, H);
    attn_kernel<<<B_ * Q_ * NQ, 128, 0, stream>>>(qkv, kv_cache, kv_page_indices, sinks, attn);
    gemm_kernel<<<dim3(H / BN, T_ / BM), 256, 0, stream>>>(attn, w_o, b_o, hidden, hbuf,
                                                           T_, H, NQ * HD);
    rmsnorm_kernel<<<T_, 256, 0, stream>>>(hbuf, ln2_w, x2);
    router_kernel<<<T_, 256, 0, stream>>>(x2, w_router, b_router, ridx, rwt);
    moe_kernel<<<T_ * 2, 256, 0, stream>>>(x2, ridx, rwt, w_gate_up, b_gate_up, w_down, b_down, part);
    final_add_kernel<<<T_, 256, 0, stream>>>(hbuf, part, out);
}

// Round 2
// 791.072 us; speedup vs baseline: 1.6817x; 1.6817x over previous
//
#include <hip/hip_runtime.h>

// ---- static config (mirrors reference) ----
constexpr int H    = 1024;
constexpr int HD   = 64;
constexpr int NQ   = 16;
constexpr int NKV  = 4;
constexpr int E_   = 8;
constexpr int FFN  = 1024;
constexpr int B_   = 4;
constexpr int Q_   = 128;
constexpr int P_   = 8;
constexpr int PS   = 128;
constexpr int S_   = P_ * PS;                 // 1024
constexpr int T_   = B_ * Q_;                 // 512
constexpr int QKV_N = HD * (NQ + 2 * NKV);    // 1536
constexpr float EPS   = 1e-5f;
constexpr float ALPHA = 1.702f;
constexpr float LIMIT = 7.0f;
constexpr float SCALE = 0.125f;               // HD^-0.5

constexpr int MAXROWS = 1536;                 // 1024 assignments + per-expert pad to 64

// ---------------- RMSNorm: one block per token ----------------
__global__ __launch_bounds__(256) void rmsnorm_kernel(const float* __restrict__ in,
                                                      const float* __restrict__ w,
                                                      float* __restrict__ out) {
    int t   = blockIdx.x;
    int tid = threadIdx.x;
    const float4* in4 = (const float4*)(in + (size_t)t * H);
    float4 v = in4[tid];
    float ss = v.x * v.x + v.y * v.y + v.z * v.z + v.w * v.w;
#pragma unroll
    for (int off = 32; off; off >>= 1) ss += __shfl_down(ss, off);
    __shared__ float partial[4];
    __shared__ float s_inv;
    if ((tid & 63) == 0) partial[tid >> 6] = ss;
    __syncthreads();
    if (tid == 0)
        s_inv = rsqrtf((partial[0] + partial[1] + partial[2] + partial[3]) * (1.0f / H) + EPS);
    __syncthreads();
    float inv = s_inv;
    float4 wv = ((const float4*)w)[tid];
    float4 o;
    o.x = v.x * wv.x * inv; o.y = v.y * wv.y * inv;
    o.z = v.z * wv.z * inv; o.w = v.w * wv.w * inv;
    ((float4*)(out + (size_t)t * H))[tid] = o;
}

// ---------------- f32 GEMM: C[M,N] = A[M,K] @ W[K,N] + bias (+resid) ----------------
constexpr int BM = 64, BN = 64, BK = 16;
__global__ __launch_bounds__(256) void gemm_kernel(const float* __restrict__ A,
                                                   const float* __restrict__ Wm,
                                                   const float* __restrict__ bias,
                                                   const float* __restrict__ resid,
                                                   float* __restrict__ C,
                                                   int M, int N, int K) {
    __shared__ float As[BM][BK + 1];
    __shared__ float Bs[BK][BN];
    int tid = threadIdx.x;
    int bm = blockIdx.y * BM;
    int bn = blockIdx.x * BN;
    int ty = tid >> 4, tx = tid & 15;
    int r0 = ty * 4, c0 = tx * 4;
    float acc[4][4] = {};
    for (int k0 = 0; k0 < K; k0 += BK) {
#pragma unroll
        for (int i = 0; i < 4; i++) {
            int idx = tid + i * 256;
            int ar = idx >> 4, ak = idx & 15;
            As[ar][ak] = A[(size_t)(bm + ar) * K + k0 + ak];
        }
#pragma unroll
        for (int i = 0; i < 4; i++) {
            int idx = tid + i * 256;
            int br = idx >> 6, bc = idx & 63;
            Bs[br][bc] = Wm[(size_t)(k0 + br) * N + bn + bc];
        }
        __syncthreads();
#pragma unroll
        for (int kk = 0; kk < BK; kk++) {
            float a[4], bv[4];
#pragma unroll
            for (int i = 0; i < 4; i++) a[i] = As[r0 + i][kk];
#pragma unroll
            for (int j = 0; j < 4; j++) bv[j] = Bs[kk][c0 + j];
#pragma unroll
            for (int i = 0; i < 4; i++)
#pragma unroll
                for (int j = 0; j < 4; j++) acc[i][j] += a[i] * bv[j];
        }
        __syncthreads();
    }
#pragma unroll
    for (int i = 0; i < 4; i++) {
        int row = bm + r0 + i;
#pragma unroll
        for (int j = 0; j < 4; j++) {
            int col = bn + c0 + j;
            float v = acc[i][j] + bias[col];
            if (resid) v += resid[(size_t)row * N + col];
            C[(size_t)row * N + col] = v;
        }
    }
}

// ---------------- Attention: one block per (b, q, head); exactly 128 keys in window ----------------
__global__ __launch_bounds__(128) void attn_kernel(const float* __restrict__ qkv,
                                                   const float* __restrict__ kv_cache,
                                                   const int* __restrict__ page_idx,
                                                   const float* __restrict__ sinks,
                                                   float* __restrict__ attn_out) {
    int blk = blockIdx.x;
    int h = blk & 15;
    int q = (blk >> 4) & 127;
    int b = blk >> 11;
    int tid = threadIdx.x;      // 128
    int t = b * Q_ + q;
    int kvh = h >> 2;           // G = 4

    __shared__ __align__(16) float qs[HD];
    __shared__ float pv[128];
    __shared__ float wmax[2];
    __shared__ float wsum[2];

    if (tid < HD) qs[tid] = qkv[(size_t)t * QKV_N + h * HD + tid];
    __syncthreads();

    int s_lo = S_ - Q_ - 127 + q;   // 769+q
    int s = s_lo + tid;
    const float* kp;
    if (s < S_ - Q_) {
        int page = page_idx[b * P_ + (s >> 7)];
        kp = kv_cache + (size_t)page * 65536 + (size_t)(s & 127) * (NKV * HD) + kvh * HD;
    } else {
        kp = qkv + (size_t)(b * Q_ + (s - (S_ - Q_))) * QKV_N + NQ * HD + kvh * HD;
    }
    float sc = 0.f;
    const float4* kp4 = (const float4*)kp;
    const float4* qs4 = (const float4*)qs;
#pragma unroll
    for (int d = 0; d < HD / 4; d++) {
        float4 kk = kp4[d], qq = qs4[d];
        sc += qq.x * kk.x + qq.y * kk.y + qq.z * kk.z + qq.w * kk.w;
    }
    sc *= SCALE;

    float m = sc;
#pragma unroll
    for (int off = 32; off; off >>= 1) m = fmaxf(m, __shfl_down(m, off));
    if ((tid & 63) == 0) wmax[tid >> 6] = m;
    __syncthreads();
    float mm = fmaxf(wmax[0], wmax[1]);

    float p = __expf(sc - mm);
    pv[tid] = p;
    float l = p;
#pragma unroll
    for (int off = 32; off; off >>= 1) l += __shfl_down(l, off);
    if ((tid & 63) == 0) wsum[tid >> 6] = l;
    __syncthreads();
    float denom = wsum[0] + wsum[1] + __expf(sinks[h] - mm);

    if (tid < HD) {
        float acc = 0.f;
        for (int i = 0; i < 128; i++) {
            int s2 = s_lo + i;
            const float* vp;
            if (s2 < S_ - Q_) {
                int page = page_idx[b * P_ + (s2 >> 7)];
                vp = kv_cache + (size_t)page * 65536 + 32768 + (size_t)(s2 & 127) * (NKV * HD) + kvh * HD;
            } else {
                vp = qkv + (size_t)(b * Q_ + (s2 - (S_ - Q_))) * QKV_N + (NQ + NKV) * HD + kvh * HD;
            }
            acc += pv[i] * vp[tid];
        }
        attn_out[(size_t)t * (NQ * HD) + h * HD + tid] = acc / denom;
    }
}

// ---------------- MoE routing plumbing ----------------
__global__ __launch_bounds__(64) void moe_zero_kernel(int* __restrict__ cnt, int* __restrict__ pos) {
    if (threadIdx.x < E_) { cnt[threadIdx.x] = 0; pos[threadIdx.x] = 0; }
}

// Router: logits, top-2, softmax weights; also histogram experts
__global__ __launch_bounds__(256) void router_kernel(const float* __restrict__ x2,
                                                     const float* __restrict__ w_router,
                                                     const float* __restrict__ b_router,
                                                     int* __restrict__ ridx,
                                                     float* __restrict__ rwt,
                                                     int* __restrict__ cnt) {
    int t = blockIdx.x;
    int tid = threadIdx.x;
    int e = tid >> 5;       // 0..7
    int j = tid & 31;
    float acc = 0.f;
    for (int hh = j; hh < H; hh += 32) acc += x2[(size_t)t * H + hh] * w_router[hh * E_ + e];
#pragma unroll
    for (int off = 16; off; off >>= 1) acc += __shfl_down(acc, off);
    __shared__ float logits[E_];
    if (j == 0) logits[e] = acc + b_router[e];
    __syncthreads();
    if (tid == 0) {
        int i0 = 0; float v0 = logits[0];
        for (int ee = 1; ee < E_; ee++)
            if (logits[ee] > v0) { v0 = logits[ee]; i0 = ee; }
        int i1 = -1; float v1 = -3.4e38f;
        for (int ee = 0; ee < E_; ee++)
            if (ee != i0 && logits[ee] > v1) { v1 = logits[ee]; i1 = ee; }
        float w0 = 1.0f / (1.0f + __expf(v1 - v0));
        ridx[t * 2] = i0; ridx[t * 2 + 1] = i1;
        rwt[t * 2] = w0;  rwt[t * 2 + 1] = 1.0f - w0;
        atomicAdd(&cnt[i0], 1);
        atomicAdd(&cnt[i1], 1);
    }
}

__global__ __launch_bounds__(64) void moe_offsets_kernel(const int* __restrict__ cnt,
                                                         int* __restrict__ poff) {
    if (threadIdx.x == 0) {
        int run = 0;
        for (int e = 0; e < E_; e++) { poff[e] = run; run += (cnt[e] + 63) & ~63; }
    }
}

__global__ __launch_bounds__(256) void moe_scatter_kernel(const int* __restrict__ ridx,
                                                          int* __restrict__ pos,
                                                          const int* __restrict__ poff,
                                                          int* __restrict__ list) {
    int i = blockIdx.x * 256 + threadIdx.x;   // 0 .. 2T-1
    if (i < 2 * T_) {
        int e = ridx[i];
        int p = atomicAdd(&pos[e], 1);
        list[poff[e] + p] = i;                // i = t*2 + k
    }
}

// ---------------- Grouped gate_up GEMM + swiglu -> act[slot, FFN] ----------------
// grid: x = 2*FFN/128 = 16 (64 act cols per block), y = E*16 (row tiles of 64)
__global__ __launch_bounds__(256) void moe_gateup_kernel(const float* __restrict__ x2,
                                                         const int* __restrict__ list,
                                                         const int* __restrict__ cnt,
                                                         const int* __restrict__ poff,
                                                         const float* __restrict__ w_gate_up,
                                                         const float* __restrict__ b_gate_up,
                                                         float* __restrict__ act) {
    int e  = blockIdx.y >> 4;
    int tl = blockIdx.y & 15;
    int n  = cnt[e];
    if (tl * 64 >= n) return;
    int base = poff[e];
    int bn = blockIdx.x * 64;                 // act-col base (gu col base = 2*bn)

    __shared__ float As[BK][68];              // [k][m], stride 68 keeps b128 aligned + banks clean
    __shared__ float Wg[BK][68];
    __shared__ float Wu[BK][68];

    int tid = threadIdx.x;
    int ty = tid >> 4, tx = tid & 15;
    int r0 = ty * 4, c0 = tx * 4;

    // staging coords
    int ar = tid >> 2;                        // 0..63 row within tile
    int aq = (tid & 3) * 4;                   // k quad
    int row = tl * 64 + ar;
    int t2 = (row < n) ? list[base + row] : -1;
    const float* arow = (t2 >= 0) ? x2 + (size_t)(t2 >> 1) * H : x2;
    int wr = tid >> 4;                        // 0..15 k row
    int wc8 = (tid & 15) * 8;                 // 8 interleaved gu cols
    int wc4 = wc8 >> 1;
    const float* wbase = w_gate_up + (size_t)e * H * 2 * FFN + 2 * bn + wc8;

    float accg[4][4] = {}, accu[4][4] = {};
    for (int k0 = 0; k0 < H; k0 += BK) {
        float4 av = make_float4(0.f, 0.f, 0.f, 0.f);
        if (t2 >= 0) av = *(const float4*)(arow + k0 + aq);
        As[aq + 0][ar] = av.x; As[aq + 1][ar] = av.y;
        As[aq + 2][ar] = av.z; As[aq + 3][ar] = av.w;
        const float4* wp = (const float4*)(wbase + (size_t)(k0 + wr) * 2 * FFN);
        float4 w0 = wp[0], w1 = wp[1];
        Wg[wr][wc4 + 0] = w0.x; Wu[wr][wc4 + 0] = w0.y;
        Wg[wr][wc4 + 1] = w0.z; Wu[wr][wc4 + 1] = w0.w;
        Wg[wr][wc4 + 2] = w1.x; Wu[wr][wc4 + 2] = w1.y;
        Wg[wr][wc4 + 3] = w1.z; Wu[wr][wc4 + 3] = w1.w;
        __syncthreads();
#pragma unroll
        for (int kk = 0; kk < BK; kk++) {
            float4 a = *(const float4*)&As[kk][r0];
            float4 g = *(const float4*)&Wg[kk][c0];
            float4 u = *(const float4*)&Wu[kk][c0];
            float av4[4] = { a.x, a.y, a.z, a.w };
#pragma unroll
            for (int i = 0; i < 4; i++) {
                accg[i][0] += av4[i] * g.x; accg[i][1] += av4[i] * g.y;
                accg[i][2] += av4[i] * g.z; accg[i][3] += av4[i] * g.w;
                accu[i][0] += av4[i] * u.x; accu[i][1] += av4[i] * u.y;
                accu[i][2] += av4[i] * u.z; accu[i][3] += av4[i] * u.w;
            }
        }
        __syncthreads();
    }
#pragma unroll
    for (int i = 0; i < 4; i++) {
        int r = tl * 64 + r0 + i;
        int slot = base + r;
        if (r < n) {
#pragma unroll
            for (int j = 0; j < 4; j++) {
                int colA = bn + c0 + j;
                float gate = accg[i][j] + b_gate_up[(size_t)e * 2 * FFN + 2 * colA];
                float up   = accu[i][j] + b_gate_up[(size_t)e * 2 * FFN + 2 * colA + 1];
                gate = fminf(gate, LIMIT);
                up = fminf(fmaxf(up, -LIMIT), LIMIT);
                float glu = gate / (1.0f + __expf(-ALPHA * gate));
                act[(size_t)slot * FFN + colA] = (up + 1.0f) * glu;
            }
        } else {
#pragma unroll
            for (int j = 0; j < 4; j++)
                act[(size_t)slot * FFN + bn + c0 + j] = 0.f;
        }
    }
}

// ---------------- Grouped down GEMM: part[t2, H] = wgt*(act @ w_down[e] + b_down[e]) ----------------
// grid: x = H/64 = 16, y = E*16
__global__ __launch_bounds__(256) void moe_down_kernel(const float* __restrict__ act,
                                                       const int* __restrict__ list,
                                                       const int* __restrict__ cnt,
                                                       const int* __restrict__ poff,
                                                       const float* __restrict__ rwt,
                                                       const float* __restrict__ w_down,
                                                       const float* __restrict__ b_down,
                                                       float* __restrict__ part) {
    int e  = blockIdx.y >> 4;
    int tl = blockIdx.y & 15;
    int n  = cnt[e];
    if (tl * 64 >= n) return;
    int base = poff[e];
    int bn = blockIdx.x * 64;

    __shared__ float As[BK][68];
    __shared__ float Ws[BK][68];

    int tid = threadIdx.x;
    int ty = tid >> 4, tx = tid & 15;
    int r0 = ty * 4, c0 = tx * 4;

    int ar = tid >> 2;
    int aq = (tid & 3) * 4;
    const float* arow = act + (size_t)(base + tl * 64 + ar) * FFN;
    int wr = tid >> 4;
    int wc = (tid & 15) * 4;
    const float* wbase = w_down + (size_t)e * FFN * H + bn + wc;

    float acc[4][4] = {};
    for (int k0 = 0; k0 < FFN; k0 += BK) {
        float4 av = *(const float4*)(arow + k0 + aq);
        As[aq + 0][ar] = av.x; As[aq + 1][ar] = av.y;
        As[aq + 2][ar] = av.z; As[aq + 3][ar] = av.w;
        float4 wv = *(const float4*)(wbase + (size_t)(k0 + wr) * H);
        *(float4*)&Ws[wr][wc] = wv;
        __syncthreads();
#pragma unroll
        for (int kk = 0; kk < BK; kk++) {
            float4 a = *(const float4*)&As[kk][r0];
            float4 w = *(const float4*)&Ws[kk][c0];
            float av4[4] = { a.x, a.y, a.z, a.w };
#pragma unroll
            for (int i = 0; i < 4; i++) {
                acc[i][0] += av4[i] * w.x; acc[i][1] += av4[i] * w.y;
                acc[i][2] += av4[i] * w.z; acc[i][3] += av4[i] * w.w;
            }
        }
        __syncthreads();
    }
#pragma unroll
    for (int i = 0; i < 4; i++) {
        int r = tl * 64 + r0 + i;
        if (r < n) {
            int t2 = list[base + r];
            float wgt = rwt[t2];
#pragma unroll
            for (int j = 0; j < 4; j++) {
                int col = bn + c0 + j;
                part[(size_t)t2 * H + col] = wgt * (acc[i][j] + b_down[(size_t)e * H + col]);
            }
        }
    }
}

// ---------------- out = h + part0 + part1 ----------------
__global__ __launch_bounds__(256) void final_add_kernel(const float* __restrict__ hbuf,
                                                        const float* __restrict__ part,
                                                        float* __restrict__ out) {
    int t = blockIdx.x;
    int tid = threadIdx.x;
    float4 a  = ((const float4*)(hbuf + (size_t)t * H))[tid];
    float4 p0 = ((const float4*)(part + (size_t)(t * 2) * H))[tid];
    float4 p1 = ((const float4*)(part + (size_t)(t * 2 + 1) * H))[tid];
    float4 o;
    o.x = a.x + p0.x + p1.x; o.y = a.y + p0.y + p1.y;
    o.z = a.z + p0.z + p1.z; o.w = a.w + p0.w + p1.w;
    ((float4*)(out + (size_t)t * H))[tid] = o;
}

extern "C" void kernel_launch(void* const* d_in, const int* in_sizes, int n_in,
                              void* d_out, int out_size, void* d_ws, size_t ws_size,
                              hipStream_t stream) {
    const float* hidden          = (const float*)d_in[0];
    const float* kv_cache        = (const float*)d_in[1];
    const int*   kv_page_indices = (const int*)d_in[3];
    const float* sinks           = (const float*)d_in[4];
    const float* w_qkv           = (const float*)d_in[5];
    const float* b_qkv           = (const float*)d_in[6];
    const float* w_o             = (const float*)d_in[7];
    const float* b_o             = (const float*)d_in[8];
    const float* ln1_w           = (const float*)d_in[9];
    const float* ln2_w           = (const float*)d_in[10];
    const float* w_router        = (const float*)d_in[11];
    const float* b_router        = (const float*)d_in[12];
    const float* w_gate_up       = (const float*)d_in[13];
    const float* b_gate_up       = (const float*)d_in[14];
    const float* w_down          = (const float*)d_in[15];
    const float* b_down          = (const float*)d_in[16];
    float* out = (float*)d_out;

    // workspace layout; act (6 MB) reuses the x/qkv/attn region (7 MB), all dead by MoE time
    float* ws   = (float*)d_ws;
    float* x    = ws;                               // T*H
    float* qkv  = x + (size_t)T_ * H;               // T*QKV_N
    float* attn = qkv + (size_t)T_ * QKV_N;         // T*NQ*HD
    float* act  = ws;                               // MAXROWS*FFN (aliases x/qkv/attn)
    float* hbuf = attn + (size_t)T_ * NQ * HD;      // T*H
    float* x2   = hbuf + (size_t)T_ * H;            // T*H
    float* part = x2 + (size_t)T_ * H;              // 2*T*H
    float* rwt  = part + (size_t)2 * T_ * H;        // 2*T
    int*   ridx = (int*)(rwt + 2 * T_);             // 2*T
    int*   cnt  = ridx + 2 * T_;                    // E
    int*   pos  = cnt + E_;                         // E
    int*   poff = pos + E_;                         // E
    int*   list = poff + E_;                        // MAXROWS

    moe_zero_kernel<<<1, 64, 0, stream>>>(cnt, pos);
    rmsnorm_kernel<<<T_, 256, 0, stream>>>(hidden, ln1_w, x);
    gemm_kernel<<<dim3(QKV_N / BN, T_ / BM), 256, 0, stream>>>(x, w_qkv, b_qkv, nullptr, qkv,
                                                               T_, QKV_N, H);
    attn_kernel<<<B_ * Q_ * NQ, 128, 0, stream>>>(qkv, kv_cache, kv_page_indices, sinks, attn);
    gemm_kernel<<<dim3(H / BN, T_ / BM), 256, 0, stream>>>(attn, w_o, b_o, hidden, hbuf,
                                                           T_, H, NQ * HD);
    rmsnorm_kernel<<<T_, 256, 0, stream>>>(hbuf, ln2_w, x2);
    router_kernel<<<T_, 256, 0, stream>>>(x2, w_router, b_router, ridx, rwt, cnt);
    moe_offsets_kernel<<<1, 64, 0, stream>>>(cnt, poff);
    moe_scatter_kernel<<<(2 * T_ + 255) / 256, 256, 0, stream>>>(ridx, pos, poff, list);
    moe_gateup_kernel<<<dim3(2 * FFN / 128, E_ * 16), 256, 0, stream>>>(
        x2, list, cnt, poff, w_gate_up, b_gate_up, act);
    moe_down_kernel<<<dim3(H / 64, E_ * 16), 256, 0, stream>>>(
        act, list, cnt, poff, rwt, w_down, b_down, part);
    final_add_kernel<<<T_, 256, 0, stream>>>(hbuf, part, out);
}

// Round 3
// 520.838 us; speedup vs baseline: 2.5543x; 1.5188x over previous
//
#include <hip/hip_runtime.h>

// ---- static config (mirrors reference) ----
constexpr int H    = 1024;
constexpr int HD   = 64;
constexpr int NQ   = 16;
constexpr int NKV  = 4;
constexpr int E_   = 8;
constexpr int FFN  = 1024;
constexpr int B_   = 4;
constexpr int Q_   = 128;
constexpr int P_   = 8;
constexpr int PS   = 128;
constexpr int S_   = P_ * PS;                 // 1024
constexpr int T_   = B_ * Q_;                 // 512
constexpr int QKV_N = HD * (NQ + 2 * NKV);    // 1536
constexpr float EPS   = 1e-5f;
constexpr float ALPHA = 1.702f;
constexpr float LIMIT = 7.0f;
constexpr float SCALE = 0.125f;               // HD^-0.5

constexpr int MAXROWS = 1536;                 // 1024 assignments + per-expert pad to 64

typedef __attribute__((ext_vector_type(4))) float f32x4;
typedef __attribute__((ext_vector_type(8))) short s16x8;

// f32 -> bf16 bits, round-to-nearest-even
__device__ __forceinline__ short f2bf(float f) {
    unsigned u = __float_as_uint(f);
    u += 0x7FFFu + ((u >> 16) & 1u);
    return (short)(u >> 16);
}

// ---------------- RMSNorm: one block per token ----------------
__global__ __launch_bounds__(256) void rmsnorm_kernel(const float* __restrict__ in,
                                                      const float* __restrict__ w,
                                                      float* __restrict__ out) {
    int t   = blockIdx.x;
    int tid = threadIdx.x;
    const float4* in4 = (const float4*)(in + (size_t)t * H);
    float4 v = in4[tid];
    float ss = v.x * v.x + v.y * v.y + v.z * v.z + v.w * v.w;
#pragma unroll
    for (int off = 32; off; off >>= 1) ss += __shfl_down(ss, off);
    __shared__ float partial[4];
    __shared__ float s_inv;
    if ((tid & 63) == 0) partial[tid >> 6] = ss;
    __syncthreads();
    if (tid == 0)
        s_inv = rsqrtf((partial[0] + partial[1] + partial[2] + partial[3]) * (1.0f / H) + EPS);
    __syncthreads();
    float inv = s_inv;
    float4 wv = ((const float4*)w)[tid];
    float4 o;
    o.x = v.x * wv.x * inv; o.y = v.y * wv.y * inv;
    o.z = v.z * wv.z * inv; o.w = v.w * wv.w * inv;
    ((float4*)(out + (size_t)t * H))[tid] = o;
}

// ---------------- dense bf16-MFMA GEMM: C[512,N] = A[512,1024] @ W[1024,N] + bias (+resid)
// 64x64 tile, 4 waves; wave w computes 4 m-tiles x 1 n-tile (w) of 16x16 via mfma 16x16x32.
// LDS fragments stored lane-order: frag for lane l is one contiguous 16B read.
__global__ __launch_bounds__(256) void gemm_bf16_kernel(const float* __restrict__ A,
                                                        const float* __restrict__ Wm,
                                                        const float* __restrict__ bias,
                                                        const float* __restrict__ resid,
                                                        float* __restrict__ C, int N) {
    __shared__ s16x8 A_s[4][64];
    __shared__ s16x8 B_s[4][64];
    int tid = threadIdx.x;
    int wv = tid >> 6, lane = tid & 63;
    int bm = blockIdx.y * 64, bn = blockIdx.x * 64;
    int sm = tid & 63, skq = tid >> 6;       // staging: row/col index, k-quad
    int dl = (skq << 4) + (sm & 15);          // dest lane in fragment order
    int dt = sm >> 4;                         // dest tile
    const float* aptr = A + (size_t)(bm + sm) * 1024 + skq * 8;
    const float* bptr = Wm + (size_t)(skq * 8) * N + bn + sm;
    f32x4 acc[4] = {};
    for (int k0 = 0; k0 < 1024; k0 += 32) {
        float4 a0 = *(const float4*)(aptr + k0);
        float4 a1 = *(const float4*)(aptr + k0 + 4);
        float bv[8];
#pragma unroll
        for (int j = 0; j < 8; j++) bv[j] = bptr[(size_t)(k0 + j) * N];
        __syncthreads();
        s16x8 pa;
        pa[0] = f2bf(a0.x); pa[1] = f2bf(a0.y); pa[2] = f2bf(a0.z); pa[3] = f2bf(a0.w);
        pa[4] = f2bf(a1.x); pa[5] = f2bf(a1.y); pa[6] = f2bf(a1.z); pa[7] = f2bf(a1.w);
        A_s[dt][dl] = pa;
        s16x8 pb;
#pragma unroll
        for (int j = 0; j < 8; j++) pb[j] = f2bf(bv[j]);
        B_s[dt][dl] = pb;
        __syncthreads();
        s16x8 bf = B_s[wv][lane];
#pragma unroll
        for (int mt = 0; mt < 4; mt++)
            acc[mt] = __builtin_amdgcn_mfma_f32_16x16x32_bf16(A_s[mt][lane], bf, acc[mt], 0, 0, 0);
    }
    int col = bn + wv * 16 + (lane & 15);
    int rb = (lane >> 4) * 4;
    float bcol = bias[col];
#pragma unroll
    for (int mt = 0; mt < 4; mt++)
#pragma unroll
        for (int r = 0; r < 4; r++) {
            int row = bm + mt * 16 + rb + r;
            float v = acc[mt][r] + bcol;
            if (resid) v += resid[(size_t)row * N + col];
            C[(size_t)row * N + col] = v;
        }
}

// ---------------- Attention: one block per (b, q, head); exactly 128 keys in window ----------------
__global__ __launch_bounds__(128) void attn_kernel(const float* __restrict__ qkv,
                                                   const float* __restrict__ kv_cache,
                                                   const int* __restrict__ page_idx,
                                                   const float* __restrict__ sinks,
                                                   float* __restrict__ attn_out) {
    int blk = blockIdx.x;
    int h = blk & 15;
    int q = (blk >> 4) & 127;
    int b = blk >> 11;
    int tid = threadIdx.x;      // 128
    int t = b * Q_ + q;
    int kvh = h >> 2;           // G = 4

    __shared__ __align__(16) float qs[HD];
    __shared__ float pv[128];
    __shared__ float wmax[2];
    __shared__ float wsum[2];

    if (tid < HD) qs[tid] = qkv[(size_t)t * QKV_N + h * HD + tid];
    __syncthreads();

    int s_lo = S_ - Q_ - 127 + q;   // 769+q
    int s = s_lo + tid;
    const float* kp;
    if (s < S_ - Q_) {
        int page = page_idx[b * P_ + (s >> 7)];
        kp = kv_cache + (size_t)page * 65536 + (size_t)(s & 127) * (NKV * HD) + kvh * HD;
    } else {
        kp = qkv + (size_t)(b * Q_ + (s - (S_ - Q_))) * QKV_N + NQ * HD + kvh * HD;
    }
    float sc = 0.f;
    const float4* kp4 = (const float4*)kp;
    const float4* qs4 = (const float4*)qs;
#pragma unroll
    for (int d = 0; d < HD / 4; d++) {
        float4 kk = kp4[d], qq = qs4[d];
        sc += qq.x * kk.x + qq.y * kk.y + qq.z * kk.z + qq.w * kk.w;
    }
    sc *= SCALE;

    float m = sc;
#pragma unroll
    for (int off = 32; off; off >>= 1) m = fmaxf(m, __shfl_down(m, off));
    if ((tid & 63) == 0) wmax[tid >> 6] = m;
    __syncthreads();
    float mm = fmaxf(wmax[0], wmax[1]);

    float p = __expf(sc - mm);
    pv[tid] = p;
    float l = p;
#pragma unroll
    for (int off = 32; off; off >>= 1) l += __shfl_down(l, off);
    if ((tid & 63) == 0) wsum[tid >> 6] = l;
    __syncthreads();
    float denom = wsum[0] + wsum[1] + __expf(sinks[h] - mm);

    if (tid < HD) {
        float acc = 0.f;
        for (int i = 0; i < 128; i++) {
            int s2 = s_lo + i;
            const float* vp;
            if (s2 < S_ - Q_) {
                int page = page_idx[b * P_ + (s2 >> 7)];
                vp = kv_cache + (size_t)page * 65536 + 32768 + (size_t)(s2 & 127) * (NKV * HD) + kvh * HD;
            } else {
                vp = qkv + (size_t)(b * Q_ + (s2 - (S_ - Q_))) * QKV_N + (NQ + NKV) * HD + kvh * HD;
            }
            acc += pv[i] * vp[tid];
        }
        attn_out[(size_t)t * (NQ * HD) + h * HD + tid] = acc / denom;
    }
}

// ---------------- MoE routing plumbing ----------------
__global__ __launch_bounds__(64) void moe_zero_kernel(int* __restrict__ cnt, int* __restrict__ pos) {
    if (threadIdx.x < E_) { cnt[threadIdx.x] = 0; pos[threadIdx.x] = 0; }
}

__global__ __launch_bounds__(256) void router_kernel(const float* __restrict__ x2,
                                                     const float* __restrict__ w_router,
                                                     const float* __restrict__ b_router,
                                                     int* __restrict__ ridx,
                                                     float* __restrict__ rwt,
                                                     int* __restrict__ cnt) {
    int t = blockIdx.x;
    int tid = threadIdx.x;
    int e = tid >> 5;       // 0..7
    int j = tid & 31;
    float acc = 0.f;
    for (int hh = j; hh < H; hh += 32) acc += x2[(size_t)t * H + hh] * w_router[hh * E_ + e];
#pragma unroll
    for (int off = 16; off; off >>= 1) acc += __shfl_down(acc, off);
    __shared__ float logits[E_];
    if (j == 0) logits[e] = acc + b_router[e];
    __syncthreads();
    if (tid == 0) {
        int i0 = 0; float v0 = logits[0];
        for (int ee = 1; ee < E_; ee++)
            if (logits[ee] > v0) { v0 = logits[ee]; i0 = ee; }
        int i1 = -1; float v1 = -3.4e38f;
        for (int ee = 0; ee < E_; ee++)
            if (ee != i0 && logits[ee] > v1) { v1 = logits[ee]; i1 = ee; }
        float w0 = 1.0f / (1.0f + __expf(v1 - v0));
        ridx[t * 2] = i0; ridx[t * 2 + 1] = i1;
        rwt[t * 2] = w0;  rwt[t * 2 + 1] = 1.0f - w0;
        atomicAdd(&cnt[i0], 1);
        atomicAdd(&cnt[i1], 1);
    }
}

__global__ __launch_bounds__(64) void moe_offsets_kernel(const int* __restrict__ cnt,
                                                         int* __restrict__ poff) {
    if (threadIdx.x == 0) {
        int run = 0;
        for (int e = 0; e < E_; e++) { poff[e] = run; run += (cnt[e] + 63) & ~63; }
    }
}

__global__ __launch_bounds__(256) void moe_scatter_kernel(const int* __restrict__ ridx,
                                                          int* __restrict__ pos,
                                                          const int* __restrict__ poff,
                                                          int* __restrict__ list) {
    int i = blockIdx.x * 256 + threadIdx.x;   // 0 .. 2T-1
    if (i < 2 * T_) {
        int e = ridx[i];
        int p = atomicAdd(&pos[e], 1);
        list[poff[e] + p] = i;                // i = t*2 + k
    }
}

// ---------------- Grouped gate_up bf16-MFMA GEMM + swiglu -> act[slot, FFN] ----------------
// grid: x = FFN/64 = 16 (64 act cols/block), y = E*16 (row tiles of 64, early exit)
__global__ __launch_bounds__(256) void moe_gateup_mfma(const float* __restrict__ x2,
                                                       const int* __restrict__ list,
                                                       const int* __restrict__ cnt,
                                                       const int* __restrict__ poff,
                                                       const float* __restrict__ w_gate_up,
                                                       const float* __restrict__ b_gate_up,
                                                       float* __restrict__ act) {
    int e  = blockIdx.y >> 4;
    int tl = blockIdx.y & 15;
    int n  = cnt[e];
    if (tl * 64 >= n) return;
    int base = poff[e];
    int bn = blockIdx.x * 64;                 // act-col base

    __shared__ s16x8 A_s[4][64];
    __shared__ s16x8 Bg_s[4][64];
    __shared__ s16x8 Bu_s[4][64];

    int tid = threadIdx.x;
    int wv = tid >> 6, lane = tid & 63;
    int sm = tid & 63, skq = tid >> 6;
    int dl = (skq << 4) + (sm & 15);
    int dt = sm >> 4;
    int row = tl * 64 + sm;
    bool valid = row < n;
    int t2 = valid ? list[base + row] : 0;
    const float* aptr = x2 + (size_t)(t2 >> 1) * 1024 + skq * 8;
    const float* bptr = w_gate_up + (size_t)e * 1024 * 2048 + (size_t)(skq * 8) * 2048 + 2 * (bn + sm);

    f32x4 accg[4] = {}, accu[4] = {};
    for (int k0 = 0; k0 < 1024; k0 += 32) {
        float4 a0 = make_float4(0.f, 0.f, 0.f, 0.f), a1 = a0;
        if (valid) { a0 = *(const float4*)(aptr + k0); a1 = *(const float4*)(aptr + k0 + 4); }
        float2 gv[8];
#pragma unroll
        for (int j = 0; j < 8; j++) gv[j] = *(const float2*)(bptr + (size_t)(k0 + j) * 2048);
        __syncthreads();
        s16x8 pa;
        pa[0] = f2bf(a0.x); pa[1] = f2bf(a0.y); pa[2] = f2bf(a0.z); pa[3] = f2bf(a0.w);
        pa[4] = f2bf(a1.x); pa[5] = f2bf(a1.y); pa[6] = f2bf(a1.z); pa[7] = f2bf(a1.w);
        A_s[dt][dl] = pa;
        s16x8 pg, pu;
#pragma unroll
        for (int j = 0; j < 8; j++) { pg[j] = f2bf(gv[j].x); pu[j] = f2bf(gv[j].y); }
        Bg_s[dt][dl] = pg;
        Bu_s[dt][dl] = pu;
        __syncthreads();
        s16x8 bg = Bg_s[wv][lane];
        s16x8 bu = Bu_s[wv][lane];
#pragma unroll
        for (int mt = 0; mt < 4; mt++) {
            accg[mt] = __builtin_amdgcn_mfma_f32_16x16x32_bf16(A_s[mt][lane], bg, accg[mt], 0, 0, 0);
            accu[mt] = __builtin_amdgcn_mfma_f32_16x16x32_bf16(A_s[mt][lane], bu, accu[mt], 0, 0, 0);
        }
    }
    int col = bn + wv * 16 + (lane & 15);
    int rb = (lane >> 4) * 4;
    float bg_b = b_gate_up[(size_t)e * 2048 + 2 * col];
    float bu_b = b_gate_up[(size_t)e * 2048 + 2 * col + 1];
#pragma unroll
    for (int mt = 0; mt < 4; mt++)
#pragma unroll
        for (int r = 0; r < 4; r++) {
            int rr = tl * 64 + mt * 16 + rb + r;
            float av = 0.f;
            if (rr < n) {
                float gate = fminf(accg[mt][r] + bg_b, LIMIT);
                float up = fminf(fmaxf(accu[mt][r] + bu_b, -LIMIT), LIMIT);
                float glu = gate / (1.0f + __expf(-ALPHA * gate));
                av = (up + 1.0f) * glu;
            }
            act[(size_t)(base + rr) * FFN + col] = av;
        }
}

// ---------------- Grouped down bf16-MFMA GEMM: part[t2,H] = wgt*(act @ w_down[e] + b_down[e])
// grid: x = H/64 = 16, y = E*16
__global__ __launch_bounds__(256) void moe_down_mfma(const float* __restrict__ act,
                                                     const int* __restrict__ list,
                                                     const int* __restrict__ cnt,
                                                     const int* __restrict__ poff,
                                                     const float* __restrict__ rwt,
                                                     const float* __restrict__ w_down,
                                                     const float* __restrict__ b_down,
                                                     float* __restrict__ part) {
    int e  = blockIdx.y >> 4;
    int tl = blockIdx.y & 15;
    int n  = cnt[e];
    if (tl * 64 >= n) return;
    int base = poff[e];
    int bn = blockIdx.x * 64;

    __shared__ s16x8 A_s[4][64];
    __shared__ s16x8 B_s[4][64];

    int tid = threadIdx.x;
    int wv = tid >> 6, lane = tid & 63;
    int sm = tid & 63, skq = tid >> 6;
    int dl = (skq << 4) + (sm & 15);
    int dt = sm >> 4;
    const float* aptr = act + (size_t)(base + tl * 64 + sm) * 1024 + skq * 8;
    const float* bptr = w_down + (size_t)e * 1024 * 1024 + (size_t)(skq * 8) * 1024 + bn + sm;

    f32x4 acc[4] = {};
    for (int k0 = 0; k0 < 1024; k0 += 32) {
        float4 a0 = *(const float4*)(aptr + k0);
        float4 a1 = *(const float4*)(aptr + k0 + 4);
        float bv[8];
#pragma unroll
        for (int j = 0; j < 8; j++) bv[j] = bptr[(size_t)(k0 + j) * 1024];
        __syncthreads();
        s16x8 pa;
        pa[0] = f2bf(a0.x); pa[1] = f2bf(a0.y); pa[2] = f2bf(a0.z); pa[3] = f2bf(a0.w);
        pa[4] = f2bf(a1.x); pa[5] = f2bf(a1.y); pa[6] = f2bf(a1.z); pa[7] = f2bf(a1.w);
        A_s[dt][dl] = pa;
        s16x8 pb;
#pragma unroll
        for (int j = 0; j < 8; j++) pb[j] = f2bf(bv[j]);
        B_s[dt][dl] = pb;
        __syncthreads();
        s16x8 bf = B_s[wv][lane];
#pragma unroll
        for (int mt = 0; mt < 4; mt++)
            acc[mt] = __builtin_amdgcn_mfma_f32_16x16x32_bf16(A_s[mt][lane], bf, acc[mt], 0, 0, 0);
    }
    int col = bn + wv * 16 + (lane & 15);
    int rb = (lane >> 4) * 4;
    float bcol = b_down[(size_t)e * 1024 + col];
#pragma unroll
    for (int mt = 0; mt < 4; mt++)
#pragma unroll
        for (int r = 0; r < 4; r++) {
            int rr = tl * 64 + mt * 16 + rb + r;
            if (rr < n) {
                int t2 = list[base + rr];
                part[(size_t)t2 * H + col] = rwt[t2] * (acc[mt][r] + bcol);
            }
        }
}

// ---------------- out = h + part0 + part1 ----------------
__global__ __launch_bounds__(256) void final_add_kernel(const float* __restrict__ hbuf,
                                                        const float* __restrict__ part,
                                                        float* __restrict__ out) {
    int t = blockIdx.x;
    int tid = threadIdx.x;
    float4 a  = ((const float4*)(hbuf + (size_t)t * H))[tid];
    float4 p0 = ((const float4*)(part + (size_t)(t * 2) * H))[tid];
    float4 p1 = ((const float4*)(part + (size_t)(t * 2 + 1) * H))[tid];
    float4 o;
    o.x = a.x + p0.x + p1.x; o.y = a.y + p0.y + p1.y;
    o.z = a.z + p0.z + p1.z; o.w = a.w + p0.w + p1.w;
    ((float4*)(out + (size_t)t * H))[tid] = o;
}

extern "C" void kernel_launch(void* const* d_in, const int* in_sizes, int n_in,
                              void* d_out, int out_size, void* d_ws, size_t ws_size,
                              hipStream_t stream) {
    const float* hidden          = (const float*)d_in[0];
    const float* kv_cache        = (const float*)d_in[1];
    const int*   kv_page_indices = (const int*)d_in[3];
    const float* sinks           = (const float*)d_in[4];
    const float* w_qkv           = (const float*)d_in[5];
    const float* b_qkv           = (const float*)d_in[6];
    const float* w_o             = (const float*)d_in[7];
    const float* b_o             = (const float*)d_in[8];
    const float* ln1_w           = (const float*)d_in[9];
    const float* ln2_w           = (const float*)d_in[10];
    const float* w_router        = (const float*)d_in[11];
    const float* b_router        = (const float*)d_in[12];
    const float* w_gate_up       = (const float*)d_in[13];
    const float* b_gate_up       = (const float*)d_in[14];
    const float* w_down          = (const float*)d_in[15];
    const float* b_down          = (const float*)d_in[16];
    float* out = (float*)d_out;

    float* ws   = (float*)d_ws;
    float* x    = ws;                               // T*H
    float* qkv  = x + (size_t)T_ * H;               // T*QKV_N
    float* attn = qkv + (size_t)T_ * QKV_N;         // T*NQ*HD
    float* act  = ws;                               // MAXROWS*FFN (aliases x/qkv/attn, dead by MoE)
    float* hbuf = attn + (size_t)T_ * NQ * HD;      // T*H
    float* x2   = hbuf + (size_t)T_ * H;            // T*H
    float* part = x2 + (size_t)T_ * H;              // 2*T*H
    float* rwt  = part + (size_t)2 * T_ * H;        // 2*T
    int*   ridx = (int*)(rwt + 2 * T_);             // 2*T
    int*   cnt  = ridx + 2 * T_;                    // E
    int*   pos  = cnt + E_;                         // E
    int*   poff = pos + E_;                         // E
    int*   list = poff + E_;                        // MAXROWS

    moe_zero_kernel<<<1, 64, 0, stream>>>(cnt, pos);
    rmsnorm_kernel<<<T_, 256, 0, stream>>>(hidden, ln1_w, x);
    gemm_bf16_kernel<<<dim3(QKV_N / 64, T_ / 64), 256, 0, stream>>>(x, w_qkv, b_qkv, nullptr, qkv, QKV_N);
    attn_kernel<<<B_ * Q_ * NQ, 128, 0, stream>>>(qkv, kv_cache, kv_page_indices, sinks, attn);
    gemm_bf16_kernel<<<dim3(H / 64, T_ / 64), 256, 0, stream>>>(attn, w_o, b_o, hidden, hbuf, H);
    rmsnorm_kernel<<<T_, 256, 0, stream>>>(hbuf, ln2_w, x2);
    router_kernel<<<T_, 256, 0, stream>>>(x2, w_router, b_router, ridx, rwt, cnt);
    moe_offsets_kernel<<<1, 64, 0, stream>>>(cnt, poff);
    moe_scatter_kernel<<<(2 * T_ + 255) / 256, 256, 0, stream>>>(ridx, pos, poff, list);
    moe_gateup_mfma<<<dim3(FFN / 64, E_ * 16), 256, 0, stream>>>(
        x2, list, cnt, poff, w_gate_up, b_gate_up, act);
    moe_down_mfma<<<dim3(H / 64, E_ * 16), 256, 0, stream>>>(
        act, list, cnt, poff, rwt, w_down, b_down, part);
    final_add_kernel<<<T_, 256, 0, stream>>>(hbuf, part, out);
}

// Round 4
// 508.924 us; speedup vs baseline: 2.6140x; 1.0234x over previous
//
#include <hip/hip_runtime.h>

// ---- static config (mirrors reference) ----
constexpr int H    = 1024;
constexpr int HD   = 64;
constexpr int NQ   = 16;
constexpr int NKV  = 4;
constexpr int E_   = 8;
constexpr int FFN  = 1024;
constexpr int B_   = 4;
constexpr int Q_   = 128;
constexpr int P_   = 8;
constexpr int PS   = 128;
constexpr int S_   = P_ * PS;                 // 1024
constexpr int T_   = B_ * Q_;                 // 512
constexpr int QKV_N = HD * (NQ + 2 * NKV);    // 1536
constexpr float EPS   = 1e-5f;
constexpr float ALPHA = 1.702f;
constexpr float LIMIT = 7.0f;
constexpr float SCALE = 0.125f;               // HD^-0.5

constexpr int MAXROWS = 1536;                 // 1024 assignments + per-expert pad to 64

typedef __attribute__((ext_vector_type(4))) float f32x4;
typedef __attribute__((ext_vector_type(8))) short s16x8;

// f32 -> bf16 bits, round-to-nearest-even
__device__ __forceinline__ short f2bf(float f) {
    unsigned u = __float_as_uint(f);
    u += 0x7FFFu + ((u >> 16) & 1u);
    return (short)(u >> 16);
}

__device__ __forceinline__ s16x8 pack_a(float4 a0, float4 a1) {
    s16x8 p;
    p[0] = f2bf(a0.x); p[1] = f2bf(a0.y); p[2] = f2bf(a0.z); p[3] = f2bf(a0.w);
    p[4] = f2bf(a1.x); p[5] = f2bf(a1.y); p[6] = f2bf(a1.z); p[7] = f2bf(a1.w);
    return p;
}

// ---------------- RMSNorm: one block per token ----------------
__global__ __launch_bounds__(256) void rmsnorm_kernel(const float* __restrict__ in,
                                                      const float* __restrict__ w,
                                                      float* __restrict__ out) {
    int t   = blockIdx.x;
    int tid = threadIdx.x;
    const float4* in4 = (const float4*)(in + (size_t)t * H);
    float4 v = in4[tid];
    float ss = v.x * v.x + v.y * v.y + v.z * v.z + v.w * v.w;
#pragma unroll
    for (int off = 32; off; off >>= 1) ss += __shfl_down(ss, off);
    __shared__ float partial[4];
    __shared__ float s_inv;
    if ((tid & 63) == 0) partial[tid >> 6] = ss;
    __syncthreads();
    if (tid == 0)
        s_inv = rsqrtf((partial[0] + partial[1] + partial[2] + partial[3]) * (1.0f / H) + EPS);
    __syncthreads();
    float inv = s_inv;
    float4 wv = ((const float4*)w)[tid];
    float4 o;
    o.x = v.x * wv.x * inv; o.y = v.y * wv.y * inv;
    o.z = v.z * wv.z * inv; o.w = v.w * wv.w * inv;
    ((float4*)(out + (size_t)t * H))[tid] = o;
}

// ---------------- dense bf16-MFMA GEMM, double-buffered + prefetch ----------------
// C[512,N] = A[512,1024] @ W[1024,N] + bias (+resid). 64x64 tile, 4 waves.
__global__ __launch_bounds__(256) void gemm_bf16_kernel(const float* __restrict__ A,
                                                        const float* __restrict__ Wm,
                                                        const float* __restrict__ bias,
                                                        const float* __restrict__ resid,
                                                        float* __restrict__ C, int N) {
    __shared__ s16x8 A_s[2][4][64];
    __shared__ s16x8 B_s[2][4][64];
    int tid = threadIdx.x;
    int wv = tid >> 6, lane = tid & 63;
    int bm = blockIdx.y * 64, bn = blockIdx.x * 64;
    int sm = tid & 63, skq = tid >> 6;        // staging: row/col, k-quad
    int dl = (skq << 4) + (sm & 15);           // dest lane in fragment order
    int dt = sm >> 4;                          // dest tile
    const float* aptr = A + (size_t)(bm + sm) * 1024 + skq * 8;
    const float* bptr = Wm + (size_t)(skq * 8) * N + bn + sm;

    // prologue: stage k-block 0 into buffer 0
    {
        float4 a0 = *(const float4*)(aptr);
        float4 a1 = *(const float4*)(aptr + 4);
        float bv[8];
#pragma unroll
        for (int j = 0; j < 8; j++) bv[j] = bptr[(size_t)j * N];
        A_s[0][dt][dl] = pack_a(a0, a1);
        s16x8 pb;
#pragma unroll
        for (int j = 0; j < 8; j++) pb[j] = f2bf(bv[j]);
        B_s[0][dt][dl] = pb;
    }
    f32x4 acc[4] = {};
    for (int it = 0; it < 32; it++) {
        int cur = it & 1, nxt = cur ^ 1;
        float4 na0, na1; float nbv[8];
        if (it < 31) {
            int k0 = (it + 1) * 32;
            na0 = *(const float4*)(aptr + k0);
            na1 = *(const float4*)(aptr + k0 + 4);
#pragma unroll
            for (int j = 0; j < 8; j++) nbv[j] = bptr[(size_t)(k0 + j) * N];
        }
        __syncthreads();
        s16x8 bf = B_s[cur][wv][lane];
#pragma unroll
        for (int mt = 0; mt < 4; mt++)
            acc[mt] = __builtin_amdgcn_mfma_f32_16x16x32_bf16(A_s[cur][mt][lane], bf, acc[mt], 0, 0, 0);
        if (it < 31) {
            A_s[nxt][dt][dl] = pack_a(na0, na1);
            s16x8 pb;
#pragma unroll
            for (int j = 0; j < 8; j++) pb[j] = f2bf(nbv[j]);
            B_s[nxt][dt][dl] = pb;
        }
    }
    int col = bn + wv * 16 + (lane & 15);
    int rb = (lane >> 4) * 4;
    float bcol = bias[col];
#pragma unroll
    for (int mt = 0; mt < 4; mt++)
#pragma unroll
        for (int r = 0; r < 4; r++) {
            int row = bm + mt * 16 + rb + r;
            float v = acc[mt][r] + bcol;
            if (resid) v += resid[(size_t)row * N + col];
            C[(size_t)row * N + col] = v;
        }
}

// ---------------- Attention: one block per (b, q, head); exactly 128 keys in window ----------------
__global__ __launch_bounds__(128) void attn_kernel(const float* __restrict__ qkv,
                                                   const float* __restrict__ kv_cache,
                                                   const int* __restrict__ page_idx,
                                                   const float* __restrict__ sinks,
                                                   float* __restrict__ attn_out) {
    int blk = blockIdx.x;
    int h = blk & 15;
    int q = (blk >> 4) & 127;
    int b = blk >> 11;
    int tid = threadIdx.x;      // 128
    int t = b * Q_ + q;
    int kvh = h >> 2;           // G = 4

    __shared__ __align__(16) float qs[HD];
    __shared__ float pv[128];
    __shared__ float wmax[2];
    __shared__ float wsum[2];

    if (tid < HD) qs[tid] = qkv[(size_t)t * QKV_N + h * HD + tid];
    __syncthreads();

    int s_lo = S_ - Q_ - 127 + q;   // 769+q
    int s = s_lo + tid;
    const float* kp;
    if (s < S_ - Q_) {
        int page = page_idx[b * P_ + (s >> 7)];
        kp = kv_cache + (size_t)page * 65536 + (size_t)(s & 127) * (NKV * HD) + kvh * HD;
    } else {
        kp = qkv + (size_t)(b * Q_ + (s - (S_ - Q_))) * QKV_N + NQ * HD + kvh * HD;
    }
    float sc = 0.f;
    const float4* kp4 = (const float4*)kp;
    const float4* qs4 = (const float4*)qs;
#pragma unroll
    for (int d = 0; d < HD / 4; d++) {
        float4 kk = kp4[d], qq = qs4[d];
        sc += qq.x * kk.x + qq.y * kk.y + qq.z * kk.z + qq.w * kk.w;
    }
    sc *= SCALE;

    float m = sc;
#pragma unroll
    for (int off = 32; off; off >>= 1) m = fmaxf(m, __shfl_down(m, off));
    if ((tid & 63) == 0) wmax[tid >> 6] = m;
    __syncthreads();
    float mm = fmaxf(wmax[0], wmax[1]);

    float p = __expf(sc - mm);
    pv[tid] = p;
    float l = p;
#pragma unroll
    for (int off = 32; off; off >>= 1) l += __shfl_down(l, off);
    if ((tid & 63) == 0) wsum[tid >> 6] = l;
    __syncthreads();
    float denom = wsum[0] + wsum[1] + __expf(sinks[h] - mm);

    if (tid < HD) {
        float acc = 0.f;
        for (int i = 0; i < 128; i++) {
            int s2 = s_lo + i;
            const float* vp;
            if (s2 < S_ - Q_) {
                int page = page_idx[b * P_ + (s2 >> 7)];
                vp = kv_cache + (size_t)page * 65536 + 32768 + (size_t)(s2 & 127) * (NKV * HD) + kvh * HD;
            } else {
                vp = qkv + (size_t)(b * Q_ + (s2 - (S_ - Q_))) * QKV_N + (NQ + NKV) * HD + kvh * HD;
            }
            acc += pv[i] * vp[tid];
        }
        attn_out[(size_t)t * (NQ * HD) + h * HD + tid] = acc / denom;
    }
}

// ---------------- MoE routing plumbing ----------------
__global__ __launch_bounds__(64) void moe_zero_kernel(int* __restrict__ cnt, int* __restrict__ pos) {
    if (threadIdx.x < E_) { cnt[threadIdx.x] = 0; pos[threadIdx.x] = 0; }
}

__global__ __launch_bounds__(256) void router_kernel(const float* __restrict__ x2,
                                                     const float* __restrict__ w_router,
                                                     const float* __restrict__ b_router,
                                                     int* __restrict__ ridx,
                                                     float* __restrict__ rwt,
                                                     int* __restrict__ cnt) {
    int t = blockIdx.x;
    int tid = threadIdx.x;
    int e = tid >> 5;       // 0..7
    int j = tid & 31;
    float acc = 0.f;
    for (int hh = j; hh < H; hh += 32) acc += x2[(size_t)t * H + hh] * w_router[hh * E_ + e];
#pragma unroll
    for (int off = 16; off; off >>= 1) acc += __shfl_down(acc, off);
    __shared__ float logits[E_];
    if (j == 0) logits[e] = acc + b_router[e];
    __syncthreads();
    if (tid == 0) {
        int i0 = 0; float v0 = logits[0];
        for (int ee = 1; ee < E_; ee++)
            if (logits[ee] > v0) { v0 = logits[ee]; i0 = ee; }
        int i1 = -1; float v1 = -3.4e38f;
        for (int ee = 0; ee < E_; ee++)
            if (ee != i0 && logits[ee] > v1) { v1 = logits[ee]; i1 = ee; }
        float w0 = 1.0f / (1.0f + __expf(v1 - v0));
        ridx[t * 2] = i0; ridx[t * 2 + 1] = i1;
        rwt[t * 2] = w0;  rwt[t * 2 + 1] = 1.0f - w0;
        atomicAdd(&cnt[i0], 1);
        atomicAdd(&cnt[i1], 1);
    }
}

__global__ __launch_bounds__(64) void moe_offsets_kernel(const int* __restrict__ cnt,
                                                         int* __restrict__ poff) {
    if (threadIdx.x == 0) {
        int run = 0;
        for (int e = 0; e < E_; e++) { poff[e] = run; run += (cnt[e] + 63) & ~63; }
    }
}

__global__ __launch_bounds__(256) void moe_scatter_kernel(const int* __restrict__ ridx,
                                                          int* __restrict__ pos,
                                                          const int* __restrict__ poff,
                                                          int* __restrict__ list) {
    int i = blockIdx.x * 256 + threadIdx.x;   // 0 .. 2T-1
    if (i < 2 * T_) {
        int e = ridx[i];
        int p = atomicAdd(&pos[e], 1);
        list[poff[e] + p] = i;                // i = t*2 + k
    }
}

// ---------------- Grouped gate_up bf16-MFMA GEMM + swiglu, double-buffered ----------------
// grid: x = FFN/64 = 16 (64 act cols/block), y = E*16 (row tiles of 64, early exit)
__global__ __launch_bounds__(256) void moe_gateup_mfma(const float* __restrict__ x2,
                                                       const int* __restrict__ list,
                                                       const int* __restrict__ cnt,
                                                       const int* __restrict__ poff,
                                                       const float* __restrict__ w_gate_up,
                                                       const float* __restrict__ b_gate_up,
                                                       float* __restrict__ act) {
    int e  = blockIdx.y >> 4;
    int tl = blockIdx.y & 15;
    int n  = cnt[e];
    if (tl * 64 >= n) return;
    int base = poff[e];
    int bn = blockIdx.x * 64;                 // act-col base

    __shared__ s16x8 A_s[2][4][64];
    __shared__ s16x8 Bg_s[2][4][64];
    __shared__ s16x8 Bu_s[2][4][64];

    int tid = threadIdx.x;
    int wv = tid >> 6, lane = tid & 63;
    int sm = tid & 63, skq = tid >> 6;
    int dl = (skq << 4) + (sm & 15);
    int dt = sm >> 4;
    int row = tl * 64 + sm;
    bool valid = row < n;
    int t2 = valid ? list[base + row] : 0;
    const float* aptr = x2 + (size_t)(t2 >> 1) * 1024 + skq * 8;
    const float* bptr = w_gate_up + (size_t)e * 1024 * 2048 + (size_t)(skq * 8) * 2048 + 2 * (bn + sm);

    {
        float4 a0 = make_float4(0.f, 0.f, 0.f, 0.f), a1 = a0;
        if (valid) { a0 = *(const float4*)(aptr); a1 = *(const float4*)(aptr + 4); }
        float2 gv[8];
#pragma unroll
        for (int j = 0; j < 8; j++) gv[j] = *(const float2*)(bptr + (size_t)j * 2048);
        A_s[0][dt][dl] = pack_a(a0, a1);
        s16x8 pg, pu;
#pragma unroll
        for (int j = 0; j < 8; j++) { pg[j] = f2bf(gv[j].x); pu[j] = f2bf(gv[j].y); }
        Bg_s[0][dt][dl] = pg;
        Bu_s[0][dt][dl] = pu;
    }
    f32x4 accg[4] = {}, accu[4] = {};
    for (int it = 0; it < 32; it++) {
        int cur = it & 1, nxt = cur ^ 1;
        float4 na0, na1; float2 ngv[8];
        if (it < 31) {
            int k0 = (it + 1) * 32;
            na0 = make_float4(0.f, 0.f, 0.f, 0.f); na1 = na0;
            if (valid) { na0 = *(const float4*)(aptr + k0); na1 = *(const float4*)(aptr + k0 + 4); }
#pragma unroll
            for (int j = 0; j < 8; j++) ngv[j] = *(const float2*)(bptr + (size_t)(k0 + j) * 2048);
        }
        __syncthreads();
        s16x8 bg = Bg_s[cur][wv][lane];
        s16x8 bu = Bu_s[cur][wv][lane];
#pragma unroll
        for (int mt = 0; mt < 4; mt++) {
            accg[mt] = __builtin_amdgcn_mfma_f32_16x16x32_bf16(A_s[cur][mt][lane], bg, accg[mt], 0, 0, 0);
            accu[mt] = __builtin_amdgcn_mfma_f32_16x16x32_bf16(A_s[cur][mt][lane], bu, accu[mt], 0, 0, 0);
        }
        if (it < 31) {
            A_s[nxt][dt][dl] = pack_a(na0, na1);
            s16x8 pg, pu;
#pragma unroll
            for (int j = 0; j < 8; j++) { pg[j] = f2bf(ngv[j].x); pu[j] = f2bf(ngv[j].y); }
            Bg_s[nxt][dt][dl] = pg;
            Bu_s[nxt][dt][dl] = pu;
        }
    }
    int col = bn + wv * 16 + (lane & 15);
    int rb = (lane >> 4) * 4;
    float bg_b = b_gate_up[(size_t)e * 2048 + 2 * col];
    float bu_b = b_gate_up[(size_t)e * 2048 + 2 * col + 1];
#pragma unroll
    for (int mt = 0; mt < 4; mt++)
#pragma unroll
        for (int r = 0; r < 4; r++) {
            int rr = tl * 64 + mt * 16 + rb + r;
            float av = 0.f;
            if (rr < n) {
                float gate = fminf(accg[mt][r] + bg_b, LIMIT);
                float up = fminf(fmaxf(accu[mt][r] + bu_b, -LIMIT), LIMIT);
                float glu = gate / (1.0f + __expf(-ALPHA * gate));
                av = (up + 1.0f) * glu;
            }
            act[(size_t)(base + rr) * FFN + col] = av;
        }
}

// ---------------- Grouped down bf16-MFMA GEMM, double-buffered ----------------
// grid: x = H/64 = 16, y = E*16
__global__ __launch_bounds__(256) void moe_down_mfma(const float* __restrict__ act,
                                                     const int* __restrict__ list,
                                                     const int* __restrict__ cnt,
                                                     const int* __restrict__ poff,
                                                     const float* __restrict__ rwt,
                                                     const float* __restrict__ w_down,
                                                     const float* __restrict__ b_down,
                                                     float* __restrict__ part) {
    int e  = blockIdx.y >> 4;
    int tl = blockIdx.y & 15;
    int n  = cnt[e];
    if (tl * 64 >= n) return;
    int base = poff[e];
    int bn = blockIdx.x * 64;

    __shared__ s16x8 A_s[2][4][64];
    __shared__ s16x8 B_s[2][4][64];

    int tid = threadIdx.x;
    int wv = tid >> 6, lane = tid & 63;
    int sm = tid & 63, skq = tid >> 6;
    int dl = (skq << 4) + (sm & 15);
    int dt = sm >> 4;
    const float* aptr = act + (size_t)(base + tl * 64 + sm) * 1024 + skq * 8;
    const float* bptr = w_down + (size_t)e * 1024 * 1024 + (size_t)(skq * 8) * 1024 + bn + sm;

    {
        float4 a0 = *(const float4*)(aptr);
        float4 a1 = *(const float4*)(aptr + 4);
        float bv[8];
#pragma unroll
        for (int j = 0; j < 8; j++) bv[j] = bptr[(size_t)j * 1024];
        A_s[0][dt][dl] = pack_a(a0, a1);
        s16x8 pb;
#pragma unroll
        for (int j = 0; j < 8; j++) pb[j] = f2bf(bv[j]);
        B_s[0][dt][dl] = pb;
    }
    f32x4 acc[4] = {};
    for (int it = 0; it < 32; it++) {
        int cur = it & 1, nxt = cur ^ 1;
        float4 na0, na1; float nbv[8];
        if (it < 31) {
            int k0 = (it + 1) * 32;
            na0 = *(const float4*)(aptr + k0);
            na1 = *(const float4*)(aptr + k0 + 4);
#pragma unroll
            for (int j = 0; j < 8; j++) nbv[j] = bptr[(size_t)(k0 + j) * 1024];
        }
        __syncthreads();
        s16x8 bf = B_s[cur][wv][lane];
#pragma unroll
        for (int mt = 0; mt < 4; mt++)
            acc[mt] = __builtin_amdgcn_mfma_f32_16x16x32_bf16(A_s[cur][mt][lane], bf, acc[mt], 0, 0, 0);
        if (it < 31) {
            A_s[nxt][dt][dl] = pack_a(na0, na1);
            s16x8 pb;
#pragma unroll
            for (int j = 0; j < 8; j++) pb[j] = f2bf(nbv[j]);
            B_s[nxt][dt][dl] = pb;
        }
    }
    int col = bn + wv * 16 + (lane & 15);
    int rb = (lane >> 4) * 4;
    float bcol = b_down[(size_t)e * 1024 + col];
#pragma unroll
    for (int mt = 0; mt < 4; mt++)
#pragma unroll
        for (int r = 0; r < 4; r++) {
            int rr = tl * 64 + mt * 16 + rb + r;
            if (rr < n) {
                int t2 = list[base + rr];
                part[(size_t)t2 * H + col] = rwt[t2] * (acc[mt][r] + bcol);
            }
        }
}

// ---------------- out = h + part0 + part1 ----------------
__global__ __launch_bounds__(256) void final_add_kernel(const float* __restrict__ hbuf,
                                                        const float* __restrict__ part,
                                                        float* __restrict__ out) {
    int t = blockIdx.x;
    int tid = threadIdx.x;
    float4 a  = ((const float4*)(hbuf + (size_t)t * H))[tid];
    float4 p0 = ((const float4*)(part + (size_t)(t * 2) * H))[tid];
    float4 p1 = ((const float4*)(part + (size_t)(t * 2 + 1) * H))[tid];
    float4 o;
    o.x = a.x + p0.x + p1.x; o.y = a.y + p0.y + p1.y;
    o.z = a.z + p0.z + p1.z; o.w = a.w + p0.w + p1.w;
    ((float4*)(out + (size_t)t * H))[tid] = o;
}

extern "C" void kernel_launch(void* const* d_in, const int* in_sizes, int n_in,
                              void* d_out, int out_size, void* d_ws, size_t ws_size,
                              hipStream_t stream) {
    const float* hidden          = (const float*)d_in[0];
    const float* kv_cache        = (const float*)d_in[1];
    const int*   kv_page_indices = (const int*)d_in[3];
    const float* sinks           = (const float*)d_in[4];
    const float* w_qkv           = (const float*)d_in[5];
    const float* b_qkv           = (const float*)d_in[6];
    const float* w_o             = (const float*)d_in[7];
    const float* b_o             = (const float*)d_in[8];
    const float* ln1_w           = (const float*)d_in[9];
    const float* ln2_w           = (const float*)d_in[10];
    const float* w_router        = (const float*)d_in[11];
    const float* b_router        = (const float*)d_in[12];
    const float* w_gate_up       = (const float*)d_in[13];
    const float* b_gate_up       = (const float*)d_in[14];
    const float* w_down          = (const float*)d_in[15];
    const float* b_down          = (const float*)d_in[16];
    float* out = (float*)d_out;

    float* ws   = (float*)d_ws;
    float* x    = ws;                               // T*H
    float* qkv  = x + (size_t)T_ * H;               // T*QKV_N
    float* attn = qkv + (size_t)T_ * QKV_N;         // T*NQ*HD
    float* act  = ws;                               // MAXROWS*FFN (aliases x/qkv/attn, dead by MoE)
    float* hbuf = attn + (size_t)T_ * NQ * HD;      // T*H
    float* x2   = hbuf + (size_t)T_ * H;            // T*H
    float* part = x2 + (size_t)T_ * H;              // 2*T*H
    float* rwt  = part + (size_t)2 * T_ * H;        // 2*T
    int*   ridx = (int*)(rwt + 2 * T_);             // 2*T
    int*   cnt  = ridx + 2 * T_;                    // E
    int*   pos  = cnt + E_;                         // E
    int*   poff = pos + E_;                         // E
    int*   list = poff + E_;                        // MAXROWS

    moe_zero_kernel<<<1, 64, 0, stream>>>(cnt, pos);
    rmsnorm_kernel<<<T_, 256, 0, stream>>>(hidden, ln1_w, x);
    gemm_bf16_kernel<<<dim3(QKV_N / 64, T_ / 64), 256, 0, stream>>>(x, w_qkv, b_qkv, nullptr, qkv, QKV_N);
    attn_kernel<<<B_ * Q_ * NQ, 128, 0, stream>>>(qkv, kv_cache, kv_page_indices, sinks, attn);
    gemm_bf16_kernel<<<dim3(H / 64, T_ / 64), 256, 0, stream>>>(attn, w_o, b_o, hidden, hbuf, H);
    rmsnorm_kernel<<<T_, 256, 0, stream>>>(hbuf, ln2_w, x2);
    router_kernel<<<T_, 256, 0, stream>>>(x2, w_router, b_router, ridx, rwt, cnt);
    moe_offsets_kernel<<<1, 64, 0, stream>>>(cnt, poff);
    moe_scatter_kernel<<<(2 * T_ + 255) / 256, 256, 0, stream>>>(ridx, pos, poff, list);
    moe_gateup_mfma<<<dim3(FFN / 64, E_ * 16), 256, 0, stream>>>(
        x2, list, cnt, poff, w_gate_up, b_gate_up, act);
    moe_down_mfma<<<dim3(H / 64, E_ * 16), 256, 0, stream>>>(
        act, list, cnt, poff, rwt, w_down, b_down, part);
    final_add_kernel<<<T_, 256, 0, stream>>>(hbuf, part, out);
}

// Round 5
// 496.627 us; speedup vs baseline: 2.6788x; 1.0248x over previous
//
#include <hip/hip_runtime.h>

// ---- static config (mirrors reference) ----
constexpr int H    = 1024;
constexpr int HD   = 64;
constexpr int NQ   = 16;
constexpr int NKV  = 4;
constexpr int E_   = 8;
constexpr int FFN  = 1024;
constexpr int B_   = 4;
constexpr int Q_   = 128;
constexpr int P_   = 8;
constexpr int PS   = 128;
constexpr int S_   = P_ * PS;                 // 1024
constexpr int T_   = B_ * Q_;                 // 512
constexpr int QKV_N = HD * (NQ + 2 * NKV);    // 1536
constexpr float EPS   = 1e-5f;
constexpr float ALPHA = 1.702f;
constexpr float LIMIT = 7.0f;
constexpr float SCALE = 0.125f;               // HD^-0.5

constexpr int MAXROWS = 1536;                 // 1024 assignments + per-expert pad to 64

typedef __attribute__((ext_vector_type(4))) float f32x4;
typedef __attribute__((ext_vector_type(8))) short s16x8;

// f32 -> bf16 bits, round-to-nearest-even
__device__ __forceinline__ short f2bf(float f) {
    unsigned u = __float_as_uint(f);
    u += 0x7FFFu + ((u >> 16) & 1u);
    return (short)(u >> 16);
}

__device__ __forceinline__ s16x8 pack_a(float4 a0, float4 a1) {
    s16x8 p;
    p[0] = f2bf(a0.x); p[1] = f2bf(a0.y); p[2] = f2bf(a0.z); p[3] = f2bf(a0.w);
    p[4] = f2bf(a1.x); p[5] = f2bf(a1.y); p[6] = f2bf(a1.z); p[7] = f2bf(a1.w);
    return p;
}

// ---------------- RMSNorm: one block per token ----------------
__global__ __launch_bounds__(256) void rmsnorm_kernel(const float* __restrict__ in,
                                                      const float* __restrict__ w,
                                                      float* __restrict__ out) {
    int t   = blockIdx.x;
    int tid = threadIdx.x;
    const float4* in4 = (const float4*)(in + (size_t)t * H);
    float4 v = in4[tid];
    float ss = v.x * v.x + v.y * v.y + v.z * v.z + v.w * v.w;
#pragma unroll
    for (int off = 32; off; off >>= 1) ss += __shfl_down(ss, off);
    __shared__ float partial[4];
    __shared__ float s_inv;
    if ((tid & 63) == 0) partial[tid >> 6] = ss;
    __syncthreads();
    if (tid == 0)
        s_inv = rsqrtf((partial[0] + partial[1] + partial[2] + partial[3]) * (1.0f / H) + EPS);
    __syncthreads();
    float inv = s_inv;
    float4 wv = ((const float4*)w)[tid];
    float4 o;
    o.x = v.x * wv.x * inv; o.y = v.y * wv.y * inv;
    o.z = v.z * wv.z * inv; o.w = v.w * wv.w * inv;
    ((float4*)(out + (size_t)t * H))[tid] = o;
}

// ---------------- single-wave direct-MFMA dense GEMM ----------------
// C[*,N] = A[*,1024] @ W[1024,N] + bias (+resid). One wave per 64m x 16n tile.
// No LDS, no barriers: MFMA fragments loaded straight from global; compiler
// pipelines across k-steps with fine-grained vmcnt.
__global__ __launch_bounds__(64) void gemm_wave_kernel(const float* __restrict__ A,
                                                       const float* __restrict__ Wm,
                                                       const float* __restrict__ bias,
                                                       const float* __restrict__ resid,
                                                       float* __restrict__ C, int N) {
    int lane = threadIdx.x;
    int nb = blockIdx.x * 16, mb = blockIdx.y * 64;
    int r16 = lane & 15, kq = lane >> 4;
    const float* ap = A + (size_t)(mb + r16) * 1024 + kq * 8;
    const float* bp = Wm + (size_t)(kq * 8) * N + nb + r16;
    f32x4 acc[4] = {};
#pragma unroll 2
    for (int k0 = 0; k0 < 1024; k0 += 32) {
        s16x8 af[4];
#pragma unroll
        for (int mt = 0; mt < 4; mt++) {
            float4 a0 = *(const float4*)(ap + mt * 16384 + k0);
            float4 a1 = *(const float4*)(ap + mt * 16384 + k0 + 4);
            af[mt] = pack_a(a0, a1);
        }
        s16x8 bf;
#pragma unroll
        for (int j = 0; j < 8; j++) bf[j] = f2bf(bp[(size_t)(k0 + j) * N]);
#pragma unroll
        for (int mt = 0; mt < 4; mt++)
            acc[mt] = __builtin_amdgcn_mfma_f32_16x16x32_bf16(af[mt], bf, acc[mt], 0, 0, 0);
    }
    int col = nb + r16;
    int rb = kq * 4;
    float bcol = bias[col];
#pragma unroll
    for (int mt = 0; mt < 4; mt++)
#pragma unroll
        for (int r = 0; r < 4; r++) {
            int row = mb + mt * 16 + rb + r;
            float v = acc[mt][r] + bcol;
            if (resid) v += resid[(size_t)row * N + col];
            C[(size_t)row * N + col] = v;
        }
}

// ---------------- Attention: one block per (b, q, head); exactly 128 keys in window ----------------
__global__ __launch_bounds__(128) void attn_kernel(const float* __restrict__ qkv,
                                                   const float* __restrict__ kv_cache,
                                                   const int* __restrict__ page_idx,
                                                   const float* __restrict__ sinks,
                                                   float* __restrict__ attn_out) {
    int blk = blockIdx.x;
    int h = blk & 15;
    int q = (blk >> 4) & 127;
    int b = blk >> 11;
    int tid = threadIdx.x;      // 128
    int t = b * Q_ + q;
    int kvh = h >> 2;           // G = 4

    __shared__ __align__(16) float qs[HD];
    __shared__ float pv[128];
    __shared__ float wmax[2];
    __shared__ float wsum[2];

    if (tid < HD) qs[tid] = qkv[(size_t)t * QKV_N + h * HD + tid];
    __syncthreads();

    int s_lo = S_ - Q_ - 127 + q;   // 769+q
    int s = s_lo + tid;
    const float* kp;
    if (s < S_ - Q_) {
        int page = page_idx[b * P_ + (s >> 7)];
        kp = kv_cache + (size_t)page * 65536 + (size_t)(s & 127) * (NKV * HD) + kvh * HD;
    } else {
        kp = qkv + (size_t)(b * Q_ + (s - (S_ - Q_))) * QKV_N + NQ * HD + kvh * HD;
    }
    float sc = 0.f;
    const float4* kp4 = (const float4*)kp;
    const float4* qs4 = (const float4*)qs;
#pragma unroll
    for (int d = 0; d < HD / 4; d++) {
        float4 kk = kp4[d], qq = qs4[d];
        sc += qq.x * kk.x + qq.y * kk.y + qq.z * kk.z + qq.w * kk.w;
    }
    sc *= SCALE;

    float m = sc;
#pragma unroll
    for (int off = 32; off; off >>= 1) m = fmaxf(m, __shfl_down(m, off));
    if ((tid & 63) == 0) wmax[tid >> 6] = m;
    __syncthreads();
    float mm = fmaxf(wmax[0], wmax[1]);

    float p = __expf(sc - mm);
    pv[tid] = p;
    float l = p;
#pragma unroll
    for (int off = 32; off; off >>= 1) l += __shfl_down(l, off);
    if ((tid & 63) == 0) wsum[tid >> 6] = l;
    __syncthreads();
    float denom = wsum[0] + wsum[1] + __expf(sinks[h] - mm);

    if (tid < HD) {
        float acc = 0.f;
        for (int i = 0; i < 128; i++) {
            int s2 = s_lo + i;
            const float* vp;
            if (s2 < S_ - Q_) {
                int page = page_idx[b * P_ + (s2 >> 7)];
                vp = kv_cache + (size_t)page * 65536 + 32768 + (size_t)(s2 & 127) * (NKV * HD) + kvh * HD;
            } else {
                vp = qkv + (size_t)(b * Q_ + (s2 - (S_ - Q_))) * QKV_N + (NQ + NKV) * HD + kvh * HD;
            }
            acc += pv[i] * vp[tid];
        }
        attn_out[(size_t)t * (NQ * HD) + h * HD + tid] = acc / denom;
    }
}

// ---------------- MoE routing plumbing ----------------
__global__ __launch_bounds__(64) void moe_zero_kernel(int* __restrict__ cnt, int* __restrict__ pos) {
    if (threadIdx.x < E_) { cnt[threadIdx.x] = 0; pos[threadIdx.x] = 0; }
}

__global__ __launch_bounds__(256) void router_kernel(const float* __restrict__ x2,
                                                     const float* __restrict__ w_router,
                                                     const float* __restrict__ b_router,
                                                     int* __restrict__ ridx,
                                                     float* __restrict__ rwt,
                                                     int* __restrict__ cnt) {
    int t = blockIdx.x;
    int tid = threadIdx.x;
    int e = tid >> 5;       // 0..7
    int j = tid & 31;
    float acc = 0.f;
    for (int hh = j; hh < H; hh += 32) acc += x2[(size_t)t * H + hh] * w_router[hh * E_ + e];
#pragma unroll
    for (int off = 16; off; off >>= 1) acc += __shfl_down(acc, off);
    __shared__ float logits[E_];
    if (j == 0) logits[e] = acc + b_router[e];
    __syncthreads();
    if (tid == 0) {
        int i0 = 0; float v0 = logits[0];
        for (int ee = 1; ee < E_; ee++)
            if (logits[ee] > v0) { v0 = logits[ee]; i0 = ee; }
        int i1 = -1; float v1 = -3.4e38f;
        for (int ee = 0; ee < E_; ee++)
            if (ee != i0 && logits[ee] > v1) { v1 = logits[ee]; i1 = ee; }
        float w0 = 1.0f / (1.0f + __expf(v1 - v0));
        ridx[t * 2] = i0; ridx[t * 2 + 1] = i1;
        rwt[t * 2] = w0;  rwt[t * 2 + 1] = 1.0f - w0;
        atomicAdd(&cnt[i0], 1);
        atomicAdd(&cnt[i1], 1);
    }
}

__global__ __launch_bounds__(64) void moe_offsets_kernel(const int* __restrict__ cnt,
                                                         int* __restrict__ poff) {
    if (threadIdx.x == 0) {
        int run = 0;
        for (int e = 0; e < E_; e++) { poff[e] = run; run += (cnt[e] + 63) & ~63; }
    }
}

__global__ __launch_bounds__(256) void moe_scatter_kernel(const int* __restrict__ ridx,
                                                          int* __restrict__ pos,
                                                          const int* __restrict__ poff,
                                                          int* __restrict__ list) {
    int i = blockIdx.x * 256 + threadIdx.x;   // 0 .. 2T-1
    if (i < 2 * T_) {
        int e = ridx[i];
        int p = atomicAdd(&pos[e], 1);
        list[poff[e] + p] = i;                // i = t*2 + k
    }
}

// ---------------- Grouped gate_up single-wave MFMA + swiglu ----------------
// grid: x = FFN/16 = 64 (16 act cols/wave), y = E*16 (64-row tiles, early exit)
__global__ __launch_bounds__(64) void moe_gateup_wave(const float* __restrict__ x2,
                                                      const int* __restrict__ list,
                                                      const int* __restrict__ cnt,
                                                      const int* __restrict__ poff,
                                                      const float* __restrict__ w_gate_up,
                                                      const float* __restrict__ b_gate_up,
                                                      float* __restrict__ act) {
    int e  = blockIdx.y >> 4;
    int tl = blockIdx.y & 15;
    int n  = cnt[e];
    if (tl * 64 >= n) return;
    int base = poff[e];
    int nb = blockIdx.x * 16;                 // act-col base

    int lane = threadIdx.x;
    int r16 = lane & 15, kq = lane >> 4;
    // per-mt token row (padded rows -> token 0; their outputs are not stored)
    const float* ap[4];
#pragma unroll
    for (int mt = 0; mt < 4; mt++) {
        int row = tl * 64 + mt * 16 + r16;
        int t2 = (row < n) ? list[base + row] : 0;
        ap[mt] = x2 + (size_t)(t2 >> 1) * 1024 + kq * 8;
    }
    const float* bp = w_gate_up + (size_t)e * 1024 * 2048 + (size_t)(kq * 8) * 2048 + 2 * (nb + r16);

    f32x4 accg[4] = {}, accu[4] = {};
#pragma unroll 2
    for (int k0 = 0; k0 < 1024; k0 += 32) {
        s16x8 af[4];
#pragma unroll
        for (int mt = 0; mt < 4; mt++) {
            float4 a0 = *(const float4*)(ap[mt] + k0);
            float4 a1 = *(const float4*)(ap[mt] + k0 + 4);
            af[mt] = pack_a(a0, a1);
        }
        s16x8 bg, bu;
#pragma unroll
        for (int j = 0; j < 8; j++) {
            float2 gu = *(const float2*)(bp + (size_t)(k0 + j) * 2048);
            bg[j] = f2bf(gu.x); bu[j] = f2bf(gu.y);
        }
#pragma unroll
        for (int mt = 0; mt < 4; mt++) {
            accg[mt] = __builtin_amdgcn_mfma_f32_16x16x32_bf16(af[mt], bg, accg[mt], 0, 0, 0);
            accu[mt] = __builtin_amdgcn_mfma_f32_16x16x32_bf16(af[mt], bu, accu[mt], 0, 0, 0);
        }
    }
    int col = nb + r16;
    int rb = kq * 4;
    float bg_b = b_gate_up[(size_t)e * 2048 + 2 * col];
    float bu_b = b_gate_up[(size_t)e * 2048 + 2 * col + 1];
#pragma unroll
    for (int mt = 0; mt < 4; mt++)
#pragma unroll
        for (int r = 0; r < 4; r++) {
            int rr = tl * 64 + mt * 16 + rb + r;
            if (rr < n) {
                float gate = fminf(accg[mt][r] + bg_b, LIMIT);
                float up = fminf(fmaxf(accu[mt][r] + bu_b, -LIMIT), LIMIT);
                float glu = gate / (1.0f + __expf(-ALPHA * gate));
                act[(size_t)(base + rr) * FFN + col] = (up + 1.0f) * glu;
            }
        }
}

// ---------------- Grouped down single-wave MFMA ----------------
// grid: x = H/16 = 64, y = E*16. Padded act rows hold stale/poison but finite
// values; they only influence padded output rows, which are never stored.
__global__ __launch_bounds__(64) void moe_down_wave(const float* __restrict__ act,
                                                    const int* __restrict__ list,
                                                    const int* __restrict__ cnt,
                                                    const int* __restrict__ poff,
                                                    const float* __restrict__ rwt,
                                                    const float* __restrict__ w_down,
                                                    const float* __restrict__ b_down,
                                                    float* __restrict__ part) {
    int e  = blockIdx.y >> 4;
    int tl = blockIdx.y & 15;
    int n  = cnt[e];
    if (tl * 64 >= n) return;
    int base = poff[e];
    int nb = blockIdx.x * 16;

    int lane = threadIdx.x;
    int r16 = lane & 15, kq = lane >> 4;
    const float* ap = act + (size_t)(base + tl * 64 + r16) * 1024 + kq * 8;
    const float* bp = w_down + (size_t)e * 1024 * 1024 + (size_t)(kq * 8) * 1024 + nb + r16;

    f32x4 acc[4] = {};
#pragma unroll 2
    for (int k0 = 0; k0 < 1024; k0 += 32) {
        s16x8 af[4];
#pragma unroll
        for (int mt = 0; mt < 4; mt++) {
            float4 a0 = *(const float4*)(ap + mt * 16384 + k0);
            float4 a1 = *(const float4*)(ap + mt * 16384 + k0 + 4);
            af[mt] = pack_a(a0, a1);
        }
        s16x8 bf;
#pragma unroll
        for (int j = 0; j < 8; j++) bf[j] = f2bf(bp[(size_t)(k0 + j) * 1024]);
#pragma unroll
        for (int mt = 0; mt < 4; mt++)
            acc[mt] = __builtin_amdgcn_mfma_f32_16x16x32_bf16(af[mt], bf, acc[mt], 0, 0, 0);
    }
    int col = nb + r16;
    int rb = kq * 4;
    float bcol = b_down[(size_t)e * 1024 + col];
#pragma unroll
    for (int mt = 0; mt < 4; mt++)
#pragma unroll
        for (int r = 0; r < 4; r++) {
            int rr = tl * 64 + mt * 16 + rb + r;
            if (rr < n) {
                int t2 = list[base + rr];
                part[(size_t)t2 * H + col] = rwt[t2] * (acc[mt][r] + bcol);
            }
        }
}

// ---------------- out = h + part0 + part1 ----------------
__global__ __launch_bounds__(256) void final_add_kernel(const float* __restrict__ hbuf,
                                                        const float* __restrict__ part,
                                                        float* __restrict__ out) {
    int t = blockIdx.x;
    int tid = threadIdx.x;
    float4 a  = ((const float4*)(hbuf + (size_t)t * H))[tid];
    float4 p0 = ((const float4*)(part + (size_t)(t * 2) * H))[tid];
    float4 p1 = ((const float4*)(part + (size_t)(t * 2 + 1) * H))[tid];
    float4 o;
    o.x = a.x + p0.x + p1.x; o.y = a.y + p0.y + p1.y;
    o.z = a.z + p0.z + p1.z; o.w = a.w + p0.w + p1.w;
    ((float4*)(out + (size_t)t * H))[tid] = o;
}

extern "C" void kernel_launch(void* const* d_in, const int* in_sizes, int n_in,
                              void* d_out, int out_size, void* d_ws, size_t ws_size,
                              hipStream_t stream) {
    const float* hidden          = (const float*)d_in[0];
    const float* kv_cache        = (const float*)d_in[1];
    const int*   kv_page_indices = (const int*)d_in[3];
    const float* sinks           = (const float*)d_in[4];
    const float* w_qkv           = (const float*)d_in[5];
    const float* b_qkv           = (const float*)d_in[6];
    const float* w_o             = (const float*)d_in[7];
    const float* b_o             = (const float*)d_in[8];
    const float* ln1_w           = (const float*)d_in[9];
    const float* ln2_w           = (const float*)d_in[10];
    const float* w_router        = (const float*)d_in[11];
    const float* b_router        = (const float*)d_in[12];
    const float* w_gate_up       = (const float*)d_in[13];
    const float* b_gate_up       = (const float*)d_in[14];
    const float* w_down          = (const float*)d_in[15];
    const float* b_down          = (const float*)d_in[16];
    float* out = (float*)d_out;

    float* ws   = (float*)d_ws;
    float* x    = ws;                               // T*H
    float* qkv  = x + (size_t)T_ * H;               // T*QKV_N
    float* attn = qkv + (size_t)T_ * QKV_N;         // T*NQ*HD
    float* act  = ws;                               // MAXROWS*FFN (aliases x/qkv/attn, dead by MoE)
    float* hbuf = attn + (size_t)T_ * NQ * HD;      // T*H
    float* x2   = hbuf + (size_t)T_ * H;            // T*H
    float* part = x2 + (size_t)T_ * H;              // 2*T*H
    float* rwt  = part + (size_t)2 * T_ * H;        // 2*T
    int*   ridx = (int*)(rwt + 2 * T_);             // 2*T
    int*   cnt  = ridx + 2 * T_;                    // E
    int*   pos  = cnt + E_;                         // E
    int*   poff = pos + E_;                         // E
    int*   list = poff + E_;                        // MAXROWS

    moe_zero_kernel<<<1, 64, 0, stream>>>(cnt, pos);
    rmsnorm_kernel<<<T_, 256, 0, stream>>>(hidden, ln1_w, x);
    gemm_wave_kernel<<<dim3(QKV_N / 16, T_ / 64), 64, 0, stream>>>(x, w_qkv, b_qkv, nullptr, qkv, QKV_N);
    attn_kernel<<<B_ * Q_ * NQ, 128, 0, stream>>>(qkv, kv_cache, kv_page_indices, sinks, attn);
    gemm_wave_kernel<<<dim3(H / 16, T_ / 64), 64, 0, stream>>>(attn, w_o, b_o, hidden, hbuf, H);
    rmsnorm_kernel<<<T_, 256, 0, stream>>>(hbuf, ln2_w, x2);
    router_kernel<<<T_, 256, 0, stream>>>(x2, w_router, b_router, ridx, rwt, cnt);
    moe_offsets_kernel<<<1, 64, 0, stream>>>(cnt, poff);
    moe_scatter_kernel<<<(2 * T_ + 255) / 256, 256, 0, stream>>>(ridx, pos, poff, list);
    moe_gateup_wave<<<dim3(FFN / 16, E_ * 16), 64, 0, stream>>>(
        x2, list, cnt, poff, w_gate_up, b_gate_up, act);
    moe_down_wave<<<dim3(H / 16, E_ * 16), 64, 0, stream>>>(
        act, list, cnt, poff, rwt, w_down, b_down, part);
    final_add_kernel<<<T_, 256, 0, stream>>>(hbuf, part, out);
}

// Round 6
// 412.525 us; speedup vs baseline: 3.2249x; 1.2039x over previous
//
#include <hip/hip_runtime.h>

// ---- static config (mirrors reference) ----
constexpr int H    = 1024;
constexpr int HD   = 64;
constexpr int NQ   = 16;
constexpr int NKV  = 4;
constexpr int E_   = 8;
constexpr int FFN  = 1024;
constexpr int B_   = 4;
constexpr int Q_   = 128;
constexpr int P_   = 8;
constexpr int PS   = 128;
constexpr int S_   = P_ * PS;                 // 1024
constexpr int T_   = B_ * Q_;                 // 512
constexpr int QKV_N = HD * (NQ + 2 * NKV);    // 1536
constexpr float EPS   = 1e-5f;
constexpr float ALPHA = 1.702f;
constexpr float LIMIT = 7.0f;
constexpr float SCALE = 0.125f;               // HD^-0.5

constexpr int MAXROWS = 1536;                 // 1024 assignments + per-expert pad to 64

typedef __attribute__((ext_vector_type(4))) float f32x4;
typedef __attribute__((ext_vector_type(8))) short s16x8;

// f32 -> bf16 bits, round-to-nearest-even
__device__ __forceinline__ short f2bf(float f) {
    unsigned u = __float_as_uint(f);
    u += 0x7FFFu + ((u >> 16) & 1u);
    return (short)(u >> 16);
}

__device__ __forceinline__ s16x8 pack_a(float4 a0, float4 a1) {
    s16x8 p;
    p[0] = f2bf(a0.x); p[1] = f2bf(a0.y); p[2] = f2bf(a0.z); p[3] = f2bf(a0.w);
    p[4] = f2bf(a1.x); p[5] = f2bf(a1.y); p[6] = f2bf(a1.z); p[7] = f2bf(a1.w);
    return p;
}

// ---------------- RMSNorm: one block per token ----------------
__global__ __launch_bounds__(256) void rmsnorm_kernel(const float* __restrict__ in,
                                                      const float* __restrict__ w,
                                                      float* __restrict__ out) {
    int t   = blockIdx.x;
    int tid = threadIdx.x;
    const float4* in4 = (const float4*)(in + (size_t)t * H);
    float4 v = in4[tid];
    float ss = v.x * v.x + v.y * v.y + v.z * v.z + v.w * v.w;
#pragma unroll
    for (int off = 32; off; off >>= 1) ss += __shfl_down(ss, off);
    __shared__ float partial[4];
    __shared__ float s_inv;
    if ((tid & 63) == 0) partial[tid >> 6] = ss;
    __syncthreads();
    if (tid == 0)
        s_inv = rsqrtf((partial[0] + partial[1] + partial[2] + partial[3]) * (1.0f / H) + EPS);
    __syncthreads();
    float inv = s_inv;
    float4 wv = ((const float4*)w)[tid];
    float4 o;
    o.x = v.x * wv.x * inv; o.y = v.y * wv.y * inv;
    o.z = v.z * wv.z * inv; o.w = v.w * wv.w * inv;
    ((float4*)(out + (size_t)t * H))[tid] = o;
}

// ---------------- dense split-K MFMA GEMM ----------------
// C[*,N] = A[*,1024] @ W[1024,N] + bias (+resid). Block = 4 waves, each wave
// computes the SAME 64m x 16n tile over a 256-wide K chunk (no barriers in the
// K loop); single end-of-kernel LDS reduction.  4x the waves of R5 => 4x MLP.
__global__ __launch_bounds__(256) void gemm_splitk_kernel(const float* __restrict__ A,
                                                          const float* __restrict__ Wm,
                                                          const float* __restrict__ bias,
                                                          const float* __restrict__ resid,
                                                          float* __restrict__ C, int N) {
    int tid = threadIdx.x;
    int wv = tid >> 6, lane = tid & 63;
    int nb = blockIdx.x * 16, mb = blockIdx.y * 64;
    int r16 = lane & 15, kq = lane >> 4;
    const float* ap = A + (size_t)(mb + r16) * 1024 + wv * 256 + kq * 8;
    const float* bp = Wm + (size_t)(wv * 256 + kq * 8) * N + nb + r16;
    f32x4 acc[4] = {};
#pragma unroll 2
    for (int k0 = 0; k0 < 256; k0 += 32) {
        s16x8 af[4];
#pragma unroll
        for (int mt = 0; mt < 4; mt++) {
            float4 a0 = *(const float4*)(ap + mt * 16384 + k0);
            float4 a1 = *(const float4*)(ap + mt * 16384 + k0 + 4);
            af[mt] = pack_a(a0, a1);
        }
        s16x8 bf;
#pragma unroll
        for (int j = 0; j < 8; j++) bf[j] = f2bf(bp[(size_t)(k0 + j) * N]);
#pragma unroll
        for (int mt = 0; mt < 4; mt++)
            acc[mt] = __builtin_amdgcn_mfma_f32_16x16x32_bf16(af[mt], bf, acc[mt], 0, 0, 0);
    }
    __shared__ float red[4][4][4][64];     // [wave][mt][r][lane] - stride-1 in lane, conflict-free
#pragma unroll
    for (int mt = 0; mt < 4; mt++)
#pragma unroll
        for (int r = 0; r < 4; r++) red[wv][mt][r][lane] = acc[mt][r];
    __syncthreads();
    int mt = tid >> 6, li = tid & 63;
    int kq2 = li >> 4, c16 = li & 15;
    int col = nb + c16;
    float bcol = bias[col];
#pragma unroll
    for (int r = 0; r < 4; r++) {
        float s = red[0][mt][r][li] + red[1][mt][r][li] + red[2][mt][r][li] + red[3][mt][r][li];
        int row = mb + mt * 16 + kq2 * 4 + r;
        float v = s + bcol;
        if (resid) v += resid[(size_t)row * N + col];
        C[(size_t)row * N + col] = v;
    }
}

// ---------------- Attention: one block per (b, q, head); exactly 128 keys in window ----------------
__global__ __launch_bounds__(128) void attn_kernel(const float* __restrict__ qkv,
                                                   const float* __restrict__ kv_cache,
                                                   const int* __restrict__ page_idx,
                                                   const float* __restrict__ sinks,
                                                   float* __restrict__ attn_out) {
    int blk = blockIdx.x;
    int h = blk & 15;
    int q = (blk >> 4) & 127;
    int b = blk >> 11;
    int tid = threadIdx.x;      // 128
    int t = b * Q_ + q;
    int kvh = h >> 2;           // G = 4

    __shared__ __align__(16) float qs[HD];
    __shared__ float pv[128];
    __shared__ float wmax[2];
    __shared__ float wsum[2];

    if (tid < HD) qs[tid] = qkv[(size_t)t * QKV_N + h * HD + tid];
    __syncthreads();

    int s_lo = S_ - Q_ - 127 + q;   // 769+q
    int s = s_lo + tid;
    const float* kp;
    if (s < S_ - Q_) {
        int page = page_idx[b * P_ + (s >> 7)];
        kp = kv_cache + (size_t)page * 65536 + (size_t)(s & 127) * (NKV * HD) + kvh * HD;
    } else {
        kp = qkv + (size_t)(b * Q_ + (s - (S_ - Q_))) * QKV_N + NQ * HD + kvh * HD;
    }
    float sc = 0.f;
    const float4* kp4 = (const float4*)kp;
    const float4* qs4 = (const float4*)qs;
#pragma unroll
    for (int d = 0; d < HD / 4; d++) {
        float4 kk = kp4[d], qq = qs4[d];
        sc += qq.x * kk.x + qq.y * kk.y + qq.z * kk.z + qq.w * kk.w;
    }
    sc *= SCALE;

    float m = sc;
#pragma unroll
    for (int off = 32; off; off >>= 1) m = fmaxf(m, __shfl_down(m, off));
    if ((tid & 63) == 0) wmax[tid >> 6] = m;
    __syncthreads();
    float mm = fmaxf(wmax[0], wmax[1]);

    float p = __expf(sc - mm);
    pv[tid] = p;
    float l = p;
#pragma unroll
    for (int off = 32; off; off >>= 1) l += __shfl_down(l, off);
    if ((tid & 63) == 0) wsum[tid >> 6] = l;
    __syncthreads();
    float denom = wsum[0] + wsum[1] + __expf(sinks[h] - mm);

    if (tid < HD) {
        float acc = 0.f;
        for (int i = 0; i < 128; i++) {
            int s2 = s_lo + i;
            const float* vp;
            if (s2 < S_ - Q_) {
                int page = page_idx[b * P_ + (s2 >> 7)];
                vp = kv_cache + (size_t)page * 65536 + 32768 + (size_t)(s2 & 127) * (NKV * HD) + kvh * HD;
            } else {
                vp = qkv + (size_t)(b * Q_ + (s2 - (S_ - Q_))) * QKV_N + (NQ + NKV) * HD + kvh * HD;
            }
            acc += pv[i] * vp[tid];
        }
        attn_out[(size_t)t * (NQ * HD) + h * HD + tid] = acc / denom;
    }
}

// ---------------- MoE routing plumbing ----------------
__global__ __launch_bounds__(64) void moe_zero_kernel(int* __restrict__ cnt, int* __restrict__ pos) {
    if (threadIdx.x < E_) { cnt[threadIdx.x] = 0; pos[threadIdx.x] = 0; }
}

__global__ __launch_bounds__(256) void router_kernel(const float* __restrict__ x2,
                                                     const float* __restrict__ w_router,
                                                     const float* __restrict__ b_router,
                                                     int* __restrict__ ridx,
                                                     float* __restrict__ rwt,
                                                     int* __restrict__ cnt) {
    int t = blockIdx.x;
    int tid = threadIdx.x;
    int e = tid >> 5;       // 0..7
    int j = tid & 31;
    float acc = 0.f;
    for (int hh = j; hh < H; hh += 32) acc += x2[(size_t)t * H + hh] * w_router[hh * E_ + e];
#pragma unroll
    for (int off = 16; off; off >>= 1) acc += __shfl_down(acc, off);
    __shared__ float logits[E_];
    if (j == 0) logits[e] = acc + b_router[e];
    __syncthreads();
    if (tid == 0) {
        int i0 = 0; float v0 = logits[0];
        for (int ee = 1; ee < E_; ee++)
            if (logits[ee] > v0) { v0 = logits[ee]; i0 = ee; }
        int i1 = -1; float v1 = -3.4e38f;
        for (int ee = 0; ee < E_; ee++)
            if (ee != i0 && logits[ee] > v1) { v1 = logits[ee]; i1 = ee; }
        float w0 = 1.0f / (1.0f + __expf(v1 - v0));
        ridx[t * 2] = i0; ridx[t * 2 + 1] = i1;
        rwt[t * 2] = w0;  rwt[t * 2 + 1] = 1.0f - w0;
        atomicAdd(&cnt[i0], 1);
        atomicAdd(&cnt[i1], 1);
    }
}

__global__ __launch_bounds__(64) void moe_offsets_kernel(const int* __restrict__ cnt,
                                                         int* __restrict__ poff) {
    if (threadIdx.x == 0) {
        int run = 0;
        for (int e = 0; e < E_; e++) { poff[e] = run; run += (cnt[e] + 63) & ~63; }
    }
}

__global__ __launch_bounds__(256) void moe_scatter_kernel(const int* __restrict__ ridx,
                                                          int* __restrict__ pos,
                                                          const int* __restrict__ poff,
                                                          int* __restrict__ list) {
    int i = blockIdx.x * 256 + threadIdx.x;   // 0 .. 2T-1
    if (i < 2 * T_) {
        int e = ridx[i];
        int p = atomicAdd(&pos[e], 1);
        list[poff[e] + p] = i;                // i = t*2 + k
    }
}

// ---------------- Grouped gate_up split-K MFMA + swiglu ----------------
// grid: x = FFN/16 = 64, y = E*16 (64-row tiles, early exit). Block = 4 waves
// splitting K=1024 into 4x256; end reduction + swiglu.
__global__ __launch_bounds__(256) void moe_gateup_sk(const float* __restrict__ x2,
                                                     const int* __restrict__ list,
                                                     const int* __restrict__ cnt,
                                                     const int* __restrict__ poff,
                                                     const float* __restrict__ w_gate_up,
                                                     const float* __restrict__ b_gate_up,
                                                     float* __restrict__ act) {
    int e  = blockIdx.y >> 4;
    int tl = blockIdx.y & 15;
    int n  = cnt[e];
    if (tl * 64 >= n) return;
    int base = poff[e];
    int nb = blockIdx.x * 16;                 // act-col base

    int tid = threadIdx.x;
    int wv = tid >> 6, lane = tid & 63;
    int r16 = lane & 15, kq = lane >> 4;
    const float* ap[4];
#pragma unroll
    for (int mt = 0; mt < 4; mt++) {
        int row = tl * 64 + mt * 16 + r16;
        int t2 = (row < n) ? list[base + row] : 0;
        ap[mt] = x2 + (size_t)(t2 >> 1) * 1024 + wv * 256 + kq * 8;
    }
    const float* bp = w_gate_up + (size_t)e * 1024 * 2048 + (size_t)(wv * 256 + kq * 8) * 2048 + 2 * (nb + r16);

    f32x4 accg[4] = {}, accu[4] = {};
#pragma unroll 2
    for (int k0 = 0; k0 < 256; k0 += 32) {
        s16x8 af[4];
#pragma unroll
        for (int mt = 0; mt < 4; mt++) {
            float4 a0 = *(const float4*)(ap[mt] + k0);
            float4 a1 = *(const float4*)(ap[mt] + k0 + 4);
            af[mt] = pack_a(a0, a1);
        }
        s16x8 bg, bu;
#pragma unroll
        for (int j = 0; j < 8; j++) {
            float2 gu = *(const float2*)(bp + (size_t)(k0 + j) * 2048);
            bg[j] = f2bf(gu.x); bu[j] = f2bf(gu.y);
        }
#pragma unroll
        for (int mt = 0; mt < 4; mt++) {
            accg[mt] = __builtin_amdgcn_mfma_f32_16x16x32_bf16(af[mt], bg, accg[mt], 0, 0, 0);
            accu[mt] = __builtin_amdgcn_mfma_f32_16x16x32_bf16(af[mt], bu, accu[mt], 0, 0, 0);
        }
    }
    __shared__ float redg[4][4][4][64];    // [wave][mt][r][lane]
    __shared__ float redu[4][4][4][64];
#pragma unroll
    for (int mt = 0; mt < 4; mt++)
#pragma unroll
        for (int r = 0; r < 4; r++) {
            redg[wv][mt][r][lane] = accg[mt][r];
            redu[wv][mt][r][lane] = accu[mt][r];
        }
    __syncthreads();
    int mt = tid >> 6, li = tid & 63;
    int kq2 = li >> 4, c16 = li & 15;
    int col = nb + c16;
    float bg_b = b_gate_up[(size_t)e * 2048 + 2 * col];
    float bu_b = b_gate_up[(size_t)e * 2048 + 2 * col + 1];
#pragma unroll
    for (int r = 0; r < 4; r++) {
        int rr = tl * 64 + mt * 16 + kq2 * 4 + r;
        if (rr < n) {
            float g = redg[0][mt][r][li] + redg[1][mt][r][li] + redg[2][mt][r][li] + redg[3][mt][r][li];
            float u = redu[0][mt][r][li] + redu[1][mt][r][li] + redu[2][mt][r][li] + redu[3][mt][r][li];
            float gate = fminf(g + bg_b, LIMIT);
            float up = fminf(fmaxf(u + bu_b, -LIMIT), LIMIT);
            float glu = gate / (1.0f + __expf(-ALPHA * gate));
            act[(size_t)(base + rr) * FFN + col] = (up + 1.0f) * glu;
        }
    }
}

// ---------------- Grouped down split-K MFMA ----------------
// grid: x = H/16 = 64, y = E*16. Padded act rows (rr>=n) hold poison but finite
// values; they only influence padded output rows, which are never stored.
__global__ __launch_bounds__(256) void moe_down_sk(const float* __restrict__ act,
                                                   const int* __restrict__ list,
                                                   const int* __restrict__ cnt,
                                                   const int* __restrict__ poff,
                                                   const float* __restrict__ rwt,
                                                   const float* __restrict__ w_down,
                                                   const float* __restrict__ b_down,
                                                   float* __restrict__ part) {
    int e  = blockIdx.y >> 4;
    int tl = blockIdx.y & 15;
    int n  = cnt[e];
    if (tl * 64 >= n) return;
    int base = poff[e];
    int nb = blockIdx.x * 16;

    int tid = threadIdx.x;
    int wv = tid >> 6, lane = tid & 63;
    int r16 = lane & 15, kq = lane >> 4;
    const float* ap = act + (size_t)(base + tl * 64 + r16) * 1024 + wv * 256 + kq * 8;
    const float* bp = w_down + (size_t)e * 1024 * 1024 + (size_t)(wv * 256 + kq * 8) * 1024 + nb + r16;

    f32x4 acc[4] = {};
#pragma unroll 2
    for (int k0 = 0; k0 < 256; k0 += 32) {
        s16x8 af[4];
#pragma unroll
        for (int mt = 0; mt < 4; mt++) {
            float4 a0 = *(const float4*)(ap + mt * 16384 + k0);
            float4 a1 = *(const float4*)(ap + mt * 16384 + k0 + 4);
            af[mt] = pack_a(a0, a1);
        }
        s16x8 bf;
#pragma unroll
        for (int j = 0; j < 8; j++) bf[j] = f2bf(bp[(size_t)(k0 + j) * 1024]);
#pragma unroll
        for (int mt = 0; mt < 4; mt++)
            acc[mt] = __builtin_amdgcn_mfma_f32_16x16x32_bf16(af[mt], bf, acc[mt], 0, 0, 0);
    }
    __shared__ float red[4][4][4][64];
#pragma unroll
    for (int mt = 0; mt < 4; mt++)
#pragma unroll
        for (int r = 0; r < 4; r++) red[wv][mt][r][lane] = acc[mt][r];
    __syncthreads();
    int mt = tid >> 6, li = tid & 63;
    int kq2 = li >> 4, c16 = li & 15;
    int col = nb + c16;
    float bcol = b_down[(size_t)e * 1024 + col];
#pragma unroll
    for (int r = 0; r < 4; r++) {
        int rr = tl * 64 + mt * 16 + kq2 * 4 + r;
        if (rr < n) {
            float s = red[0][mt][r][li] + red[1][mt][r][li] + red[2][mt][r][li] + red[3][mt][r][li];
            int t2 = list[base + rr];
            part[(size_t)t2 * H + col] = rwt[t2] * (s + bcol);
        }
    }
}

// ---------------- out = h + part0 + part1 ----------------
__global__ __launch_bounds__(256) void final_add_kernel(const float* __restrict__ hbuf,
                                                        const float* __restrict__ part,
                                                        float* __restrict__ out) {
    int t = blockIdx.x;
    int tid = threadIdx.x;
    float4 a  = ((const float4*)(hbuf + (size_t)t * H))[tid];
    float4 p0 = ((const float4*)(part + (size_t)(t * 2) * H))[tid];
    float4 p1 = ((const float4*)(part + (size_t)(t * 2 + 1) * H))[tid];
    float4 o;
    o.x = a.x + p0.x + p1.x; o.y = a.y + p0.y + p1.y;
    o.z = a.z + p0.z + p1.z; o.w = a.w + p0.w + p1.w;
    ((float4*)(out + (size_t)t * H))[tid] = o;
}

extern "C" void kernel_launch(void* const* d_in, const int* in_sizes, int n_in,
                              void* d_out, int out_size, void* d_ws, size_t ws_size,
                              hipStream_t stream) {
    const float* hidden          = (const float*)d_in[0];
    const float* kv_cache        = (const float*)d_in[1];
    const int*   kv_page_indices = (const int*)d_in[3];
    const float* sinks           = (const float*)d_in[4];
    const float* w_qkv           = (const float*)d_in[5];
    const float* b_qkv           = (const float*)d_in[6];
    const float* w_o             = (const float*)d_in[7];
    const float* b_o             = (const float*)d_in[8];
    const float* ln1_w           = (const float*)d_in[9];
    const float* ln2_w           = (const float*)d_in[10];
    const float* w_router        = (const float*)d_in[11];
    const float* b_router        = (const float*)d_in[12];
    const float* w_gate_up       = (const float*)d_in[13];
    const float* b_gate_up       = (const float*)d_in[14];
    const float* w_down          = (const float*)d_in[15];
    const float* b_down          = (const float*)d_in[16];
    float* out = (float*)d_out;

    float* ws   = (float*)d_ws;
    float* x    = ws;                               // T*H
    float* qkv  = x + (size_t)T_ * H;               // T*QKV_N
    float* attn = qkv + (size_t)T_ * QKV_N;         // T*NQ*HD
    float* act  = ws;                               // MAXROWS*FFN (aliases x/qkv/attn, dead by MoE)
    float* hbuf = attn + (size_t)T_ * NQ * HD;      // T*H
    float* x2   = hbuf + (size_t)T_ * H;            // T*H
    float* part = x2 + (size_t)T_ * H;              // 2*T*H
    float* rwt  = part + (size_t)2 * T_ * H;        // 2*T
    int*   ridx = (int*)(rwt + 2 * T_);             // 2*T
    int*   cnt  = ridx + 2 * T_;                    // E
    int*   pos  = cnt + E_;                         // E
    int*   poff = pos + E_;                         // E
    int*   list = poff + E_;                        // MAXROWS

    moe_zero_kernel<<<1, 64, 0, stream>>>(cnt, pos);
    rmsnorm_kernel<<<T_, 256, 0, stream>>>(hidden, ln1_w, x);
    gemm_splitk_kernel<<<dim3(QKV_N / 16, T_ / 64), 256, 0, stream>>>(x, w_qkv, b_qkv, nullptr, qkv, QKV_N);
    attn_kernel<<<B_ * Q_ * NQ, 128, 0, stream>>>(qkv, kv_cache, kv_page_indices, sinks, attn);
    gemm_splitk_kernel<<<dim3(H / 16, T_ / 64), 256, 0, stream>>>(attn, w_o, b_o, hidden, hbuf, H);
    rmsnorm_kernel<<<T_, 256, 0, stream>>>(hbuf, ln2_w, x2);
    router_kernel<<<T_, 256, 0, stream>>>(x2, w_router, b_router, ridx, rwt, cnt);
    moe_offsets_kernel<<<1, 64, 0, stream>>>(cnt, poff);
    moe_scatter_kernel<<<(2 * T_ + 255) / 256, 256, 0, stream>>>(ridx, pos, poff, list);
    moe_gateup_sk<<<dim3(FFN / 16, E_ * 16), 256, 0, stream>>>(
        x2, list, cnt, poff, w_gate_up, b_gate_up, act);
    moe_down_sk<<<dim3(H / 16, E_ * 16), 256, 0, stream>>>(
        act, list, cnt, poff, rwt, w_down, b_down, part);
    final_add_kernel<<<T_, 256, 0, stream>>>(hbuf, part, out);
}

// Round 7
// 366.781 us; speedup vs baseline: 3.6271x; 1.1247x over previous
//
#include <hip/hip_runtime.h>

// ---- static config (mirrors reference) ----
constexpr int H    = 1024;
constexpr int HD   = 64;
constexpr int NQ   = 16;
constexpr int NKV  = 4;
constexpr int E_   = 8;
constexpr int FFN  = 1024;
constexpr int B_   = 4;
constexpr int Q_   = 128;
constexpr int P_   = 8;
constexpr int PS   = 128;
constexpr int S_   = P_ * PS;                 // 1024
constexpr int T_   = B_ * Q_;                 // 512
constexpr int QKV_N = HD * (NQ + 2 * NKV);    // 1536
constexpr float EPS   = 1e-5f;
constexpr float ALPHA = 1.702f;
constexpr float LIMIT = 7.0f;
constexpr float SCALE = 0.125f;               // HD^-0.5

constexpr int MAXROWS = 1536;                 // 1024 assignments + per-expert pad to 64

typedef __attribute__((ext_vector_type(4))) float f32x4;
typedef __attribute__((ext_vector_type(8))) short s16x8;

// f32 -> bf16 bits, round-to-nearest-even
__device__ __forceinline__ short f2bf(float f) {
    unsigned u = __float_as_uint(f);
    u += 0x7FFFu + ((u >> 16) & 1u);
    return (short)(u >> 16);
}

__device__ __forceinline__ s16x8 pack_a(float4 a0, float4 a1) {
    s16x8 p;
    p[0] = f2bf(a0.x); p[1] = f2bf(a0.y); p[2] = f2bf(a0.z); p[3] = f2bf(a0.w);
    p[4] = f2bf(a1.x); p[5] = f2bf(a1.y); p[6] = f2bf(a1.z); p[7] = f2bf(a1.w);
    return p;
}

// ---------------- RMSNorm: one block per token ----------------
__global__ __launch_bounds__(256) void rmsnorm_kernel(const float* __restrict__ in,
                                                      const float* __restrict__ w,
                                                      float* __restrict__ out) {
    int t   = blockIdx.x;
    int tid = threadIdx.x;
    const float4* in4 = (const float4*)(in + (size_t)t * H);
    float4 v = in4[tid];
    float ss = v.x * v.x + v.y * v.y + v.z * v.z + v.w * v.w;
#pragma unroll
    for (int off = 32; off; off >>= 1) ss += __shfl_down(ss, off);
    __shared__ float partial[4];
    __shared__ float s_inv;
    if ((tid & 63) == 0) partial[tid >> 6] = ss;
    __syncthreads();
    if (tid == 0)
        s_inv = rsqrtf((partial[0] + partial[1] + partial[2] + partial[3]) * (1.0f / H) + EPS);
    __syncthreads();
    float inv = s_inv;
    float4 wv = ((const float4*)w)[tid];
    float4 o;
    o.x = v.x * wv.x * inv; o.y = v.y * wv.y * inv;
    o.z = v.z * wv.z * inv; o.w = v.w * wv.w * inv;
    ((float4*)(out + (size_t)t * H))[tid] = o;
}

// ---------------- dense split-K MFMA GEMM ----------------
__global__ __launch_bounds__(256) void gemm_splitk_kernel(const float* __restrict__ A,
                                                          const float* __restrict__ Wm,
                                                          const float* __restrict__ bias,
                                                          const float* __restrict__ resid,
                                                          float* __restrict__ C, int N) {
    int tid = threadIdx.x;
    int wv = tid >> 6, lane = tid & 63;
    int nb = blockIdx.x * 16, mb = blockIdx.y * 64;
    int r16 = lane & 15, kq = lane >> 4;
    const float* ap = A + (size_t)(mb + r16) * 1024 + wv * 256 + kq * 8;
    const float* bp = Wm + (size_t)(wv * 256 + kq * 8) * N + nb + r16;
    f32x4 acc[4] = {};
#pragma unroll 2
    for (int k0 = 0; k0 < 256; k0 += 32) {
        s16x8 af[4];
#pragma unroll
        for (int mt = 0; mt < 4; mt++) {
            float4 a0 = *(const float4*)(ap + mt * 16384 + k0);
            float4 a1 = *(const float4*)(ap + mt * 16384 + k0 + 4);
            af[mt] = pack_a(a0, a1);
        }
        s16x8 bf;
#pragma unroll
        for (int j = 0; j < 8; j++) bf[j] = f2bf(bp[(size_t)(k0 + j) * N]);
#pragma unroll
        for (int mt = 0; mt < 4; mt++)
            acc[mt] = __builtin_amdgcn_mfma_f32_16x16x32_bf16(af[mt], bf, acc[mt], 0, 0, 0);
    }
    __shared__ float red[4][4][4][64];     // [wave][mt][r][lane]
#pragma unroll
    for (int mt = 0; mt < 4; mt++)
#pragma unroll
        for (int r = 0; r < 4; r++) red[wv][mt][r][lane] = acc[mt][r];
    __syncthreads();
    int mt = tid >> 6, li = tid & 63;
    int kq2 = li >> 4, c16 = li & 15;
    int col = nb + c16;
    float bcol = bias[col];
#pragma unroll
    for (int r = 0; r < 4; r++) {
        float s = red[0][mt][r][li] + red[1][mt][r][li] + red[2][mt][r][li] + red[3][mt][r][li];
        int row = mb + mt * 16 + kq2 * 4 + r;
        float v = s + bcol;
        if (resid) v += resid[(size_t)row * N + col];
        C[(size_t)row * N + col] = v;
    }
}

// ---------------- Attention v2: one block per (b, q, kvh); 4 heads per block ----------------
// 128-key window staged: V into LDS (coalesced, page logic once); K read direct.
__global__ __launch_bounds__(256) void attn_group_kernel(const float* __restrict__ qkv,
                                                         const float* __restrict__ kv_cache,
                                                         const int* __restrict__ page_idx,
                                                         const float* __restrict__ sinks,
                                                         float* __restrict__ attn_out) {
    int blk = blockIdx.x;
    int kvh = blk & 3;
    int q   = (blk >> 2) & 127;
    int b   = blk >> 9;
    int t   = b * Q_ + q;
    int tid = threadIdx.x;     // 256
    int s_lo = S_ - Q_ - 127 + q;   // 769+q; window is always exactly 128 keys

    __shared__ __align__(16) float Vs[128][64];   // 32 KB
    __shared__ __align__(16) float qs4[4][64];
    __shared__ float pv[4][128];
    __shared__ float sD[4];

    // ---- stage V window into LDS (8 rounds x 256 threads x 16B) ----
#pragma unroll
    for (int r = 0; r < 8; r++) {
        int l = r * 256 + tid;
        int key = l >> 4, c = l & 15;
        int s = s_lo + key;
        const float* vp;
        if (s < S_ - Q_) {
            int page = page_idx[b * P_ + (s >> 7)];
            vp = kv_cache + (size_t)page * 65536 + 32768 + (size_t)(s & 127) * (NKV * HD) + kvh * HD;
        } else {
            vp = qkv + (size_t)(b * Q_ + (s - (S_ - Q_))) * QKV_N + (NQ + NKV) * HD + kvh * HD;
        }
        ((float4*)Vs[key])[c] = *(const float4*)(vp + c * 4);
    }
    // ---- stage the 4 query heads ----
    {
        int hh = tid >> 6, d = tid & 63;
        qs4[hh][d] = qkv[(size_t)t * QKV_N + (kvh * 4 + hh) * HD + d];
    }
    __syncthreads();

    // ---- scores: thread = (key, head-pair); K direct from global ----
    {
        int key = tid & 127, hp = tid >> 7;
        int s = s_lo + key;
        const float* kp;
        if (s < S_ - Q_) {
            int page = page_idx[b * P_ + (s >> 7)];
            kp = kv_cache + (size_t)page * 65536 + (size_t)(s & 127) * (NKV * HD) + kvh * HD;
        } else {
            kp = qkv + (size_t)(b * Q_ + (s - (S_ - Q_))) * QKV_N + NQ * HD + kvh * HD;
        }
        const float4* kp4 = (const float4*)kp;
        const float4* q0p = (const float4*)qs4[hp * 2];
        const float4* q1p = (const float4*)qs4[hp * 2 + 1];
        float sc0 = 0.f, sc1 = 0.f;
#pragma unroll
        for (int d4 = 0; d4 < 16; d4++) {
            float4 kk = kp4[d4];
            float4 q0 = q0p[d4], q1 = q1p[d4];
            sc0 += q0.x * kk.x + q0.y * kk.y + q0.z * kk.z + q0.w * kk.w;
            sc1 += q1.x * kk.x + q1.y * kk.y + q1.z * kk.z + q1.w * kk.w;
        }
        pv[hp * 2][key]     = sc0 * SCALE;
        pv[hp * 2 + 1][key] = sc1 * SCALE;
    }
    __syncthreads();

    // ---- softmax: wave w handles head w (128 keys over 64 lanes) ----
    {
        int wv = tid >> 6, lane = tid & 63;
        float a0 = pv[wv][lane], a1 = pv[wv][lane + 64];
        float m = fmaxf(a0, a1);
#pragma unroll
        for (int off = 32; off; off >>= 1) m = fmaxf(m, __shfl_xor(m, off));
        float p0 = __expf(a0 - m), p1 = __expf(a1 - m);
        float l = p0 + p1;
#pragma unroll
        for (int off = 32; off; off >>= 1) l += __shfl_xor(l, off);
        pv[wv][lane] = p0;
        pv[wv][lane + 64] = p1;
        if (lane == 0) sD[wv] = l + __expf(sinks[kvh * 4 + wv] - m);
    }
    __syncthreads();

    // ---- V accumulate from LDS: thread = (head, d) ----
    {
        int hh = tid >> 6, d = tid & 63;
        float a0 = 0.f, a1 = 0.f, a2 = 0.f, a3 = 0.f;
#pragma unroll 4
        for (int i = 0; i < 128; i += 4) {
            a0 += pv[hh][i]     * Vs[i][d];
            a1 += pv[hh][i + 1] * Vs[i + 1][d];
            a2 += pv[hh][i + 2] * Vs[i + 2][d];
            a3 += pv[hh][i + 3] * Vs[i + 3][d];
        }
        float acc = (a0 + a1) + (a2 + a3);
        attn_out[(size_t)t * (NQ * HD) + (kvh * 4 + hh) * HD + d] = acc / sD[hh];
    }
}

// ---------------- MoE routing plumbing ----------------
__global__ __launch_bounds__(64) void moe_zero_kernel(int* __restrict__ cnt, int* __restrict__ pos) {
    if (threadIdx.x < E_) { cnt[threadIdx.x] = 0; pos[threadIdx.x] = 0; }
}

__global__ __launch_bounds__(256) void router_kernel(const float* __restrict__ x2,
                                                     const float* __restrict__ w_router,
                                                     const float* __restrict__ b_router,
                                                     int* __restrict__ ridx,
                                                     float* __restrict__ rwt,
                                                     int* __restrict__ cnt) {
    int t = blockIdx.x;
    int tid = threadIdx.x;
    int e = tid >> 5;       // 0..7
    int j = tid & 31;
    float acc = 0.f;
    for (int hh = j; hh < H; hh += 32) acc += x2[(size_t)t * H + hh] * w_router[hh * E_ + e];
#pragma unroll
    for (int off = 16; off; off >>= 1) acc += __shfl_down(acc, off);
    __shared__ float logits[E_];
    if (j == 0) logits[e] = acc + b_router[e];
    __syncthreads();
    if (tid == 0) {
        int i0 = 0; float v0 = logits[0];
        for (int ee = 1; ee < E_; ee++)
            if (logits[ee] > v0) { v0 = logits[ee]; i0 = ee; }
        int i1 = -1; float v1 = -3.4e38f;
        for (int ee = 0; ee < E_; ee++)
            if (ee != i0 && logits[ee] > v1) { v1 = logits[ee]; i1 = ee; }
        float w0 = 1.0f / (1.0f + __expf(v1 - v0));
        ridx[t * 2] = i0; ridx[t * 2 + 1] = i1;
        rwt[t * 2] = w0;  rwt[t * 2 + 1] = 1.0f - w0;
        atomicAdd(&cnt[i0], 1);
        atomicAdd(&cnt[i1], 1);
    }
}

__global__ __launch_bounds__(64) void moe_offsets_kernel(const int* __restrict__ cnt,
                                                         int* __restrict__ poff) {
    if (threadIdx.x == 0) {
        int run = 0;
        for (int e = 0; e < E_; e++) { poff[e] = run; run += (cnt[e] + 63) & ~63; }
    }
}

__global__ __launch_bounds__(256) void moe_scatter_kernel(const int* __restrict__ ridx,
                                                          int* __restrict__ pos,
                                                          const int* __restrict__ poff,
                                                          int* __restrict__ list) {
    int i = blockIdx.x * 256 + threadIdx.x;   // 0 .. 2T-1
    if (i < 2 * T_) {
        int e = ridx[i];
        int p = atomicAdd(&pos[e], 1);
        list[poff[e] + p] = i;                // i = t*2 + k
    }
}

// ---------------- Grouped gate_up split-K MFMA + swiglu ----------------
__global__ __launch_bounds__(256) void moe_gateup_sk(const float* __restrict__ x2,
                                                     const int* __restrict__ list,
                                                     const int* __restrict__ cnt,
                                                     const int* __restrict__ poff,
                                                     const float* __restrict__ w_gate_up,
                                                     const float* __restrict__ b_gate_up,
                                                     float* __restrict__ act) {
    int e  = blockIdx.y >> 4;
    int tl = blockIdx.y & 15;
    int n  = cnt[e];
    if (tl * 64 >= n) return;
    int base = poff[e];
    int nb = blockIdx.x * 16;                 // act-col base

    int tid = threadIdx.x;
    int wv = tid >> 6, lane = tid & 63;
    int r16 = lane & 15, kq = lane >> 4;
    const float* ap[4];
#pragma unroll
    for (int mt = 0; mt < 4; mt++) {
        int row = tl * 64 + mt * 16 + r16;
        int t2 = (row < n) ? list[base + row] : 0;
        ap[mt] = x2 + (size_t)(t2 >> 1) * 1024 + wv * 256 + kq * 8;
    }
    const float* bp = w_gate_up + (size_t)e * 1024 * 2048 + (size_t)(wv * 256 + kq * 8) * 2048 + 2 * (nb + r16);

    f32x4 accg[4] = {}, accu[4] = {};
#pragma unroll 2
    for (int k0 = 0; k0 < 256; k0 += 32) {
        s16x8 af[4];
#pragma unroll
        for (int mt = 0; mt < 4; mt++) {
            float4 a0 = *(const float4*)(ap[mt] + k0);
            float4 a1 = *(const float4*)(ap[mt] + k0 + 4);
            af[mt] = pack_a(a0, a1);
        }
        s16x8 bg, bu;
#pragma unroll
        for (int j = 0; j < 8; j++) {
            float2 gu = *(const float2*)(bp + (size_t)(k0 + j) * 2048);
            bg[j] = f2bf(gu.x); bu[j] = f2bf(gu.y);
        }
#pragma unroll
        for (int mt = 0; mt < 4; mt++) {
            accg[mt] = __builtin_amdgcn_mfma_f32_16x16x32_bf16(af[mt], bg, accg[mt], 0, 0, 0);
            accu[mt] = __builtin_amdgcn_mfma_f32_16x16x32_bf16(af[mt], bu, accu[mt], 0, 0, 0);
        }
    }
    __shared__ float redg[4][4][4][64];    // [wave][mt][r][lane]
    __shared__ float redu[4][4][4][64];
#pragma unroll
    for (int mt = 0; mt < 4; mt++)
#pragma unroll
        for (int r = 0; r < 4; r++) {
            redg[wv][mt][r][lane] = accg[mt][r];
            redu[wv][mt][r][lane] = accu[mt][r];
        }
    __syncthreads();
    int mt = tid >> 6, li = tid & 63;
    int kq2 = li >> 4, c16 = li & 15;
    int col = nb + c16;
    float bg_b = b_gate_up[(size_t)e * 2048 + 2 * col];
    float bu_b = b_gate_up[(size_t)e * 2048 + 2 * col + 1];
#pragma unroll
    for (int r = 0; r < 4; r++) {
        int rr = tl * 64 + mt * 16 + kq2 * 4 + r;
        if (rr < n) {
            float g = redg[0][mt][r][li] + redg[1][mt][r][li] + redg[2][mt][r][li] + redg[3][mt][r][li];
            float u = redu[0][mt][r][li] + redu[1][mt][r][li] + redu[2][mt][r][li] + redu[3][mt][r][li];
            float gate = fminf(g + bg_b, LIMIT);
            float up = fminf(fmaxf(u + bu_b, -LIMIT), LIMIT);
            float glu = gate / (1.0f + __expf(-ALPHA * gate));
            act[(size_t)(base + rr) * FFN + col] = (up + 1.0f) * glu;
        }
    }
}

// ---------------- Grouped down split-K MFMA ----------------
__global__ __launch_bounds__(256) void moe_down_sk(const float* __restrict__ act,
                                                   const int* __restrict__ list,
                                                   const int* __restrict__ cnt,
                                                   const int* __restrict__ poff,
                                                   const float* __restrict__ rwt,
                                                   const float* __restrict__ w_down,
                                                   const float* __restrict__ b_down,
                                                   float* __restrict__ part) {
    int e  = blockIdx.y >> 4;
    int tl = blockIdx.y & 15;
    int n  = cnt[e];
    if (tl * 64 >= n) return;
    int base = poff[e];
    int nb = blockIdx.x * 16;

    int tid = threadIdx.x;
    int wv = tid >> 6, lane = tid & 63;
    int r16 = lane & 15, kq = lane >> 4;
    const float* ap = act + (size_t)(base + tl * 64 + r16) * 1024 + wv * 256 + kq * 8;
    const float* bp = w_down + (size_t)e * 1024 * 1024 + (size_t)(wv * 256 + kq * 8) * 1024 + nb + r16;

    f32x4 acc[4] = {};
#pragma unroll 2
    for (int k0 = 0; k0 < 256; k0 += 32) {
        s16x8 af[4];
#pragma unroll
        for (int mt = 0; mt < 4; mt++) {
            float4 a0 = *(const float4*)(ap + mt * 16384 + k0);
            float4 a1 = *(const float4*)(ap + mt * 16384 + k0 + 4);
            af[mt] = pack_a(a0, a1);
        }
        s16x8 bf;
#pragma unroll
        for (int j = 0; j < 8; j++) bf[j] = f2bf(bp[(size_t)(k0 + j) * 1024]);
#pragma unroll
        for (int mt = 0; mt < 4; mt++)
            acc[mt] = __builtin_amdgcn_mfma_f32_16x16x32_bf16(af[mt], bf, acc[mt], 0, 0, 0);
    }
    __shared__ float red[4][4][4][64];
#pragma unroll
    for (int mt = 0; mt < 4; mt++)
#pragma unroll
        for (int r = 0; r < 4; r++) red[wv][mt][r][lane] = acc[mt][r];
    __syncthreads();
    int mt = tid >> 6, li = tid & 63;
    int kq2 = li >> 4, c16 = li & 15;
    int col = nb + c16;
    float bcol = b_down[(size_t)e * 1024 + col];
#pragma unroll
    for (int r = 0; r < 4; r++) {
        int rr = tl * 64 + mt * 16 + kq2 * 4 + r;
        if (rr < n) {
            float s = red[0][mt][r][li] + red[1][mt][r][li] + red[2][mt][r][li] + red[3][mt][r][li];
            int t2 = list[base + rr];
            part[(size_t)t2 * H + col] = rwt[t2] * (s + bcol);
        }
    }
}

// ---------------- out = h + part0 + part1 ----------------
__global__ __launch_bounds__(256) void final_add_kernel(const float* __restrict__ hbuf,
                                                        const float* __restrict__ part,
                                                        float* __restrict__ out) {
    int t = blockIdx.x;
    int tid = threadIdx.x;
    float4 a  = ((const float4*)(hbuf + (size_t)t * H))[tid];
    float4 p0 = ((const float4*)(part + (size_t)(t * 2) * H))[tid];
    float4 p1 = ((const float4*)(part + (size_t)(t * 2 + 1) * H))[tid];
    float4 o;
    o.x = a.x + p0.x + p1.x; o.y = a.y + p0.y + p1.y;
    o.z = a.z + p0.z + p1.z; o.w = a.w + p0.w + p1.w;
    ((float4*)(out + (size_t)t * H))[tid] = o;
}

extern "C" void kernel_launch(void* const* d_in, const int* in_sizes, int n_in,
                              void* d_out, int out_size, void* d_ws, size_t ws_size,
                              hipStream_t stream) {
    const float* hidden          = (const float*)d_in[0];
    const float* kv_cache        = (const float*)d_in[1];
    const int*   kv_page_indices = (const int*)d_in[3];
    const float* sinks           = (const float*)d_in[4];
    const float* w_qkv           = (const float*)d_in[5];
    const float* b_qkv           = (const float*)d_in[6];
    const float* w_o             = (const float*)d_in[7];
    const float* b_o             = (const float*)d_in[8];
    const float* ln1_w           = (const float*)d_in[9];
    const float* ln2_w           = (const float*)d_in[10];
    const float* w_router        = (const float*)d_in[11];
    const float* b_router        = (const float*)d_in[12];
    const float* w_gate_up       = (const float*)d_in[13];
    const float* b_gate_up       = (const float*)d_in[14];
    const float* w_down          = (const float*)d_in[15];
    const float* b_down          = (const float*)d_in[16];
    float* out = (float*)d_out;

    float* ws   = (float*)d_ws;
    float* x    = ws;                               // T*H
    float* qkv  = x + (size_t)T_ * H;               // T*QKV_N
    float* attn = qkv + (size_t)T_ * QKV_N;         // T*NQ*HD
    float* act  = ws;                               // MAXROWS*FFN (aliases x/qkv/attn, dead by MoE)
    float* hbuf = attn + (size_t)T_ * NQ * HD;      // T*H
    float* x2   = hbuf + (size_t)T_ * H;            // T*H
    float* part = x2 + (size_t)T_ * H;              // 2*T*H
    float* rwt  = part + (size_t)2 * T_ * H;        // 2*T
    int*   ridx = (int*)(rwt + 2 * T_);             // 2*T
    int*   cnt  = ridx + 2 * T_;                    // E
    int*   pos  = cnt + E_;                         // E
    int*   poff = pos + E_;                         // E
    int*   list = poff + E_;                        // MAXROWS

    moe_zero_kernel<<<1, 64, 0, stream>>>(cnt, pos);
    rmsnorm_kernel<<<T_, 256, 0, stream>>>(hidden, ln1_w, x);
    gemm_splitk_kernel<<<dim3(QKV_N / 16, T_ / 64), 256, 0, stream>>>(x, w_qkv, b_qkv, nullptr, qkv, QKV_N);
    attn_group_kernel<<<B_ * Q_ * NKV, 256, 0, stream>>>(qkv, kv_cache, kv_page_indices, sinks, attn);
    gemm_splitk_kernel<<<dim3(H / 16, T_ / 64), 256, 0, stream>>>(attn, w_o, b_o, hidden, hbuf, H);
    rmsnorm_kernel<<<T_, 256, 0, stream>>>(hbuf, ln2_w, x2);
    router_kernel<<<T_, 256, 0, stream>>>(x2, w_router, b_router, ridx, rwt, cnt);
    moe_offsets_kernel<<<1, 64, 0, stream>>>(cnt, poff);
    moe_scatter_kernel<<<(2 * T_ + 255) / 256, 256, 0, stream>>>(ridx, pos, poff, list);
    moe_gateup_sk<<<dim3(FFN / 16, E_ * 16), 256, 0, stream>>>(
        x2, list, cnt, poff, w_gate_up, b_gate_up, act);
    moe_down_sk<<<dim3(H / 16, E_ * 16), 256, 0, stream>>>(
        act, list, cnt, poff, rwt, w_down, b_down, part);
    final_add_kernel<<<T_, 256, 0, stream>>>(hbuf, part, out);
}

// Round 8
// 329.823 us; speedup vs baseline: 4.0335x; 1.1121x over previous
//
#include <hip/hip_runtime.h>

// ---- static config (mirrors reference) ----
constexpr int H    = 1024;
constexpr int HD   = 64;
constexpr int NQ   = 16;
constexpr int NKV  = 4;
constexpr int E_   = 8;
constexpr int FFN  = 1024;
constexpr int B_   = 4;
constexpr int Q_   = 128;
constexpr int P_   = 8;
constexpr int PS   = 128;
constexpr int S_   = P_ * PS;                 // 1024
constexpr int T_   = B_ * Q_;                 // 512
constexpr int QKV_N = HD * (NQ + 2 * NKV);    // 1536
constexpr float EPS   = 1e-5f;
constexpr float ALPHA = 1.702f;
constexpr float LIMIT = 7.0f;
constexpr float SCALE = 0.125f;               // HD^-0.5

constexpr int MAXROWS = 1536;                 // 1024 assignments + per-expert pad to 64

typedef __attribute__((ext_vector_type(4))) float f32x4;
typedef __attribute__((ext_vector_type(8))) short s16x8;

// f32 -> bf16 bits, round-to-nearest-even
__device__ __forceinline__ unsigned short f2bf(float f) {
    unsigned u = __float_as_uint(f);
    u += 0x7FFFu + ((u >> 16) & 1u);
    return (unsigned short)(u >> 16);
}

// ---------------- weight repack: f32 [K=1024][N] -> bf16 B-fragment order ----------------
// dst[((nb*32 + kb)*64 + lane)*8 + j] = bf16(src[kb*32 + (lane>>4)*8 + j][nb*16 + (lane&15)])
// grid: (8, N/16, E), block 256 (4 kb per block)
__global__ __launch_bounds__(256) void repack_b_kernel(const float* __restrict__ src0,
                                                       unsigned short* __restrict__ dst0,
                                                       int N, size_t srcE, size_t dstE) {
    int e = blockIdx.z;
    const float* src = src0 + (size_t)e * srcE;
    unsigned short* dst = dst0 + (size_t)e * dstE;
    int nb = blockIdx.y;
    int kb = blockIdx.x * 4 + (threadIdx.x >> 6);
    int lane = threadIdx.x & 63;
    int kq = lane >> 4, c16 = lane & 15;
    const float* s = src + (size_t)(kb * 32 + kq * 8) * N + nb * 16 + c16;
    s16x8 p;
#pragma unroll
    for (int j = 0; j < 8; j++) p[j] = (short)f2bf(s[(size_t)j * N]);
    *(s16x8*)(dst + (((size_t)nb * 32 + kb) * 64 + lane) * 8) = p;
}

// gate_up variant: src [E][1024][2N], cols interleaved (g,u); writes two fragment arrays
// grid: (8, N/16 = 64, 8), block 256
__global__ __launch_bounds__(256) void repack_gu_kernel(const float* __restrict__ wgu,
                                                        unsigned short* __restrict__ g,
                                                        unsigned short* __restrict__ u) {
    int e = blockIdx.z;
    int nb = blockIdx.y;
    int kb = blockIdx.x * 4 + (threadIdx.x >> 6);
    int lane = threadIdx.x & 63;
    int kq = lane >> 4, c16 = lane & 15;
    const float* s = wgu + ((size_t)e * 1024 + kb * 32 + kq * 8) * 2048 + 2 * (nb * 16 + c16);
    s16x8 pg, pu;
#pragma unroll
    for (int j = 0; j < 8; j++) {
        float2 v = *(const float2*)(s + (size_t)j * 2048);
        pg[j] = (short)f2bf(v.x);
        pu[j] = (short)f2bf(v.y);
    }
    size_t off = ((((size_t)e * 64 + nb) * 32 + kb) * 64 + lane) * 8;
    *(s16x8*)(g + off) = pg;
    *(s16x8*)(u + off) = pu;
}

// ---------------- RMSNorm: one block per token; f32 out optional, bf16 out optional ----------------
__global__ __launch_bounds__(256) void rmsnorm_kernel(const float* __restrict__ in,
                                                      const float* __restrict__ w,
                                                      float* __restrict__ outf,
                                                      unsigned short* __restrict__ outb) {
    int t   = blockIdx.x;
    int tid = threadIdx.x;
    const float4* in4 = (const float4*)(in + (size_t)t * H);
    float4 v = in4[tid];
    float ss = v.x * v.x + v.y * v.y + v.z * v.z + v.w * v.w;
#pragma unroll
    for (int off = 32; off; off >>= 1) ss += __shfl_down(ss, off);
    __shared__ float partial[4];
    __shared__ float s_inv;
    if ((tid & 63) == 0) partial[tid >> 6] = ss;
    __syncthreads();
    if (tid == 0)
        s_inv = rsqrtf((partial[0] + partial[1] + partial[2] + partial[3]) * (1.0f / H) + EPS);
    __syncthreads();
    float inv = s_inv;
    float4 wv = ((const float4*)w)[tid];
    float4 o;
    o.x = v.x * wv.x * inv; o.y = v.y * wv.y * inv;
    o.z = v.z * wv.z * inv; o.w = v.w * wv.w * inv;
    if (outf) ((float4*)(outf + (size_t)t * H))[tid] = o;
    if (outb) {
        ushort4 ob;
        ob.x = f2bf(o.x); ob.y = f2bf(o.y); ob.z = f2bf(o.z); ob.w = f2bf(o.w);
        ((ushort4*)(outb + (size_t)t * H))[tid] = ob;
    }
}

// ---------------- dense split-K MFMA GEMM: bf16 A rows + bf16 fragment B ----------------
__global__ __launch_bounds__(256) void gemm_splitk_bf16(const unsigned short* __restrict__ Abf,
                                                        const unsigned short* __restrict__ Bp,
                                                        const float* __restrict__ bias,
                                                        const float* __restrict__ resid,
                                                        float* __restrict__ C, int N) {
    int tid = threadIdx.x;
    int wv = tid >> 6, lane = tid & 63;
    int nb16 = blockIdx.x, mb = blockIdx.y * 64;
    int r16 = lane & 15, kq = lane >> 4;
    const unsigned short* ap = Abf + (size_t)(mb + r16) * 1024 + wv * 256 + kq * 8;
    const unsigned short* bp = Bp + (((size_t)nb16 * 32 + wv * 8) * 64 + lane) * 8;
    f32x4 acc[4] = {};
#pragma unroll 4
    for (int s = 0; s < 8; s++) {
        s16x8 af[4];
#pragma unroll
        for (int mt = 0; mt < 4; mt++)
            af[mt] = *(const s16x8*)(ap + mt * 16 * 1024 + s * 32);
        s16x8 bf = *(const s16x8*)(bp + s * 512);
#pragma unroll
        for (int mt = 0; mt < 4; mt++)
            acc[mt] = __builtin_amdgcn_mfma_f32_16x16x32_bf16(af[mt], bf, acc[mt], 0, 0, 0);
    }
    __shared__ float red[4][4][4][64];     // [wave][mt][r][lane]
#pragma unroll
    for (int mt = 0; mt < 4; mt++)
#pragma unroll
        for (int r = 0; r < 4; r++) red[wv][mt][r][lane] = acc[mt][r];
    __syncthreads();
    int mt = tid >> 6, li = tid & 63;
    int kq2 = li >> 4, c16 = li & 15;
    int col = nb16 * 16 + c16;
    float bcol = bias[col];
#pragma unroll
    for (int r = 0; r < 4; r++) {
        float s = red[0][mt][r][li] + red[1][mt][r][li] + red[2][mt][r][li] + red[3][mt][r][li];
        int row = mb + mt * 16 + kq2 * 4 + r;
        float v = s + bcol;
        if (resid) v += resid[(size_t)row * N + col];
        C[(size_t)row * N + col] = v;
    }
}

// ---------------- Attention: one block per (b, q, kvh); 4 heads/block; bf16 out ----------------
__global__ __launch_bounds__(256) void attn_group_kernel(const float* __restrict__ qkv,
                                                         const float* __restrict__ kv_cache,
                                                         const int* __restrict__ page_idx,
                                                         const float* __restrict__ sinks,
                                                         unsigned short* __restrict__ attn_bf) {
    int blk = blockIdx.x;
    int kvh = blk & 3;
    int q   = (blk >> 2) & 127;
    int b   = blk >> 9;
    int t   = b * Q_ + q;
    int tid = threadIdx.x;     // 256
    int s_lo = S_ - Q_ - 127 + q;   // 769+q; window is always exactly 128 keys

    __shared__ __align__(16) float Vs[128][64];   // 32 KB
    __shared__ __align__(16) float qs4[4][64];
    __shared__ float pv[4][128];
    __shared__ float sD[4];

#pragma unroll
    for (int r = 0; r < 8; r++) {
        int l = r * 256 + tid;
        int key = l >> 4, c = l & 15;
        int s = s_lo + key;
        const float* vp;
        if (s < S_ - Q_) {
            int page = page_idx[b * P_ + (s >> 7)];
            vp = kv_cache + (size_t)page * 65536 + 32768 + (size_t)(s & 127) * (NKV * HD) + kvh * HD;
        } else {
            vp = qkv + (size_t)(b * Q_ + (s - (S_ - Q_))) * QKV_N + (NQ + NKV) * HD + kvh * HD;
        }
        ((float4*)Vs[key])[c] = *(const float4*)(vp + c * 4);
    }
    {
        int hh = tid >> 6, d = tid & 63;
        qs4[hh][d] = qkv[(size_t)t * QKV_N + (kvh * 4 + hh) * HD + d];
    }
    __syncthreads();

    {
        int key = tid & 127, hp = tid >> 7;
        int s = s_lo + key;
        const float* kp;
        if (s < S_ - Q_) {
            int page = page_idx[b * P_ + (s >> 7)];
            kp = kv_cache + (size_t)page * 65536 + (size_t)(s & 127) * (NKV * HD) + kvh * HD;
        } else {
            kp = qkv + (size_t)(b * Q_ + (s - (S_ - Q_))) * QKV_N + NQ * HD + kvh * HD;
        }
        const float4* kp4 = (const float4*)kp;
        const float4* q0p = (const float4*)qs4[hp * 2];
        const float4* q1p = (const float4*)qs4[hp * 2 + 1];
        float sc0 = 0.f, sc1 = 0.f;
#pragma unroll
        for (int d4 = 0; d4 < 16; d4++) {
            float4 kk = kp4[d4];
            float4 q0 = q0p[d4], q1 = q1p[d4];
            sc0 += q0.x * kk.x + q0.y * kk.y + q0.z * kk.z + q0.w * kk.w;
            sc1 += q1.x * kk.x + q1.y * kk.y + q1.z * kk.z + q1.w * kk.w;
        }
        pv[hp * 2][key]     = sc0 * SCALE;
        pv[hp * 2 + 1][key] = sc1 * SCALE;
    }
    __syncthreads();

    {
        int wv = tid >> 6, lane = tid & 63;
        float a0 = pv[wv][lane], a1 = pv[wv][lane + 64];
        float m = fmaxf(a0, a1);
#pragma unroll
        for (int off = 32; off; off >>= 1) m = fmaxf(m, __shfl_xor(m, off));
        float p0 = __expf(a0 - m), p1 = __expf(a1 - m);
        float l = p0 + p1;
#pragma unroll
        for (int off = 32; off; off >>= 1) l += __shfl_xor(l, off);
        pv[wv][lane] = p0;
        pv[wv][lane + 64] = p1;
        if (lane == 0) sD[wv] = l + __expf(sinks[kvh * 4 + wv] - m);
    }
    __syncthreads();

    {
        int hh = tid >> 6, d = tid & 63;
        float a0 = 0.f, a1 = 0.f, a2 = 0.f, a3 = 0.f;
#pragma unroll 4
        for (int i = 0; i < 128; i += 4) {
            a0 += pv[hh][i]     * Vs[i][d];
            a1 += pv[hh][i + 1] * Vs[i + 1][d];
            a2 += pv[hh][i + 2] * Vs[i + 2][d];
            a3 += pv[hh][i + 3] * Vs[i + 3][d];
        }
        float acc = ((a0 + a1) + (a2 + a3)) / sD[hh];
        attn_bf[(size_t)t * (NQ * HD) + (kvh * 4 + hh) * HD + d] = f2bf(acc);
    }
}

// ---------------- MoE routing plumbing ----------------
__global__ __launch_bounds__(64) void moe_zero_kernel(int* __restrict__ cnt, int* __restrict__ pos) {
    if (threadIdx.x < E_) { cnt[threadIdx.x] = 0; pos[threadIdx.x] = 0; }
}

__global__ __launch_bounds__(256) void router_kernel(const float* __restrict__ x2,
                                                     const float* __restrict__ w_router,
                                                     const float* __restrict__ b_router,
                                                     int* __restrict__ ridx,
                                                     float* __restrict__ rwt,
                                                     int* __restrict__ cnt) {
    int t = blockIdx.x;
    int tid = threadIdx.x;
    int e = tid >> 5;       // 0..7
    int j = tid & 31;
    float acc = 0.f;
    for (int hh = j; hh < H; hh += 32) acc += x2[(size_t)t * H + hh] * w_router[hh * E_ + e];
#pragma unroll
    for (int off = 16; off; off >>= 1) acc += __shfl_down(acc, off);
    __shared__ float logits[E_];
    if (j == 0) logits[e] = acc + b_router[e];
    __syncthreads();
    if (tid == 0) {
        int i0 = 0; float v0 = logits[0];
        for (int ee = 1; ee < E_; ee++)
            if (logits[ee] > v0) { v0 = logits[ee]; i0 = ee; }
        int i1 = -1; float v1 = -3.4e38f;
        for (int ee = 0; ee < E_; ee++)
            if (ee != i0 && logits[ee] > v1) { v1 = logits[ee]; i1 = ee; }
        float w0 = 1.0f / (1.0f + __expf(v1 - v0));
        ridx[t * 2] = i0; ridx[t * 2 + 1] = i1;
        rwt[t * 2] = w0;  rwt[t * 2 + 1] = 1.0f - w0;
        atomicAdd(&cnt[i0], 1);
        atomicAdd(&cnt[i1], 1);
    }
}

__global__ __launch_bounds__(64) void moe_offsets_kernel(const int* __restrict__ cnt,
                                                         int* __restrict__ poff) {
    if (threadIdx.x == 0) {
        int run = 0;
        for (int e = 0; e < E_; e++) { poff[e] = run; run += (cnt[e] + 63) & ~63; }
    }
}

__global__ __launch_bounds__(256) void moe_scatter_kernel(const int* __restrict__ ridx,
                                                          int* __restrict__ pos,
                                                          const int* __restrict__ poff,
                                                          int* __restrict__ list) {
    int i = blockIdx.x * 256 + threadIdx.x;   // 0 .. 2T-1
    if (i < 2 * T_) {
        int e = ridx[i];
        int p = atomicAdd(&pos[e], 1);
        list[poff[e] + p] = i;                // i = t*2 + k
    }
}

// ---------------- Grouped gate_up split-K MFMA + swiglu (bf16 A + fragment B) ----------------
// grid: x = FFN/16 = 64, y = E*16 (64-row tiles, early exit)
__global__ __launch_bounds__(256) void moe_gateup_sk(const unsigned short* __restrict__ x2bf,
                                                     const int* __restrict__ list,
                                                     const int* __restrict__ cnt,
                                                     const int* __restrict__ poff,
                                                     const unsigned short* __restrict__ wg,
                                                     const unsigned short* __restrict__ wu,
                                                     const float* __restrict__ b_gate_up,
                                                     unsigned short* __restrict__ act_bf) {
    int e  = blockIdx.y >> 4;
    int tl = blockIdx.y & 15;
    int n  = cnt[e];
    if (tl * 64 >= n) return;
    int base = poff[e];
    int nb = blockIdx.x;                      // 16-col block

    int tid = threadIdx.x;
    int wv = tid >> 6, lane = tid & 63;
    int r16 = lane & 15, kq = lane >> 4;
    const unsigned short* ap[4];
#pragma unroll
    for (int mt = 0; mt < 4; mt++) {
        int row = tl * 64 + mt * 16 + r16;
        int t2 = (row < n) ? list[base + row] : 0;
        ap[mt] = x2bf + (size_t)(t2 >> 1) * 1024 + wv * 256 + kq * 8;
    }
    size_t boff = ((((size_t)e * 64 + nb) * 32 + wv * 8) * 64 + lane) * 8;
    const unsigned short* gp = wg + boff;
    const unsigned short* up = wu + boff;

    f32x4 accg[4] = {}, accu[4] = {};
#pragma unroll 2
    for (int s = 0; s < 8; s++) {
        s16x8 af[4];
#pragma unroll
        for (int mt = 0; mt < 4; mt++) af[mt] = *(const s16x8*)(ap[mt] + s * 32);
        s16x8 bg = *(const s16x8*)(gp + s * 512);
        s16x8 bu = *(const s16x8*)(up + s * 512);
#pragma unroll
        for (int mt = 0; mt < 4; mt++) {
            accg[mt] = __builtin_amdgcn_mfma_f32_16x16x32_bf16(af[mt], bg, accg[mt], 0, 0, 0);
            accu[mt] = __builtin_amdgcn_mfma_f32_16x16x32_bf16(af[mt], bu, accu[mt], 0, 0, 0);
        }
    }
    __shared__ float redg[4][4][4][64];    // [wave][mt][r][lane]
    __shared__ float redu[4][4][4][64];
#pragma unroll
    for (int mt = 0; mt < 4; mt++)
#pragma unroll
        for (int r = 0; r < 4; r++) {
            redg[wv][mt][r][lane] = accg[mt][r];
            redu[wv][mt][r][lane] = accu[mt][r];
        }
    __syncthreads();
    int mt = tid >> 6, li = tid & 63;
    int kq2 = li >> 4, c16 = li & 15;
    int col = nb * 16 + c16;
    float bg_b = b_gate_up[(size_t)e * 2048 + 2 * col];
    float bu_b = b_gate_up[(size_t)e * 2048 + 2 * col + 1];
#pragma unroll
    for (int r = 0; r < 4; r++) {
        int rr = tl * 64 + mt * 16 + kq2 * 4 + r;
        if (rr < n) {
            float g = redg[0][mt][r][li] + redg[1][mt][r][li] + redg[2][mt][r][li] + redg[3][mt][r][li];
            float u = redu[0][mt][r][li] + redu[1][mt][r][li] + redu[2][mt][r][li] + redu[3][mt][r][li];
            float gate = fminf(g + bg_b, LIMIT);
            float up2 = fminf(fmaxf(u + bu_b, -LIMIT), LIMIT);
            float glu = gate / (1.0f + __expf(-ALPHA * gate));
            act_bf[(size_t)(base + rr) * FFN + col] = f2bf((up2 + 1.0f) * glu);
        }
    }
}

// ---------------- Grouped down split-K MFMA (bf16 A + fragment B) ----------------
// grid: x = H/16 = 64, y = E*16
__global__ __launch_bounds__(256) void moe_down_sk(const unsigned short* __restrict__ act_bf,
                                                   const int* __restrict__ list,
                                                   const int* __restrict__ cnt,
                                                   const int* __restrict__ poff,
                                                   const float* __restrict__ rwt,
                                                   const unsigned short* __restrict__ wd,
                                                   const float* __restrict__ b_down,
                                                   float* __restrict__ part) {
    int e  = blockIdx.y >> 4;
    int tl = blockIdx.y & 15;
    int n  = cnt[e];
    if (tl * 64 >= n) return;
    int base = poff[e];
    int nb = blockIdx.x;

    int tid = threadIdx.x;
    int wv = tid >> 6, lane = tid & 63;
    int r16 = lane & 15, kq = lane >> 4;
    const unsigned short* ap = act_bf + (size_t)(base + tl * 64 + r16) * 1024 + wv * 256 + kq * 8;
    const unsigned short* bp = wd + ((size_t)e * 64 * 32 * 64 * 8) + (((size_t)nb * 32 + wv * 8) * 64 + lane) * 8;

    f32x4 acc[4] = {};
#pragma unroll 4
    for (int s = 0; s < 8; s++) {
        s16x8 af[4];
#pragma unroll
        for (int mt = 0; mt < 4; mt++) af[mt] = *(const s16x8*)(ap + mt * 16 * 1024 + s * 32);
        s16x8 bf = *(const s16x8*)(bp + s * 512);
#pragma unroll
        for (int mt = 0; mt < 4; mt++)
            acc[mt] = __builtin_amdgcn_mfma_f32_16x16x32_bf16(af[mt], bf, acc[mt], 0, 0, 0);
    }
    __shared__ float red[4][4][4][64];
#pragma unroll
    for (int mt = 0; mt < 4; mt++)
#pragma unroll
        for (int r = 0; r < 4; r++) red[wv][mt][r][lane] = acc[mt][r];
    __syncthreads();
    int mt = tid >> 6, li = tid & 63;
    int kq2 = li >> 4, c16 = li & 15;
    int col = nb * 16 + c16;
    float bcol = b_down[(size_t)e * 1024 + col];
#pragma unroll
    for (int r = 0; r < 4; r++) {
        int rr = tl * 64 + mt * 16 + kq2 * 4 + r;
        if (rr < n) {
            float s = red[0][mt][r][li] + red[1][mt][r][li] + red[2][mt][r][li] + red[3][mt][r][li];
            int t2 = list[base + rr];
            part[(size_t)t2 * H + col] = rwt[t2] * (s + bcol);
        }
    }
}

// ---------------- out = h + part0 + part1 ----------------
__global__ __launch_bounds__(256) void final_add_kernel(const float* __restrict__ hbuf,
                                                        const float* __restrict__ part,
                                                        float* __restrict__ out) {
    int t = blockIdx.x;
    int tid = threadIdx.x;
    float4 a  = ((const float4*)(hbuf + (size_t)t * H))[tid];
    float4 p0 = ((const float4*)(part + (size_t)(t * 2) * H))[tid];
    float4 p1 = ((const float4*)(part + (size_t)(t * 2 + 1) * H))[tid];
    float4 o;
    o.x = a.x + p0.x + p1.x; o.y = a.y + p0.y + p1.y;
    o.z = a.z + p0.z + p1.z; o.w = a.w + p0.w + p1.w;
    ((float4*)(out + (size_t)t * H))[tid] = o;
}

extern "C" void kernel_launch(void* const* d_in, const int* in_sizes, int n_in,
                              void* d_out, int out_size, void* d_ws, size_t ws_size,
                              hipStream_t stream) {
    const float* hidden          = (const float*)d_in[0];
    const float* kv_cache        = (const float*)d_in[1];
    const int*   kv_page_indices = (const int*)d_in[3];
    const float* sinks           = (const float*)d_in[4];
    const float* w_qkv           = (const float*)d_in[5];
    const float* b_qkv           = (const float*)d_in[6];
    const float* w_o             = (const float*)d_in[7];
    const float* b_o             = (const float*)d_in[8];
    const float* ln1_w           = (const float*)d_in[9];
    const float* ln2_w           = (const float*)d_in[10];
    const float* w_router        = (const float*)d_in[11];
    const float* b_router        = (const float*)d_in[12];
    const float* w_gate_up       = (const float*)d_in[13];
    const float* b_gate_up       = (const float*)d_in[14];
    const float* w_down          = (const float*)d_in[15];
    const float* b_down          = (const float*)d_in[16];
    float* out = (float*)d_out;

    // ---- workspace layout (bytes; all regions 16B-aligned) ----
    char* base = (char*)d_ws;
    float* qkv   = (float*)base;                       base += (size_t)T_ * QKV_N * 4;  // 3 MB
    float* hbuf  = (float*)base;                       base += (size_t)T_ * H * 4;      // 2 MB
    float* x2    = (float*)base;                       base += (size_t)T_ * H * 4;      // 2 MB
    float* part  = (float*)base;                       base += (size_t)2 * T_ * H * 4;  // 4 MB
    unsigned short* x_bf    = (unsigned short*)base;   base += (size_t)T_ * H * 2;      // 1 MB
    unsigned short* x2_bf   = (unsigned short*)base;   base += (size_t)T_ * H * 2;      // 1 MB
    unsigned short* attn_bf = (unsigned short*)base;   base += (size_t)T_ * NQ * HD * 2;// 1 MB
    unsigned short* act_bf  = (unsigned short*)base;   base += (size_t)MAXROWS * FFN * 2;// 3 MB
    unsigned short* wq_bf   = (unsigned short*)base;   base += (size_t)H * QKV_N * 2;   // 3 MB
    unsigned short* wo_bf   = (unsigned short*)base;   base += (size_t)H * H * 2;       // 2 MB
    unsigned short* wg_bf   = (unsigned short*)base;   base += (size_t)E_ * H * FFN * 2;// 16 MB
    unsigned short* wu_bf   = (unsigned short*)base;   base += (size_t)E_ * H * FFN * 2;// 16 MB
    unsigned short* wd_bf   = (unsigned short*)base;   base += (size_t)E_ * FFN * H * 2;// 16 MB
    float* rwt = (float*)base;                         base += 2 * T_ * 4;
    int*   ridx = (int*)base;                          base += 2 * T_ * 4;
    int*   cnt  = (int*)base;                          base += E_ * 4;
    int*   pos  = (int*)base;                          base += E_ * 4;
    int*   poff = (int*)base;                          base += E_ * 4;
    int*   list = (int*)base;                          base += MAXROWS * 4;

    moe_zero_kernel<<<1, 64, 0, stream>>>(cnt, pos);
    // weight repacks (independent; run first, fill L2/L3 with bf16 copies)
    repack_gu_kernel<<<dim3(8, 64, 8), 256, 0, stream>>>(w_gate_up, wg_bf, wu_bf);
    repack_b_kernel<<<dim3(8, 64, 8), 256, 0, stream>>>(w_down, wd_bf, H,
                                                        (size_t)FFN * H, (size_t)64 * 32 * 64 * 8);
    repack_b_kernel<<<dim3(8, QKV_N / 16, 1), 256, 0, stream>>>(w_qkv, wq_bf, QKV_N, 0, 0);
    repack_b_kernel<<<dim3(8, H / 16, 1), 256, 0, stream>>>(w_o, wo_bf, H, 0, 0);

    rmsnorm_kernel<<<T_, 256, 0, stream>>>(hidden, ln1_w, nullptr, x_bf);
    gemm_splitk_bf16<<<dim3(QKV_N / 16, T_ / 64), 256, 0, stream>>>(x_bf, wq_bf, b_qkv, nullptr, qkv, QKV_N);
    attn_group_kernel<<<B_ * Q_ * NKV, 256, 0, stream>>>(qkv, kv_cache, kv_page_indices, sinks, attn_bf);
    gemm_splitk_bf16<<<dim3(H / 16, T_ / 64), 256, 0, stream>>>(attn_bf, wo_bf, b_o, hidden, hbuf, H);
    rmsnorm_kernel<<<T_, 256, 0, stream>>>(hbuf, ln2_w, x2, x2_bf);
    router_kernel<<<T_, 256, 0, stream>>>(x2, w_router, b_router, ridx, rwt, cnt);
    moe_offsets_kernel<<<1, 64, 0, stream>>>(cnt, poff);
    moe_scatter_kernel<<<(2 * T_ + 255) / 256, 256, 0, stream>>>(ridx, pos, poff, list);
    moe_gateup_sk<<<dim3(FFN / 16, E_ * 16), 256, 0, stream>>>(
        x2_bf, list, cnt, poff, wg_bf, wu_bf, b_gate_up, act_bf);
    moe_down_sk<<<dim3(H / 16, E_ * 16), 256, 0, stream>>>(
        act_bf, list, cnt, poff, rwt, wd_bf, b_down, part);
    final_add_kernel<<<T_, 256, 0, stream>>>(hbuf, part, out);
}

// Round 9
// 310.066 us; speedup vs baseline: 4.2905x; 1.0637x over previous
//
#include <hip/hip_runtime.h>

// ---- static config (mirrors reference) ----
constexpr int H    = 1024;
constexpr int HD   = 64;
constexpr int NQ   = 16;
constexpr int NKV  = 4;
constexpr int E_   = 8;
constexpr int FFN  = 1024;
constexpr int B_   = 4;
constexpr int Q_   = 128;
constexpr int P_   = 8;
constexpr int PS   = 128;
constexpr int S_   = P_ * PS;                 // 1024
constexpr int T_   = B_ * Q_;                 // 512
constexpr int QKV_N = HD * (NQ + 2 * NKV);    // 1536
constexpr float EPS   = 1e-5f;
constexpr float ALPHA = 1.702f;
constexpr float LIMIT = 7.0f;
constexpr float SCALE = 0.125f;               // HD^-0.5

constexpr int MAXROWS = 1536;                 // 1024 assignments + per-expert pad to 64

typedef __attribute__((ext_vector_type(4))) float f32x4;
typedef __attribute__((ext_vector_type(8))) short s16x8;

__device__ __forceinline__ unsigned short f2bf(float f) {
    unsigned u = __float_as_uint(f);
    u += 0x7FFFu + ((u >> 16) & 1u);
    return (unsigned short)(u >> 16);
}

// ---------------- fused repack: all weights f32 -> bf16 B-fragment order; zero cnt ----------------
// flat grid 9472 blocks x 256:
//  [0,4096)    gate_up -> wg,wu   (e, nb<64, kbg<8)
//  [4096,8192) w_down  -> wd      (e, nb<64, kbg<8)
//  [8192,8960) w_qkv   -> wq      (nb<96, kbg<8)
//  [8960,9472) w_o     -> wo      (nb<64, kbg<8)
__global__ __launch_bounds__(256) void repack_all_kernel(const float* __restrict__ wgu,
                                                         const float* __restrict__ wdn,
                                                         const float* __restrict__ wqkv,
                                                         const float* __restrict__ wo,
                                                         unsigned short* __restrict__ g,
                                                         unsigned short* __restrict__ u,
                                                         unsigned short* __restrict__ d,
                                                         unsigned short* __restrict__ q,
                                                         unsigned short* __restrict__ o,
                                                         int* __restrict__ cnt) {
    int idx = blockIdx.x;
    int tid = threadIdx.x;
    if (idx == 0 && tid < E_) cnt[tid] = 0;
    int lane = tid & 63;
    int kq = lane >> 4, c16 = lane & 15;
    if (idx < 4096) {
        int e = idx >> 9, rem = idx & 511;
        int nb = rem >> 3, kb = (rem & 7) * 4 + (tid >> 6);
        const float* s = wgu + ((size_t)e * 1024 + kb * 32 + kq * 8) * 2048 + 2 * (nb * 16 + c16);
        s16x8 pg, pu;
#pragma unroll
        for (int j = 0; j < 8; j++) {
            float2 v = *(const float2*)(s + (size_t)j * 2048);
            pg[j] = (short)f2bf(v.x);
            pu[j] = (short)f2bf(v.y);
        }
        size_t off = ((((size_t)e * 64 + nb) * 32 + kb) * 64 + lane) * 8;
        *(s16x8*)(g + off) = pg;
        *(s16x8*)(u + off) = pu;
    } else if (idx < 8192) {
        int i2 = idx - 4096;
        int e = i2 >> 9, rem = i2 & 511;
        int nb = rem >> 3, kb = (rem & 7) * 4 + (tid >> 6);
        const float* s = wdn + (size_t)e * FFN * H + (size_t)(kb * 32 + kq * 8) * 1024 + nb * 16 + c16;
        s16x8 p;
#pragma unroll
        for (int j = 0; j < 8; j++) p[j] = (short)f2bf(s[(size_t)j * 1024]);
        size_t off = (size_t)e * (64 * 32 * 64 * 8) + (((size_t)nb * 32 + kb) * 64 + lane) * 8;
        *(s16x8*)(d + off) = p;
    } else if (idx < 8960) {
        int i2 = idx - 8192;
        int nb = i2 >> 3, kb = (i2 & 7) * 4 + (tid >> 6);
        const float* s = wqkv + (size_t)(kb * 32 + kq * 8) * QKV_N + nb * 16 + c16;
        s16x8 p;
#pragma unroll
        for (int j = 0; j < 8; j++) p[j] = (short)f2bf(s[(size_t)j * QKV_N]);
        *(s16x8*)(q + (((size_t)nb * 32 + kb) * 64 + lane) * 8) = p;
    } else {
        int i2 = idx - 8960;
        int nb = i2 >> 3, kb = (i2 & 7) * 4 + (tid >> 6);
        const float* s = wo + (size_t)(kb * 32 + kq * 8) * H + nb * 16 + c16;
        s16x8 p;
#pragma unroll
        for (int j = 0; j < 8; j++) p[j] = (short)f2bf(s[(size_t)j * H]);
        *(s16x8*)(o + (((size_t)nb * 32 + kb) * 64 + lane) * 8) = p;
    }
}

// ---------------- RMSNorm -> bf16 out ----------------
__global__ __launch_bounds__(256) void rmsnorm_kernel(const float* __restrict__ in,
                                                      const float* __restrict__ w,
                                                      unsigned short* __restrict__ outb) {
    int t   = blockIdx.x;
    int tid = threadIdx.x;
    float4 v = ((const float4*)(in + (size_t)t * H))[tid];
    float ss = v.x * v.x + v.y * v.y + v.z * v.z + v.w * v.w;
#pragma unroll
    for (int off = 32; off; off >>= 1) ss += __shfl_down(ss, off);
    __shared__ float partial[4];
    __shared__ float s_inv;
    if ((tid & 63) == 0) partial[tid >> 6] = ss;
    __syncthreads();
    if (tid == 0)
        s_inv = rsqrtf((partial[0] + partial[1] + partial[2] + partial[3]) * (1.0f / H) + EPS);
    __syncthreads();
    float inv = s_inv;
    float4 wv = ((const float4*)w)[tid];
    ushort4 ob;
    ob.x = f2bf(v.x * wv.x * inv); ob.y = f2bf(v.y * wv.y * inv);
    ob.z = f2bf(v.z * wv.z * inv); ob.w = f2bf(v.w * wv.w * inv);
    ((ushort4*)(outb + (size_t)t * H))[tid] = ob;
}

// ---------------- dense split-K MFMA GEMM (bf16 A rows + fragment B); optional dup store ----------------
__global__ __launch_bounds__(256) void gemm_splitk_bf16(const unsigned short* __restrict__ Abf,
                                                        const unsigned short* __restrict__ Bp,
                                                        const float* __restrict__ bias,
                                                        const float* __restrict__ resid,
                                                        float* __restrict__ C,
                                                        float* __restrict__ Cdup, int N) {
    int tid = threadIdx.x;
    int wv = tid >> 6, lane = tid & 63;
    int nb16 = blockIdx.x, mb = blockIdx.y * 64;
    int r16 = lane & 15, kq = lane >> 4;
    const unsigned short* ap = Abf + (size_t)(mb + r16) * 1024 + wv * 256 + kq * 8;
    const unsigned short* bp = Bp + (((size_t)nb16 * 32 + wv * 8) * 64 + lane) * 8;
    f32x4 acc[4] = {};
#pragma unroll 4
    for (int s = 0; s < 8; s++) {
        s16x8 af[4];
#pragma unroll
        for (int mt = 0; mt < 4; mt++)
            af[mt] = *(const s16x8*)(ap + mt * 16 * 1024 + s * 32);
        s16x8 bf = *(const s16x8*)(bp + s * 512);
#pragma unroll
        for (int mt = 0; mt < 4; mt++)
            acc[mt] = __builtin_amdgcn_mfma_f32_16x16x32_bf16(af[mt], bf, acc[mt], 0, 0, 0);
    }
    __shared__ float red[4][4][4][64];
#pragma unroll
    for (int mt = 0; mt < 4; mt++)
#pragma unroll
        for (int r = 0; r < 4; r++) red[wv][mt][r][lane] = acc[mt][r];
    __syncthreads();
    int mt = tid >> 6, li = tid & 63;
    int kq2 = li >> 4, c16 = li & 15;
    int col = nb16 * 16 + c16;
    float bcol = bias[col];
#pragma unroll
    for (int r = 0; r < 4; r++) {
        float s = red[0][mt][r][li] + red[1][mt][r][li] + red[2][mt][r][li] + red[3][mt][r][li];
        int row = mb + mt * 16 + kq2 * 4 + r;
        float v = s + bcol;
        if (resid) v += resid[(size_t)row * N + col];
        C[(size_t)row * N + col] = v;
        if (Cdup) Cdup[(size_t)row * N + col] = v;
    }
}

// ---------------- Attention: one block per (b, q, kvh); 4 heads/block; bf16 out ----------------
__global__ __launch_bounds__(256) void attn_group_kernel(const float* __restrict__ qkv,
                                                         const float* __restrict__ kv_cache,
                                                         const int* __restrict__ page_idx,
                                                         const float* __restrict__ sinks,
                                                         unsigned short* __restrict__ attn_bf) {
    int blk = blockIdx.x;
    int kvh = blk & 3;
    int q   = (blk >> 2) & 127;
    int b   = blk >> 9;
    int t   = b * Q_ + q;
    int tid = threadIdx.x;
    int s_lo = S_ - Q_ - 127 + q;

    __shared__ __align__(16) float Vs[128][64];
    __shared__ __align__(16) float qs4[4][64];
    __shared__ float pv[4][128];
    __shared__ float sD[4];

#pragma unroll
    for (int r = 0; r < 8; r++) {
        int l = r * 256 + tid;
        int key = l >> 4, c = l & 15;
        int s = s_lo + key;
        const float* vp;
        if (s < S_ - Q_) {
            int page = page_idx[b * P_ + (s >> 7)];
            vp = kv_cache + (size_t)page * 65536 + 32768 + (size_t)(s & 127) * (NKV * HD) + kvh * HD;
        } else {
            vp = qkv + (size_t)(b * Q_ + (s - (S_ - Q_))) * QKV_N + (NQ + NKV) * HD + kvh * HD;
        }
        ((float4*)Vs[key])[c] = *(const float4*)(vp + c * 4);
    }
    {
        int hh = tid >> 6, d2 = tid & 63;
        qs4[hh][d2] = qkv[(size_t)t * QKV_N + (kvh * 4 + hh) * HD + d2];
    }
    __syncthreads();

    {
        int key = tid & 127, hp = tid >> 7;
        int s = s_lo + key;
        const float* kp;
        if (s < S_ - Q_) {
            int page = page_idx[b * P_ + (s >> 7)];
            kp = kv_cache + (size_t)page * 65536 + (size_t)(s & 127) * (NKV * HD) + kvh * HD;
        } else {
            kp = qkv + (size_t)(b * Q_ + (s - (S_ - Q_))) * QKV_N + NQ * HD + kvh * HD;
        }
        const float4* kp4 = (const float4*)kp;
        const float4* q0p = (const float4*)qs4[hp * 2];
        const float4* q1p = (const float4*)qs4[hp * 2 + 1];
        float sc0 = 0.f, sc1 = 0.f;
#pragma unroll
        for (int d4 = 0; d4 < 16; d4++) {
            float4 kk = kp4[d4];
            float4 q0 = q0p[d4], q1 = q1p[d4];
            sc0 += q0.x * kk.x + q0.y * kk.y + q0.z * kk.z + q0.w * kk.w;
            sc1 += q1.x * kk.x + q1.y * kk.y + q1.z * kk.z + q1.w * kk.w;
        }
        pv[hp * 2][key]     = sc0 * SCALE;
        pv[hp * 2 + 1][key] = sc1 * SCALE;
    }
    __syncthreads();

    {
        int wv = tid >> 6, lane = tid & 63;
        float a0 = pv[wv][lane], a1 = pv[wv][lane + 64];
        float m = fmaxf(a0, a1);
#pragma unroll
        for (int off = 32; off; off >>= 1) m = fmaxf(m, __shfl_xor(m, off));
        float p0 = __expf(a0 - m), p1 = __expf(a1 - m);
        float l = p0 + p1;
#pragma unroll
        for (int off = 32; off; off >>= 1) l += __shfl_xor(l, off);
        pv[wv][lane] = p0;
        pv[wv][lane + 64] = p1;
        if (lane == 0) sD[wv] = l + __expf(sinks[kvh * 4 + wv] - m);
    }
    __syncthreads();

    {
        int hh = tid >> 6, d2 = tid & 63;
        float a0 = 0.f, a1 = 0.f, a2 = 0.f, a3 = 0.f;
#pragma unroll 4
        for (int i = 0; i < 128; i += 4) {
            a0 += pv[hh][i]     * Vs[i][d2];
            a1 += pv[hh][i + 1] * Vs[i + 1][d2];
            a2 += pv[hh][i + 2] * Vs[i + 2][d2];
            a3 += pv[hh][i + 3] * Vs[i + 3][d2];
        }
        float acc = ((a0 + a1) + (a2 + a3)) / sD[hh];
        attn_bf[(size_t)t * (NQ * HD) + (kvh * 4 + hh) * HD + d2] = f2bf(acc);
    }
}

// ---------------- fused RMSNorm2 + router (reads hbuf; writes x2_bf, ridx, rwt, cnt) ----------------
__global__ __launch_bounds__(256) void rms_router_kernel(const float* __restrict__ hbuf,
                                                         const float* __restrict__ ln2w,
                                                         const float* __restrict__ w_router,
                                                         const float* __restrict__ b_router,
                                                         unsigned short* __restrict__ x2bf,
                                                         int* __restrict__ ridx,
                                                         float* __restrict__ rwt,
                                                         int* __restrict__ cnt) {
    int t = blockIdx.x;
    int tid = threadIdx.x;
    float4 v = ((const float4*)(hbuf + (size_t)t * H))[tid];
    float ss = v.x * v.x + v.y * v.y + v.z * v.z + v.w * v.w;
#pragma unroll
    for (int off = 32; off; off >>= 1) ss += __shfl_down(ss, off);
    __shared__ float partial[4];
    __shared__ float s_inv;
    if ((tid & 63) == 0) partial[tid >> 6] = ss;
    __syncthreads();
    if (tid == 0)
        s_inv = rsqrtf((partial[0] + partial[1] + partial[2] + partial[3]) * (1.0f / H) + EPS);
    __syncthreads();
    float inv = s_inv;
    float4 wv = ((const float4*)ln2w)[tid];
    float4 o;
    o.x = v.x * wv.x * inv; o.y = v.y * wv.y * inv;
    o.z = v.z * wv.z * inv; o.w = v.w * wv.w * inv;
    ushort4 ob;
    ob.x = f2bf(o.x); ob.y = f2bf(o.y); ob.z = f2bf(o.z); ob.w = f2bf(o.w);
    ((ushort4*)(x2bf + (size_t)t * H))[tid] = ob;

    // logits: thread covers rows h = 4*tid .. 4*tid+3 of w_router [H][E]
    const float4* wr = (const float4*)(w_router + (size_t)tid * 4 * E_);
    float p[E_];
    {
        float4 r0a = wr[0], r0b = wr[1];   // row 4t   (8 floats)
        float4 r1a = wr[2], r1b = wr[3];   // row 4t+1
        float4 r2a = wr[4], r2b = wr[5];   // row 4t+2
        float4 r3a = wr[6], r3b = wr[7];   // row 4t+3
        p[0] = o.x * r0a.x + o.y * r1a.x + o.z * r2a.x + o.w * r3a.x;
        p[1] = o.x * r0a.y + o.y * r1a.y + o.z * r2a.y + o.w * r3a.y;
        p[2] = o.x * r0a.z + o.y * r1a.z + o.z * r2a.z + o.w * r3a.z;
        p[3] = o.x * r0a.w + o.y * r1a.w + o.z * r2a.w + o.w * r3a.w;
        p[4] = o.x * r0b.x + o.y * r1b.x + o.z * r2b.x + o.w * r3b.x;
        p[5] = o.x * r0b.y + o.y * r1b.y + o.z * r2b.y + o.w * r3b.y;
        p[6] = o.x * r0b.z + o.y * r1b.z + o.z * r2b.z + o.w * r3b.z;
        p[7] = o.x * r0b.w + o.y * r1b.w + o.z * r2b.w + o.w * r3b.w;
    }
    __shared__ float wsum[4][E_];
    int wv2 = tid >> 6, lane = tid & 63;
#pragma unroll
    for (int e = 0; e < E_; e++) {
        float r = p[e];
#pragma unroll
        for (int off = 32; off; off >>= 1) r += __shfl_xor(r, off);
        if (lane == 0) wsum[wv2][e] = r;
    }
    __syncthreads();
    __shared__ float logits[E_];
    if (tid < E_)
        logits[tid] = wsum[0][tid] + wsum[1][tid] + wsum[2][tid] + wsum[3][tid] + b_router[tid];
    __syncthreads();
    if (tid == 0) {
        int i0 = 0; float v0 = logits[0];
        for (int ee = 1; ee < E_; ee++)
            if (logits[ee] > v0) { v0 = logits[ee]; i0 = ee; }
        int i1 = -1; float v1 = -3.4e38f;
        for (int ee = 0; ee < E_; ee++)
            if (ee != i0 && logits[ee] > v1) { v1 = logits[ee]; i1 = ee; }
        float w0 = 1.0f / (1.0f + __expf(v1 - v0));
        ridx[t * 2] = i0; ridx[t * 2 + 1] = i1;
        rwt[t * 2] = w0;  rwt[t * 2 + 1] = 1.0f - w0;
        atomicAdd(&cnt[i0], 1);
        atomicAdd(&cnt[i1], 1);
    }
}

// ---------------- plumb: offsets + scatter in one 1-block kernel ----------------
__global__ __launch_bounds__(256) void plumb_kernel(const int* __restrict__ cnt,
                                                    const int* __restrict__ ridx,
                                                    int* __restrict__ poff,
                                                    int* __restrict__ list) {
    __shared__ int lpos[E_], lpoff[E_];
    int tid = threadIdx.x;
    if (tid == 0) {
        int run = 0;
        for (int e = 0; e < E_; e++) { lpoff[e] = run; poff[e] = run; run += (cnt[e] + 63) & ~63; }
    }
    if (tid < E_) lpos[tid] = 0;
    __syncthreads();
    for (int i = tid; i < 2 * T_; i += 256) {
        int e = ridx[i];
        int pp = atomicAdd(&lpos[e], 1);
        list[lpoff[e] + pp] = i;
    }
}

// ---------------- Grouped gate_up split-K MFMA + swiglu, 128-row tiles ----------------
// grid: x = FFN/16 = 64, y = E*8 (128-row tiles, early exit)
__global__ __launch_bounds__(256) void moe_gateup_sk(const unsigned short* __restrict__ x2bf,
                                                     const int* __restrict__ list,
                                                     const int* __restrict__ cnt,
                                                     const int* __restrict__ poff,
                                                     const unsigned short* __restrict__ wg,
                                                     const unsigned short* __restrict__ wu,
                                                     const float* __restrict__ b_gate_up,
                                                     unsigned short* __restrict__ act_bf) {
    int e  = blockIdx.y >> 3;
    int tl = blockIdx.y & 7;
    int n  = cnt[e];
    if (tl * 128 >= n) return;
    int base = poff[e];
    int nb = blockIdx.x;

    int tid = threadIdx.x;
    int wv = tid >> 6, lane = tid & 63;
    int r16 = lane & 15, kq = lane >> 4;
    const unsigned short* ap[8];
#pragma unroll
    for (int mt = 0; mt < 8; mt++) {
        int row = tl * 128 + mt * 16 + r16;
        int t2 = (row < n) ? list[base + row] : 0;
        ap[mt] = x2bf + (size_t)(t2 >> 1) * 1024 + wv * 256 + kq * 8;
    }
    size_t boff = ((((size_t)e * 64 + nb) * 32 + wv * 8) * 64 + lane) * 8;
    const unsigned short* gp = wg + boff;
    const unsigned short* up = wu + boff;

    f32x4 accg[8] = {}, accu[8] = {};
#pragma unroll 2
    for (int s = 0; s < 8; s++) {
        s16x8 bg = *(const s16x8*)(gp + s * 512);
        s16x8 bu = *(const s16x8*)(up + s * 512);
#pragma unroll
        for (int mt = 0; mt < 8; mt++) {
            s16x8 af = *(const s16x8*)(ap[mt] + s * 32);
            accg[mt] = __builtin_amdgcn_mfma_f32_16x16x32_bf16(af, bg, accg[mt], 0, 0, 0);
            accu[mt] = __builtin_amdgcn_mfma_f32_16x16x32_bf16(af, bu, accu[mt], 0, 0, 0);
        }
    }
    __shared__ float redg[4][4][4][64];
    __shared__ float redu[4][4][4][64];
    int col = nb * 16 + (tid & 15);
    float bg_b = b_gate_up[(size_t)e * 2048 + 2 * col];
    float bu_b = b_gate_up[(size_t)e * 2048 + 2 * col + 1];
#pragma unroll
    for (int h = 0; h < 2; h++) {
        __syncthreads();
#pragma unroll
        for (int m2 = 0; m2 < 4; m2++)
#pragma unroll
            for (int r = 0; r < 4; r++) {
                redg[wv][m2][r][lane] = accg[h * 4 + m2][r];
                redu[wv][m2][r][lane] = accu[h * 4 + m2][r];
            }
        __syncthreads();
        int m2 = tid >> 6, li = tid & 63;
        int kq2 = li >> 4;
#pragma unroll
        for (int r = 0; r < 4; r++) {
            int rr = tl * 128 + (h * 4 + m2) * 16 + kq2 * 4 + r;
            if (rr < n) {
                float g = redg[0][m2][r][li] + redg[1][m2][r][li] + redg[2][m2][r][li] + redg[3][m2][r][li];
                float u = redu[0][m2][r][li] + redu[1][m2][r][li] + redu[2][m2][r][li] + redu[3][m2][r][li];
                float gate = fminf(g + bg_b, LIMIT);
                float up2 = fminf(fmaxf(u + bu_b, -LIMIT), LIMIT);
                float glu = gate / (1.0f + __expf(-ALPHA * gate));
                act_bf[(size_t)(base + rr) * FFN + col] = f2bf((up2 + 1.0f) * glu);
            }
        }
    }
}

// ---------------- Grouped down split-K MFMA, 128-row tiles; atomicAdd into out ----------------
// grid: x = H/16 = 64, y = E*8
__global__ __launch_bounds__(256) void moe_down_sk(const unsigned short* __restrict__ act_bf,
                                                   const int* __restrict__ list,
                                                   const int* __restrict__ cnt,
                                                   const int* __restrict__ poff,
                                                   const float* __restrict__ rwt,
                                                   const unsigned short* __restrict__ wd,
                                                   const float* __restrict__ b_down,
                                                   float* __restrict__ out) {
    int e  = blockIdx.y >> 3;
    int tl = blockIdx.y & 7;
    int n  = cnt[e];
    if (tl * 128 >= n) return;
    int base = poff[e];
    int nb = blockIdx.x;

    int tid = threadIdx.x;
    int wv = tid >> 6, lane = tid & 63;
    int r16 = lane & 15, kq = lane >> 4;
    const unsigned short* ap = act_bf + (size_t)(base + tl * 128 + r16) * 1024 + wv * 256 + kq * 8;
    const unsigned short* bp = wd + (size_t)e * (64 * 32 * 64 * 8) + (((size_t)nb * 32 + wv * 8) * 64 + lane) * 8;

    f32x4 acc[8] = {};
#pragma unroll 2
    for (int s = 0; s < 8; s++) {
        s16x8 bf = *(const s16x8*)(bp + s * 512);
#pragma unroll
        for (int mt = 0; mt < 8; mt++) {
            s16x8 af = *(const s16x8*)(ap + mt * 16 * 1024 + s * 32);
            acc[mt] = __builtin_amdgcn_mfma_f32_16x16x32_bf16(af, bf, acc[mt], 0, 0, 0);
        }
    }
    __shared__ float red[4][4][4][64];
    int col = nb * 16 + (tid & 15);
    float bcol = b_down[(size_t)e * 1024 + col];
#pragma unroll
    for (int h = 0; h < 2; h++) {
        __syncthreads();
#pragma unroll
        for (int m2 = 0; m2 < 4; m2++)
#pragma unroll
            for (int r = 0; r < 4; r++) red[wv][m2][r][lane] = acc[h * 4 + m2][r];
        __syncthreads();
        int m2 = tid >> 6, li = tid & 63;
        int kq2 = li >> 4;
#pragma unroll
        for (int r = 0; r < 4; r++) {
            int rr = tl * 128 + (h * 4 + m2) * 16 + kq2 * 4 + r;
            if (rr < n) {
                float s = red[0][m2][r][li] + red[1][m2][r][li] + red[2][m2][r][li] + red[3][m2][r][li];
                int t2 = list[base + rr];
                atomicAdd(&out[(size_t)(t2 >> 1) * H + col], rwt[t2] * (s + bcol));
            }
        }
    }
}

extern "C" void kernel_launch(void* const* d_in, const int* in_sizes, int n_in,
                              void* d_out, int out_size, void* d_ws, size_t ws_size,
                              hipStream_t stream) {
    const float* hidden          = (const float*)d_in[0];
    const float* kv_cache        = (const float*)d_in[1];
    const int*   kv_page_indices = (const int*)d_in[3];
    const float* sinks           = (const float*)d_in[4];
    const float* w_qkv           = (const float*)d_in[5];
    const float* b_qkv           = (const float*)d_in[6];
    const float* w_o             = (const float*)d_in[7];
    const float* b_o             = (const float*)d_in[8];
    const float* ln1_w           = (const float*)d_in[9];
    const float* ln2_w           = (const float*)d_in[10];
    const float* w_router        = (const float*)d_in[11];
    const float* b_router        = (const float*)d_in[12];
    const float* w_gate_up       = (const float*)d_in[13];
    const float* b_gate_up       = (const float*)d_in[14];
    const float* w_down          = (const float*)d_in[15];
    const float* b_down          = (const float*)d_in[16];
    float* out = (float*)d_out;

    // ---- workspace layout ----
    char* base = (char*)d_ws;
    float* qkv   = (float*)base;                       base += (size_t)T_ * QKV_N * 4;
    float* hbuf  = (float*)base;                       base += (size_t)T_ * H * 4;
    unsigned short* x_bf    = (unsigned short*)base;   base += (size_t)T_ * H * 2;
    unsigned short* x2_bf   = (unsigned short*)base;   base += (size_t)T_ * H * 2;
    unsigned short* attn_bf = (unsigned short*)base;   base += (size_t)T_ * NQ * HD * 2;
    unsigned short* act_bf  = (unsigned short*)base;   base += (size_t)(MAXROWS + 128) * FFN * 2;
    unsigned short* wq_bf   = (unsigned short*)base;   base += (size_t)H * QKV_N * 2;
    unsigned short* wo_bf   = (unsigned short*)base;   base += (size_t)H * H * 2;
    unsigned short* wg_bf   = (unsigned short*)base;   base += (size_t)E_ * H * FFN * 2;
    unsigned short* wu_bf   = (unsigned short*)base;   base += (size_t)E_ * H * FFN * 2;
    unsigned short* wd_bf   = (unsigned short*)base;   base += (size_t)E_ * FFN * H * 2;
    float* rwt  = (float*)base;                        base += 2 * T_ * 4;
    int*   ridx = (int*)base;                          base += 2 * T_ * 4;
    int*   cnt  = (int*)base;                          base += E_ * 4;
    int*   poff = (int*)base;                          base += E_ * 4;
    int*   list = (int*)base;                          base += MAXROWS * 4;

    repack_all_kernel<<<9472, 256, 0, stream>>>(w_gate_up, w_down, w_qkv, w_o,
                                                wg_bf, wu_bf, wd_bf, wq_bf, wo_bf, cnt);
    rmsnorm_kernel<<<T_, 256, 0, stream>>>(hidden, ln1_w, x_bf);
    gemm_splitk_bf16<<<dim3(QKV_N / 16, T_ / 64), 256, 0, stream>>>(
        x_bf, wq_bf, b_qkv, nullptr, qkv, nullptr, QKV_N);
    attn_group_kernel<<<B_ * Q_ * NKV, 256, 0, stream>>>(qkv, kv_cache, kv_page_indices, sinks, attn_bf);
    gemm_splitk_bf16<<<dim3(H / 16, T_ / 64), 256, 0, stream>>>(
        attn_bf, wo_bf, b_o, hidden, hbuf, out, H);
    rms_router_kernel<<<T_, 256, 0, stream>>>(hbuf, ln2_w, w_router, b_router,
                                              x2_bf, ridx, rwt, cnt);
    plumb_kernel<<<1, 256, 0, stream>>>(cnt, ridx, poff, list);
    moe_gateup_sk<<<dim3(FFN / 16, E_ * 8), 256, 0, stream>>>(
        x2_bf, list, cnt, poff, wg_bf, wu_bf, b_gate_up, act_bf);
    moe_down_sk<<<dim3(H / 16, E_ * 8), 256, 0, stream>>>(
        act_bf, list, cnt, poff, rwt, wd_bf, b_down, out);
}